// Round 14
// baseline (242.530 us; speedup 1.0000x reference)
//
#include <hip/hip_runtime.h>

using u16 = unsigned short;
using u32 = unsigned int;

typedef short bf16x8 __attribute__((ext_vector_type(8)));
typedef float f32x4 __attribute__((ext_vector_type(4)));

#define HW 3136
#define IMG 56

__device__ __forceinline__ float bf2f(u16 v) {
    union { u32 u; float f; } c; c.u = ((u32)v) << 16; return c.f;
}
__device__ __forceinline__ u16 f2bf(float f) {
    union { float f; u32 u; } c; c.f = f;
    return (u16)((c.u + 0x7fffu + ((c.u >> 16) & 1u)) >> 16);
}
// pack 2 f32 -> 2 bf16 in one u32 (RNE, hardware cvt)
__device__ __forceinline__ u32 pk2bf(float a, float b) {
    u32 r;
    asm("v_cvt_pk_bf16_f32 %0, %1, %2" : "=v"(r) : "v"(a), "v"(b));
    return r;
}
__device__ __forceinline__ int swz8(int r) { return (r ^ (r >> 3)) & 7; }

__device__ __forceinline__ f32x4 mfma16(bf16x8 a, bf16x8 b, f32x4 c) {
    return __builtin_amdgcn_mfma_f32_16x16x32_bf16(a, b, c, 0, 0, 0);
}

// async global->LDS, 16B per lane; dest = lds_base + lane*16 (wave-uniform base)
__device__ __forceinline__ void gl_lds(const void* g, void* l) {
    __builtin_amdgcn_global_load_lds((const __attribute__((address_space(1))) void*)g,
                                     (__attribute__((address_space(3))) void*)l, 16, 0, 0);
}

// ---------------------------------------------------------------------------
// wcvt: weights f32->bf16 into Wb; concat biases f32 into Bc.
// Wb: xq|xk|xv (196608) yq|yk|yv (196608) xp(65536) yp(65536) cp(65536)
//     m1(131072) m2(131072)   total 851968 elems
// Bc: qkv x|y (3072) xp(128) yp(128) cp(256) m1(512) m2(256) = 4352
// ---------------------------------------------------------------------------
__global__ __launch_bounds__(256) void wcvt(
    const float* __restrict__ s0, const float* __restrict__ s1, const float* __restrict__ s2,
    const float* __restrict__ s3, const float* __restrict__ s4, const float* __restrict__ s5,
    const float* __restrict__ s6, const float* __restrict__ s7, const float* __restrict__ s8,
    const float* __restrict__ s9, const float* __restrict__ s10,
    const float* __restrict__ b0, const float* __restrict__ b1, const float* __restrict__ b2,
    const float* __restrict__ b3, const float* __restrict__ b4, const float* __restrict__ b5,
    const float* __restrict__ b6, const float* __restrict__ b7, const float* __restrict__ b8,
    const float* __restrict__ b9, const float* __restrict__ b10,
    u16* __restrict__ Wb, float* __restrict__ Bc)
{
    const int tid = threadIdx.x;
    if (blockIdx.x == 832) {   // biases
        for (int i = tid; i < 4352; i += 256) {
            const float* src; int off;
            if      (i < 512)  { src = b0;  off = i; }
            else if (i < 1024) { src = b1;  off = i - 512; }
            else if (i < 1536) { src = b2;  off = i - 1024; }
            else if (i < 2048) { src = b3;  off = i - 1536; }
            else if (i < 2560) { src = b4;  off = i - 2048; }
            else if (i < 3072) { src = b5;  off = i - 2560; }
            else if (i < 3200) { src = b6;  off = i - 3072; }
            else if (i < 3328) { src = b7;  off = i - 3200; }
            else if (i < 3584) { src = b8;  off = i - 3328; }
            else if (i < 4096) { src = b9;  off = i - 3584; }
            else               { src = b10; off = i - 4096; }
            Bc[i] = src[off];
        }
        return;
    }
    long gid4 = ((long)blockIdx.x * 256 + tid) * 4;
    const float* src; long off;
    if (gid4 < 589824) {
        int seg = (int)(gid4 >> 16);
        const float* tab[9] = { s0, s1, s2, s3, s4, s5, s6, s7, s8 };
        src = tab[seg]; off = gid4 - ((long)seg << 16);
    } else if (gid4 < 720896) { src = s9;  off = gid4 - 589824; }
    else                      { src = s10; off = gid4 - 720896; }
    float4 v = *(const float4*)(src + off);
    *(uint2*)(Wb + gid4) = make_uint2(pk2bf(v.x, v.y), pk2bf(v.z, v.w));
}

// ---------------------------------------------------------------------------
// transpose_x: x [b][256][HW] f32  ->  Xt [b][HW][256] bf16
// ---------------------------------------------------------------------------
__global__ __launch_bounds__(256) void transpose_x(
    const float* __restrict__ x, u16* __restrict__ Xt)
{
    __shared__ u16 lds[64][80];
    const int t = threadIdx.x;
    const int Pb = blockIdx.x * 64;
    const int Cb = blockIdx.y * 64;
    const int b  = blockIdx.z;

    #pragma unroll
    for (int q = 0; q < 4; ++q) {
        int id = t + q * 256;
        int c = id >> 4, pf = (id & 15) * 4;
        float4 v = *(const float4*)(x + ((long)(b * 256 + Cb + c)) * HW + Pb + pf);
        u16 vv[4] = { f2bf(v.x), f2bf(v.y), f2bf(v.z), f2bf(v.w) };
        #pragma unroll
        for (int j = 0; j < 4; ++j) {
            int p = pf + j;
            int cc = (((c >> 3) ^ ((p >> 2) & 7)) << 3) + (c & 7);
            lds[p][cc] = vv[j];
        }
    }
    __syncthreads();
    int p = t >> 2, cf = (t & 3) * 16;
    u16* dst = Xt + ((long)b * HW + Pb + p) * 256 + Cb + cf;
    int cc0 = ((cf >> 3) + 0) ^ ((p >> 2) & 7);
    int cc1 = ((cf >> 3) + 1) ^ ((p >> 2) & 7);
    *(uint4*)(dst + 0) = *(uint4*)&lds[p][cc0 * 8];
    *(uint4*)(dst + 8) = *(uint4*)&lds[p][cc1 * 8];
}

// ---------------------------------------------------------------------------
// fused_attn: QKV projection + axial attention. Swapped QK (S^T = K*Q),
// in-register softmax, permuted-V PV, round-6/12 grid geometry (512 blocks,
// bid%8 = row-group -> per-XCD L2 partition). X fragments read per-lane
// DIRECTLY from global (L2-resident at this geometry; round 6: 9.5 MB FETCH)
// -> no gl_lds vmcnt drain in the row chain, 16KB less LDS, fewer LDS ops.
// LDS: QT[0,16K) KT[16K,32K) V[32K,48K) RELf32[49152,49664).
// ---------------------------------------------------------------------------
__global__ __launch_bounds__(256, 3) void fused_attn(
    const u16* __restrict__ Wb, const float* __restrict__ Bc,
    const u16* __restrict__ Xt,
    const float* __restrict__ rel_x, const float* __restrict__ rel_y,
    u16* __restrict__ SbX, u16* __restrict__ SbY)
{
    __shared__ __align__(16) char smem[49664];
    const int tid = threadIdx.x;
    const int lane = tid & 63, wid = tid >> 6;
    const int l15 = lane & 15, lg = lane >> 4;

    const int g = blockIdx.x;            // 8 groups of 7 rows; bid%8 = g -> XCD partition
    const int n = blockIdx.y;            // head
    const int branch = blockIdx.z >> 3;
    const int b = blockIdx.z & 7;

    const float* rel = branch ? rel_y : rel_x;
    u16* S = branch ? SbY : SbX;
    const u16* wsrc = Wb + branch * 196608 + n * 16384;   // + mat*65536
    const float* bsrc = Bc + branch * 1536 + n * 128;     // + mat*512

    if (tid < 128) {
        float v = (tid < 112) ? rel[n * HW + tid] : 0.0f;
        *(float*)(smem + 49152 + tid * 4) = v;
    }

    bf16x8 wf[3][2][4];
    #pragma unroll
    for (int mat = 0; mat < 3; ++mat)
        #pragma unroll
        for (int mt = 0; mt < 2; ++mt) {
            int mrow = (wid * 2 + mt) * 16 + l15;
            const u16* wr = wsrc + mat * 65536 + mrow * 128;
            #pragma unroll
            for (int ks = 0; ks < 4; ++ks)
                wf[mat][mt][ks] = *(const bf16x8*)(wr + (ks * 4 + lg) * 8);
        }
    float4 bq4[2], bk4[2]; float bvv[2];
    #pragma unroll
    for (int mt = 0; mt < 2; ++mt) {
        int m0 = (wid * 2 + mt) * 16 + lg * 4;
        bq4[mt] = *(const float4*)(bsrc + m0);
        bk4[mt] = *(const float4*)(bsrc + 512 + m0);
        bvv[mt] = bsrc[1024 + (wid * 2 + mt) * 16 + l15];
    }

    const int istrip = wid * 16;
    const float qscale = 0.08838834764831845f;

    for (int r = 0; r < 7; ++r) {
        const int rc = g * 7 + r;

        // ---- X fragments directly from global (row i on l15, k-chunk on lg)
        bf16x8 xf[4][4];
        #pragma unroll
        for (int it = 0; it < 4; ++it) {
            int i = it * 16 + l15; if (i > 55) i = 55;
            long p = (branch == 0) ? (long)rc * IMG + i : (long)i * IMG + rc;
            const u16* xr = Xt + ((long)b * HW + p) * 256 + branch * 128;
            #pragma unroll
            for (int ks = 0; ks < 4; ++ks)
                xf[it][ks] = *(const bf16x8*)(xr + (ks * 4 + lg) * 8);
        }
        __syncthreads();   // previous row's Q/K/V LDS reads done

        // ---- Q (mat0), K (mat1): D[m][i] -> QT/KT [i][c]
        #pragma unroll
        for (int mat = 0; mat < 2; ++mat) {
            #pragma unroll
            for (int mt = 0; mt < 2; ++mt) {
                #pragma unroll
                for (int it = 0; it < 4; ++it) {
                    f32x4 a = {};
                    #pragma unroll
                    for (int ks = 0; ks < 4; ++ks)
                        a = mfma16(wf[mat][mt][ks], xf[it][ks], a);
                    int i = it * 16 + l15;
                    int m0 = (wid * 2 + mt) * 16 + lg * 4;
                    float4 bb2 = mat ? bk4[mt] : bq4[mt];
                    int c = m0 >> 3;
                    *(uint2*)(smem + mat * 16384 + i * 256 + ((c ^ swz8(i)) * 16) + (lg & 1) * 8)
                        = make_uint2(pk2bf(a[0] + bb2.x, a[1] + bb2.y),
                                     pk2bf(a[2] + bb2.z, a[3] + bb2.w));
                }
            }
        }
        // ---- V (mat2): D[j][d] -> V LDS rows d, permuted j-order
        //   j = it*16 + lg*4 + rr  ->  slot = (it>>1)*32 + lg*8 + (it&1)*4 + rr
        #pragma unroll
        for (int mt = 0; mt < 2; ++mt) {
            #pragma unroll
            for (int it = 0; it < 4; ++it) {
                f32x4 a = {};
                #pragma unroll
                for (int ks = 0; ks < 4; ++ks)
                    a = mfma16(xf[it][ks], wf[2][mt][ks], a);
                int d = (wid * 2 + mt) * 16 + l15;
                int c2 = (it >> 1) * 4 + lg;
                float bv = bvv[mt];
                *(uint2*)(smem + 32768 + d * 128 + ((c2 ^ swz8(d)) * 16) + (it & 1) * 8)
                    = make_uint2(pk2bf(a[0] + bv, a[1] + bv),
                                 pk2bf(a[2] + bv, a[3] + bv));
            }
        }
        __syncthreads();

        // ---- S^T = K*Q : lane holds S[j = ct*16+lg*4+reg][i = istrip+l15]
        bf16x8 aq[4];
        #pragma unroll
        for (int ks = 0; ks < 4; ++ks) {
            int row = istrip + l15;
            int ch = ks * 4 + lg;
            aq[ks] = *(const bf16x8*)(smem + row * 256 + ((ch ^ swz8(row)) * 16));
        }
        f32x4 sacc[4] = {};
        #pragma unroll
        for (int ct = 0; ct < 4; ++ct) {
            #pragma unroll
            for (int ks = 0; ks < 4; ++ks) {
                int j = ct * 16 + l15;
                int ch = ks * 4 + lg;
                bf16x8 kb = *(const bf16x8*)(smem + 16384 + j * 256 + ((ch ^ swz8(j)) * 16));
                sacc[ct] = mfma16(kb, aq[ks], sacc[ct]);
            }
        }

        // ---- softmax fully in-register (row i = istrip+l15 on 4 lanes lg)
        const int irow = istrip + l15;
        float p[4][4];
        float mx = -1e30f;
        #pragma unroll
        for (int ct = 0; ct < 4; ++ct)
            #pragma unroll
            for (int rr = 0; rr < 4; ++rr) {
                int j = ct * 16 + lg * 4 + rr;
                float x = sacc[ct][rr] * qscale;
                if (j < IMG) x += *(const float*)(smem + 49152 + (irow - j + 55) * 4);
                else x = -1e30f;
                p[ct][rr] = x;
                mx = fmaxf(mx, x);
            }
        mx = fmaxf(mx, __shfl_xor(mx, 16));
        mx = fmaxf(mx, __shfl_xor(mx, 32));
        float s0 = 0.f;
        #pragma unroll
        for (int ct = 0; ct < 4; ++ct)
            #pragma unroll
            for (int rr = 0; rr < 4; ++rr) {
                float e = __expf(p[ct][rr] - mx);
                p[ct][rr] = e; s0 += e;
            }
        s0 += __shfl_xor(s0, 16);
        s0 += __shfl_xor(s0, 32);
        float inv = 1.0f / s0;

        // ---- pack P into PV B-fragments (matches V's permuted LDS layout)
        union { u32 u[4]; bf16x8 v; } pb[2];
        #pragma unroll
        for (int ks = 0; ks < 2; ++ks) {
            pb[ks].u[0] = pk2bf(p[2*ks][0] * inv, p[2*ks][1] * inv);
            pb[ks].u[1] = pk2bf(p[2*ks][2] * inv, p[2*ks][3] * inv);
            pb[ks].u[2] = pk2bf(p[2*ks+1][0] * inv, p[2*ks+1][1] * inv);
            pb[ks].u[3] = pk2bf(p[2*ks+1][2] * inv, p[2*ks+1][3] * inv);
        }

        // ---- O = V*P : D[d][i], thread holds 4 consecutive d at fixed i
        f32x4 oacc[8] = {};
        #pragma unroll
        for (int dt = 0; dt < 8; ++dt) {
            #pragma unroll
            for (int ks = 0; ks < 2; ++ks) {
                int d = dt * 16 + l15;
                int c2 = ks * 4 + lg;
                bf16x8 vb = *(const bf16x8*)(smem + 32768 + d * 128 + ((c2 ^ swz8(d)) * 16));
                oacc[dt] = mfma16(vb, pb[ks].v, oacc[dt]);
            }
        }

        // ---- store p-major scrambled Sb, packed 8B
        const int i = istrip + l15;
        if (i < IMG) {
            int im = n * 14 + (i >> 2);
            long pp = (branch == 0) ? (long)rc * IMG + im : (long)im * IMG + rc;
            u16* dst = S + ((long)b * HW + pp) * 512 + (i & 3) * 128;
            #pragma unroll
            for (int dt = 0; dt < 8; ++dt) {
                int d4 = dt * 16 + lg * 4;
                *(uint2*)(dst + d4) = make_uint2(pk2bf(oacc[dt][0], oacc[dt][1]),
                                                 pk2bf(oacc[dt][2], oacc[dt][3]));
            }
        }
    }
}

// ---------------------------------------------------------------------------
// opcp: fused out-projection (X and Y) + cp conv per 64-row p-tile.
// ---------------------------------------------------------------------------
__global__ __launch_bounds__(256, 2) void opcp(
    const u16* __restrict__ Wb, const float* __restrict__ Bc,
    const u16* __restrict__ SbX, const u16* __restrict__ SbY,
    const u16* __restrict__ Xt, const float* __restrict__ ls1,
    u16* __restrict__ NETp)
{
    __shared__ __align__(16) char smem[81920];
    const int tid = threadIdx.x;
    const int lane = tid & 63, wid = tid >> 6;
    const int l15 = lane & 15, lg = lane >> 4;
    const int P0 = blockIdx.x * 64;      // 49 tiles, exact
    const int b  = blockIdx.z;

    const u16* xp = Wb + 393216;
    const u16* yp = Wb + 458752;
    const u16* cpw = Wb + 524288;

    f32x4 acc[4][4] = {};

    // ---- stage1: K=512 over SbX/SbY
    for (int ko = 0; ko < 512; ko += 64) {
        #pragma unroll
        for (int t = 0; t < 2; ++t) {
            int row = wid * 16 + t * 8 + (lane >> 3);
            int c = (lane & 7) ^ swz8(row);
            long prow = (long)b * HW + P0 + row;
            gl_lds(SbX + prow * 512 + ko + c * 8, smem + wid * 2048 + t * 1024);
            gl_lds(SbY + prow * 512 + ko + c * 8, smem + 8192 + wid * 2048 + t * 1024);
        }
        #pragma unroll
        for (int t = 0; t < 4; ++t) {
            int row = wid * 32 + t * 8 + (lane >> 3);
            int c = (lane & 7) ^ swz8(row);
            gl_lds(xp + (long)row * 512 + ko + c * 8, smem + 16384 + wid * 4096 + t * 1024);
            gl_lds(yp + (long)row * 512 + ko + c * 8, smem + 32768 + wid * 4096 + t * 1024);
        }
        __syncthreads();

        const int actb = (wid < 2) ? 0 : 8192;
        const int wbse = (wid < 2) ? 16384 : 32768;
        const int wrow0 = (wid & 1) * 64;
        #pragma unroll
        for (int ks = 0; ks < 2; ++ks) {
            int ch = ks * 4 + lg;
            bf16x8 af[4], bfr[4];
            #pragma unroll
            for (int rt = 0; rt < 4; ++rt) {
                int row = rt * 16 + l15;
                af[rt] = *(const bf16x8*)(smem + actb + row * 128 + ((ch ^ swz8(row)) * 16));
            }
            #pragma unroll
            for (int ct = 0; ct < 4; ++ct) {
                int row = wrow0 + ct * 16 + l15;
                bfr[ct] = *(const bf16x8*)(smem + wbse + row * 128 + ((ch ^ swz8(row)) * 16));
            }
            #pragma unroll
            for (int rt = 0; rt < 4; ++rt)
                #pragma unroll
                for (int ct = 0; ct < 4; ++ct)
                    acc[rt][ct] = mfma16(bfr[ct], af[rt], acc[rt][ct]);
        }
        __syncthreads();
    }

    // ---- stage1 epilogue -> AXY LDS (rows 512B, 16B-chunk low-3 XOR swizzle)
    #pragma unroll
    for (int rt = 0; rt < 4; ++rt) {
        int pl = rt * 16 + l15;
        long rowp = (long)b * HW + P0 + pl;
        #pragma unroll
        for (int ct = 0; ct < 4; ++ct) {
            int mg2 = wid * 64 + ct * 16 + lg * 4;
            float4 bv = *(const float4*)(Bc + 3072 + mg2);
            ushort4 rv = *(const ushort4*)(Xt + rowp * 256 + mg2);
            float v0 = acc[rt][ct][0] + bv.x + bf2f(rv.x);
            float v1 = acc[rt][ct][1] + bv.y + bf2f(rv.y);
            float v2 = acc[rt][ct][2] + bv.z + bf2f(rv.z);
            float v3 = acc[rt][ct][3] + bv.w + bf2f(rv.w);
            int cc = mg2 >> 3;
            int pos = (cc & 24) | ((cc ^ swz8(pl)) & 7);
            *(uint2*)(smem + 49152 + pl * 512 + pos * 16 + (mg2 & 7) * 2)
                = make_uint2(pk2bf(v0, v1), pk2bf(v2, v3));
        }
    }
    __syncthreads();

    // ---- stage2: cp K=256, act = AXY LDS
    f32x4 acc2[4][4] = {};
    for (int ko = 0; ko < 256; ko += 64) {
        #pragma unroll
        for (int t = 0; t < 8; ++t) {
            int row = wid * 64 + t * 8 + (lane >> 3);
            int c = (lane & 7) ^ swz8(row);
            gl_lds(cpw + (long)row * 256 + ko + c * 8, smem + 16384 + wid * 8192 + t * 1024);
        }
        __syncthreads();

        #pragma unroll
        for (int ks = 0; ks < 2; ++ks) {
            int ch = ks * 4 + lg;
            bf16x8 af[4], bfr[4];
            #pragma unroll
            for (int rt = 0; rt < 4; ++rt) {
                int row = rt * 16 + l15;
                int c = (ko >> 3) + ch;
                int pos = (c & 24) | ((c ^ swz8(row)) & 7);
                af[rt] = *(const bf16x8*)(smem + 49152 + row * 512 + pos * 16);
            }
            #pragma unroll
            for (int ct = 0; ct < 4; ++ct) {
                int row = wid * 64 + ct * 16 + l15;
                bfr[ct] = *(const bf16x8*)(smem + 16384 + row * 128 + ((ch ^ swz8(row)) * 16));
            }
            #pragma unroll
            for (int rt = 0; rt < 4; ++rt)
                #pragma unroll
                for (int ct = 0; ct < 4; ++ct)
                    acc2[rt][ct] = mfma16(bfr[ct], af[rt], acc2[rt][ct]);
        }
        __syncthreads();
    }

    // ---- stage2 epilogue: ls1 scale + Xt residual -> NETp global
    #pragma unroll
    for (int rt = 0; rt < 4; ++rt) {
        int pl = rt * 16 + l15;
        long rowp = (long)b * HW + P0 + pl;
        #pragma unroll
        for (int ct = 0; ct < 4; ++ct) {
            int mg = wid * 64 + ct * 16 + lg * 4;
            float4 bv = *(const float4*)(Bc + 3328 + mg);
            float4 sv = *(const float4*)(ls1 + mg);
            ushort4 rv = *(const ushort4*)(Xt + rowp * 256 + mg);
            float v0 = (acc2[rt][ct][0] + bv.x) * sv.x + bf2f(rv.x);
            float v1 = (acc2[rt][ct][1] + bv.y) * sv.y + bf2f(rv.y);
            float v2 = (acc2[rt][ct][2] + bv.z) * sv.z + bf2f(rv.z);
            float v3 = (acc2[rt][ct][3] + bv.w) * sv.w + bf2f(rv.w);
            *(uint2*)(NETp + rowp * 256 + mg) = make_uint2(pk2bf(v0, v1), pk2bf(v2, v3));
        }
    }
}

// ---------------------------------------------------------------------------
// mlp: fused m1 (+GELU) + m2 per 64-row p-tile; hidden in 4 LDS chunks.
// ---------------------------------------------------------------------------
__global__ __launch_bounds__(256, 2) void mlp(
    const u16* __restrict__ Wb, const float* __restrict__ Bc,
    const u16* __restrict__ NETp, const float* __restrict__ ls2,
    u16* __restrict__ OUTp)
{
    __shared__ __align__(16) char smem[81920];
    const int tid = threadIdx.x;
    const int lane = tid & 63, wid = tid >> 6;
    const int l15 = lane & 15, lg = lane >> 4;
    const int P0 = blockIdx.x * 64;
    const int b  = blockIdx.z;

    const u16* m1w = Wb + 589824;
    const u16* m2w = Wb + 720896;

    // ---- stage NET tile [64][256ch] into LDS (inverse-swizzled source)
    #pragma unroll
    for (int t = 0; t < 8; ++t) {
        int row = wid * 16 + t * 2 + (lane >> 5);
        int cc = lane & 31;
        int sc = (cc & 24) | ((cc ^ swz8(row)) & 7);
        gl_lds(NETp + ((long)b * HW + P0 + row) * 256 + sc * 8,
               smem + wid * 8192 + t * 1024);
    }

    f32x4 aco[4][4] = {};

    for (int hc = 0; hc < 4; ++hc) {
        // ---- m1 chunk: H[64p][128h] = gelu(m1W[hc] @ NET + b)
        f32x4 ach[4][2] = {};
        for (int ko = 0; ko < 256; ko += 64) {
            #pragma unroll
            for (int t = 0; t < 4; ++t) {
                int row = wid * 32 + t * 8 + (lane >> 3);
                int c = (lane & 7) ^ swz8(row);
                gl_lds(m1w + (long)(hc * 128 + row) * 256 + ko + c * 8,
                       smem + 49152 + wid * 4096 + t * 1024);
            }
            __syncthreads();

            #pragma unroll
            for (int ks = 0; ks < 2; ++ks) {
                int ch = ks * 4 + lg;
                bf16x8 af[4], bfrh[2];
                #pragma unroll
                for (int rt = 0; rt < 4; ++rt) {
                    int row = rt * 16 + l15;
                    int c = (ko >> 3) + ch;
                    int pos = (c & 24) | ((c ^ swz8(row)) & 7);
                    af[rt] = *(const bf16x8*)(smem + row * 512 + pos * 16);
                }
                #pragma unroll
                for (int mt = 0; mt < 2; ++mt) {
                    int row = wid * 32 + mt * 16 + l15;
                    bfrh[mt] = *(const bf16x8*)(smem + 49152 + row * 128 + ((ch ^ swz8(row)) * 16));
                }
                #pragma unroll
                for (int rt = 0; rt < 4; ++rt)
                    #pragma unroll
                    for (int mt = 0; mt < 2; ++mt)
                        ach[rt][mt] = mfma16(bfrh[mt], af[rt], ach[rt][mt]);
            }
            __syncthreads();
        }
        // H epilogue -> H LDS (rows 256B, low-3 XOR on 16B-chunk index)
        #pragma unroll
        for (int rt = 0; rt < 4; ++rt) {
            int pl = rt * 16 + l15;
            #pragma unroll
            for (int mt = 0; mt < 2; ++mt) {
                int hloc = wid * 32 + mt * 16 + lg * 4;
                float4 bv = *(const float4*)(Bc + 3584 + hc * 128 + hloc);
                float v[4];
                #pragma unroll
                for (int j = 0; j < 4; ++j) {
                    float tt = ach[rt][mt][j] + ((const float*)&bv)[j];
                    v[j] = tt * 0.5f * (1.0f + erff(tt * 0.70710678118f));
                }
                int cc = hloc >> 3;
                int pos = (cc & 8) | ((cc ^ swz8(pl)) & 7);
                *(uint2*)(smem + 32768 + pl * 256 + pos * 16 + (hloc & 7) * 2)
                    = make_uint2(pk2bf(v[0], v[1]), pk2bf(v[2], v[3]));
            }
        }

        // ---- m2 partial: aco += m2W[:, hc*128..] @ H
        for (int ko = 0; ko < 128; ko += 64) {
            #pragma unroll
            for (int t = 0; t < 8; ++t) {
                int row = wid * 64 + t * 8 + (lane >> 3);
                int c = (lane & 7) ^ swz8(row);
                gl_lds(m2w + (long)row * 512 + hc * 128 + ko + c * 8,
                       smem + 49152 + wid * 8192 + t * 1024);
            }
            __syncthreads();

            #pragma unroll
            for (int ks = 0; ks < 2; ++ks) {
                int ch = ks * 4 + lg;
                bf16x8 af[4], bfr[4];
                #pragma unroll
                for (int rt = 0; rt < 4; ++rt) {
                    int row = rt * 16 + l15;
                    int c = (ko >> 3) + ch;
                    int pos = (c & 8) | ((c ^ swz8(row)) & 7);
                    af[rt] = *(const bf16x8*)(smem + 32768 + row * 256 + pos * 16);
                }
                #pragma unroll
                for (int ct = 0; ct < 4; ++ct) {
                    int row = wid * 64 + ct * 16 + l15;
                    bfr[ct] = *(const bf16x8*)(smem + 49152 + row * 128 + ((ch ^ swz8(row)) * 16));
                }
                #pragma unroll
                for (int rt = 0; rt < 4; ++rt)
                    #pragma unroll
                    for (int ct = 0; ct < 4; ++ct)
                        aco[rt][ct] = mfma16(bfr[ct], af[rt], aco[rt][ct]);
            }
            __syncthreads();
        }
    }

    // ---- final epilogue: +b2, *ls2, + NET residual (from LDS) -> OUTp
    #pragma unroll
    for (int rt = 0; rt < 4; ++rt) {
        int pl = rt * 16 + l15;
        long rowp = (long)b * HW + P0 + pl;
        #pragma unroll
        for (int ct = 0; ct < 4; ++ct) {
            int mg = wid * 64 + ct * 16 + lg * 4;
            float4 bv = *(const float4*)(Bc + 4096 + mg);
            float4 sv = *(const float4*)(ls2 + mg);
            int cc = mg >> 3;
            int pos = (cc & 24) | ((cc ^ swz8(pl)) & 7);
            uint2 nv2 = *(const uint2*)(smem + pl * 512 + pos * 16 + (mg & 7) * 2);
            u16 nv[4] = { (u16)(nv2.x & 0xffff), (u16)(nv2.x >> 16),
                          (u16)(nv2.y & 0xffff), (u16)(nv2.y >> 16) };
            float v0 = (aco[rt][ct][0] + bv.x) * sv.x + bf2f(nv[0]);
            float v1 = (aco[rt][ct][1] + bv.y) * sv.y + bf2f(nv[1]);
            float v2 = (aco[rt][ct][2] + bv.z) * sv.z + bf2f(nv[2]);
            float v3 = (aco[rt][ct][3] + bv.w) * sv.w + bf2f(nv[3]);
            *(uint2*)(OUTp + rowp * 256 + mg) = make_uint2(pk2bf(v0, v1), pk2bf(v2, v3));
        }
    }
}

// ---------------------------------------------------------------------------
// fuse_out: d_out[b][c][p] (f32, m-major) = OUTp[b][p][c] (bf16, p-major)
// ---------------------------------------------------------------------------
__global__ __launch_bounds__(256) void fuse_out(
    const u16* __restrict__ OUTp, float* __restrict__ y)
{
    __shared__ float lds[32][132];
    const int t = threadIdx.x;
    const int Pb = blockIdx.x * 128;
    const int Cb = blockIdx.y * 32;
    const int b  = blockIdx.z;

    #pragma unroll
    for (int q = 0; q < 4; ++q) {
        int id = t + q * 256;
        int p = id >> 3, cq = (id & 7) * 4;
        int pg = Pb + p;
        float4 v = make_float4(0.f, 0.f, 0.f, 0.f);
        if (pg < HW) {
            ushort4 nv = *(const ushort4*)(OUTp + ((long)b * HW + pg) * 256 + Cb + cq);
            v.x = bf2f(nv.x); v.y = bf2f(nv.y); v.z = bf2f(nv.z); v.w = bf2f(nv.w);
        }
        lds[cq + 0][p] = v.x; lds[cq + 1][p] = v.y;
        lds[cq + 2][p] = v.z; lds[cq + 3][p] = v.w;
    }
    __syncthreads();
    #pragma unroll
    for (int q = 0; q < 4; ++q) {
        int id = t + q * 256;
        int c = id >> 5, pq = (id & 31) * 4;
        int pg = Pb + pq;
        if (pg + 3 < HW) {
            float4 v = make_float4(lds[c][pq], lds[c][pq + 1], lds[c][pq + 2], lds[c][pq + 3]);
            *(float4*)(y + ((long)(b * 256 + Cb + c)) * HW + pg) = v;
        }
    }
}

// ---------------------------------------------------------------------------
extern "C" void kernel_launch(void* const* d_in, const int* in_sizes, int n_in,
                              void* d_out, int out_size, void* d_ws, size_t ws_size,
                              hipStream_t stream)
{
    const float* x     = (const float*)d_in[0];
    const float* xq_w  = (const float*)d_in[1];
    const float* xq_b  = (const float*)d_in[2];
    const float* xk_w  = (const float*)d_in[3];
    const float* xk_b  = (const float*)d_in[4];
    const float* xv_w  = (const float*)d_in[5];
    const float* xv_b  = (const float*)d_in[6];
    const float* xp_w  = (const float*)d_in[7];
    const float* xp_b  = (const float*)d_in[8];
    const float* rel_x = (const float*)d_in[9];
    const float* yq_w  = (const float*)d_in[10];
    const float* yq_b  = (const float*)d_in[11];
    const float* yk_w  = (const float*)d_in[12];
    const float* yk_b  = (const float*)d_in[13];
    const float* yv_w  = (const float*)d_in[14];
    const float* yv_b  = (const float*)d_in[15];
    const float* yp_w  = (const float*)d_in[16];
    const float* yp_b  = (const float*)d_in[17];
    const float* rel_y = (const float*)d_in[18];
    const float* cp_w  = (const float*)d_in[19];
    const float* cp_b  = (const float*)d_in[20];
    const float* m1_w  = (const float*)d_in[21];
    const float* m1_b  = (const float*)d_in[22];
    const float* m2_w  = (const float*)d_in[23];
    const float* m2_b  = (const float*)d_in[24];
    const float* ls1   = (const float*)d_in[25];
    const float* ls2   = (const float*)d_in[26];

    if (ws_size < 128450560) return;

    char* ws = (char*)d_ws;
    u16*   SbY  = (u16*)(ws + 0);            // [8][3136][512] bf16
    u16*   OUTp = (u16*)(ws + 25690112);     // [8][3136][256] bf16
    u16*   Xt   = (u16*)(ws + 77070336);     // [8][3136][256] bf16
    u16*   SbX  = (u16*)(ws + 89915392);     // [8][3136][512] bf16
    u16*   NETp = (u16*)(ws + 115605504);    // [8][3136][256] bf16

    // weights/biases in d_out scratch (fully overwritten by fuse_out at the end)
    u16*   Wb = (u16*)d_out;                      // 851968 bf16 = 1,703,936 B
    float* Bc = (float*)((char*)d_out + 1703936); // 4352 f32

    dim3 blk(256, 1, 1);

    wcvt<<<dim3(833, 1, 1), blk, 0, stream>>>(
        xq_w, xk_w, xv_w, yq_w, yk_w, yv_w, xp_w, yp_w, cp_w, m1_w, m2_w,
        xq_b, xk_b, xv_b, yq_b, yk_b, yv_b, xp_b, yp_b, cp_b, m1_b, m2_b,
        Wb, Bc);
    transpose_x<<<dim3(49, 4, 8), blk, 0, stream>>>(x, Xt);
    fused_attn<<<dim3(8, 4, 16), blk, 0, stream>>>(Wb, Bc, Xt, rel_x, rel_y, SbX, SbY);
    // out-proj X+Y + cp fused -> NETp
    opcp<<<dim3(49, 1, 8), blk, 0, stream>>>(Wb, Bc, SbX, SbY, Xt, ls1, NETp);
    // m1 + GELU + m2 fused -> OUTp
    mlp<<<dim3(49, 1, 8), blk, 0, stream>>>(Wb, Bc, NETp, ls2, OUTp);
    fuse_out<<<dim3(25, 8, 8), blk, 0, stream>>>(OUTp, (float*)d_out);
}

// Round 15
// 148.192 us; speedup vs baseline: 1.6366x; 1.6366x over previous
//
#include <hip/hip_runtime.h>

using u16 = unsigned short;
using u32 = unsigned int;

typedef short bf16x8 __attribute__((ext_vector_type(8)));
typedef float f32x4 __attribute__((ext_vector_type(4)));

#define HW 3136
#define IMG 56

__device__ __forceinline__ float bf2f(u16 v) {
    union { u32 u; float f; } c; c.u = ((u32)v) << 16; return c.f;
}
__device__ __forceinline__ u16 f2bf(float f) {
    union { float f; u32 u; } c; c.f = f;
    return (u16)((c.u + 0x7fffu + ((c.u >> 16) & 1u)) >> 16);
}
// pack 2 f32 -> 2 bf16 in one u32 (RNE, hardware cvt)
__device__ __forceinline__ u32 pk2bf(float a, float b) {
    u32 r;
    asm("v_cvt_pk_bf16_f32 %0, %1, %2" : "=v"(r) : "v"(a), "v"(b));
    return r;
}
__device__ __forceinline__ int swz8(int r) { return (r ^ (r >> 3)) & 7; }

__device__ __forceinline__ f32x4 mfma16(bf16x8 a, bf16x8 b, f32x4 c) {
    return __builtin_amdgcn_mfma_f32_16x16x32_bf16(a, b, c, 0, 0, 0);
}

// async global->LDS, 16B per lane; dest = lds_base + lane*16 (wave-uniform base)
__device__ __forceinline__ void gl_lds(const void* g, void* l) {
    __builtin_amdgcn_global_load_lds((const __attribute__((address_space(1))) void*)g,
                                     (__attribute__((address_space(3))) void*)l, 16, 0, 0);
}

// ---------------------------------------------------------------------------
// wcvt: weights f32->bf16 into Wb; concat biases f32 into Bc.
// Wb: xq|xk|xv (196608) yq|yk|yv (196608) xp(65536) yp(65536) cp(65536)
//     m1(131072) m2(131072)   total 851968 elems
// Bc: qkv x|y (3072) xp(128) yp(128) cp(256) m1(512) m2(256) = 4352
// ---------------------------------------------------------------------------
__global__ __launch_bounds__(256) void wcvt(
    const float* __restrict__ s0, const float* __restrict__ s1, const float* __restrict__ s2,
    const float* __restrict__ s3, const float* __restrict__ s4, const float* __restrict__ s5,
    const float* __restrict__ s6, const float* __restrict__ s7, const float* __restrict__ s8,
    const float* __restrict__ s9, const float* __restrict__ s10,
    const float* __restrict__ b0, const float* __restrict__ b1, const float* __restrict__ b2,
    const float* __restrict__ b3, const float* __restrict__ b4, const float* __restrict__ b5,
    const float* __restrict__ b6, const float* __restrict__ b7, const float* __restrict__ b8,
    const float* __restrict__ b9, const float* __restrict__ b10,
    u16* __restrict__ Wb, float* __restrict__ Bc)
{
    const int tid = threadIdx.x;
    if (blockIdx.x == 832) {   // biases
        for (int i = tid; i < 4352; i += 256) {
            const float* src; int off;
            if      (i < 512)  { src = b0;  off = i; }
            else if (i < 1024) { src = b1;  off = i - 512; }
            else if (i < 1536) { src = b2;  off = i - 1024; }
            else if (i < 2048) { src = b3;  off = i - 1536; }
            else if (i < 2560) { src = b4;  off = i - 2048; }
            else if (i < 3072) { src = b5;  off = i - 2560; }
            else if (i < 3200) { src = b6;  off = i - 3072; }
            else if (i < 3328) { src = b7;  off = i - 3200; }
            else if (i < 3584) { src = b8;  off = i - 3328; }
            else if (i < 4096) { src = b9;  off = i - 3584; }
            else               { src = b10; off = i - 4096; }
            Bc[i] = src[off];
        }
        return;
    }
    long gid4 = ((long)blockIdx.x * 256 + tid) * 4;
    const float* src; long off;
    if (gid4 < 589824) {
        int seg = (int)(gid4 >> 16);
        const float* tab[9] = { s0, s1, s2, s3, s4, s5, s6, s7, s8 };
        src = tab[seg]; off = gid4 - ((long)seg << 16);
    } else if (gid4 < 720896) { src = s9;  off = gid4 - 589824; }
    else                      { src = s10; off = gid4 - 720896; }
    float4 v = *(const float4*)(src + off);
    *(uint2*)(Wb + gid4) = make_uint2(pk2bf(v.x, v.y), pk2bf(v.z, v.w));
}

// ---------------------------------------------------------------------------
// transpose_x: x [b][256][HW] f32  ->  Xt [b][HW][256] bf16
// ---------------------------------------------------------------------------
__global__ __launch_bounds__(256) void transpose_x(
    const float* __restrict__ x, u16* __restrict__ Xt)
{
    __shared__ u16 lds[64][80];
    const int t = threadIdx.x;
    const int Pb = blockIdx.x * 64;
    const int Cb = blockIdx.y * 64;
    const int b  = blockIdx.z;

    #pragma unroll
    for (int q = 0; q < 4; ++q) {
        int id = t + q * 256;
        int c = id >> 4, pf = (id & 15) * 4;
        float4 v = *(const float4*)(x + ((long)(b * 256 + Cb + c)) * HW + Pb + pf);
        u16 vv[4] = { f2bf(v.x), f2bf(v.y), f2bf(v.z), f2bf(v.w) };
        #pragma unroll
        for (int j = 0; j < 4; ++j) {
            int p = pf + j;
            int cc = (((c >> 3) ^ ((p >> 2) & 7)) << 3) + (c & 7);
            lds[p][cc] = vv[j];
        }
    }
    __syncthreads();
    int p = t >> 2, cf = (t & 3) * 16;
    u16* dst = Xt + ((long)b * HW + Pb + p) * 256 + Cb + cf;
    int cc0 = ((cf >> 3) + 0) ^ ((p >> 2) & 7);
    int cc1 = ((cf >> 3) + 1) ^ ((p >> 2) & 7);
    *(uint4*)(dst + 0) = *(uint4*)&lds[p][cc0 * 8];
    *(uint4*)(dst + 8) = *(uint4*)&lds[p][cc1 * 8];
}

// ---------------------------------------------------------------------------
// fused_attn: QKV projection + axial attention. Round-13 structure (X staged
// via global_load_lds, per-XCD L2 partition grid) + T14 async-STAGE split:
// X(r+1) staged AFTER barrier B (all xf reads of X(r) done) so its latency
// hides under the QK/softmax/PV phase; barrier A of the next iteration
// guarantees completion. LDS: QT[0,16K) KT[16K,32K) V[32K,48K)
// X[49152,65536) RELf32[65536,66048).
// ---------------------------------------------------------------------------
__global__ __launch_bounds__(256, 2) void fused_attn(
    const u16* __restrict__ Wb, const float* __restrict__ Bc,
    const u16* __restrict__ Xt,
    const float* __restrict__ rel_x, const float* __restrict__ rel_y,
    u16* __restrict__ SbX, u16* __restrict__ SbY)
{
    __shared__ __align__(16) char smem[66048];
    const int tid = threadIdx.x;
    const int lane = tid & 63, wid = tid >> 6;
    const int l15 = lane & 15, lg = lane >> 4;

    const int g = blockIdx.x;            // 8 groups of 7 rows; bid%8 = g -> XCD partition
    const int n = blockIdx.y;            // head
    const int branch = blockIdx.z >> 3;
    const int b = blockIdx.z & 7;

    const float* rel = branch ? rel_y : rel_x;
    u16* S = branch ? SbY : SbX;
    const u16* wsrc = Wb + branch * 196608 + n * 16384;   // + mat*65536
    const float* bsrc = Bc + branch * 1536 + n * 128;     // + mat*512

    if (tid < 128) {
        float v = (tid < 112) ? rel[n * HW + tid] : 0.0f;
        *(float*)(smem + 65536 + tid * 4) = v;
    }

    // ---- preload W fragments: [mat][mt][ks]; wave owns m in [32*wid, 32*wid+32)
    bf16x8 wf[3][2][4];
    #pragma unroll
    for (int mat = 0; mat < 3; ++mat)
        #pragma unroll
        for (int mt = 0; mt < 2; ++mt) {
            int mrow = (wid * 2 + mt) * 16 + l15;
            const u16* wr = wsrc + mat * 65536 + mrow * 128;
            #pragma unroll
            for (int ks = 0; ks < 4; ++ks)
                wf[mat][mt][ks] = *(const bf16x8*)(wr + (ks * 4 + lg) * 8);
        }
    float4 bq4[2], bk4[2]; float bvv[2];
    #pragma unroll
    for (int mt = 0; mt < 2; ++mt) {
        int m0 = (wid * 2 + mt) * 16 + lg * 4;
        bq4[mt] = *(const float4*)(bsrc + m0);
        bk4[mt] = *(const float4*)(bsrc + 512 + m0);
        bvv[mt] = bsrc[1024 + (wid * 2 + mt) * 16 + l15];
    }

    const int istrip = wid * 16;
    const float qscale = 0.08838834764831845f;

    // stage X for row rc2 into LDS X region (wave wid -> rows wid*16..+15)
    auto stageX = [&](int rc2) {
        const int i0 = wid * 16 + (lane >> 4);
        #pragma unroll
        for (int t = 0; t < 4; ++t) {
            int i = i0 + t * 4;
            int ic = (i > 55) ? 55 : i;
            long p = (branch == 0) ? (long)rc2 * IMG + ic : (long)ic * IMG + rc2;
            const u16* src = Xt + ((long)b * HW + p) * 256 + branch * 128
                             + (((lane & 15) ^ swz8(i)) * 8);
            gl_lds(src, smem + 49152 + wid * 4096 + t * 1024);
        }
    };

    stageX(g * 7);   // prologue: row 0 of this group

    for (int r = 0; r < 7; ++r) {
        const int rc = g * 7 + r;

        __syncthreads();   // A: X(r) staged (vmcnt drained) + prev QK/PV LDS reads done

        // ---- X fragments from LDS
        bf16x8 xf[4][4];
        #pragma unroll
        for (int it = 0; it < 4; ++it) {
            int i = it * 16 + l15;
            #pragma unroll
            for (int ks = 0; ks < 4; ++ks)
                xf[it][ks] = *(const bf16x8*)(smem + 49152 + i * 256
                                              + (((ks * 4 + lg) ^ swz8(i)) * 16));
        }

        // ---- Q (mat0), K (mat1): D[m][i] -> QT/KT [i][c]
        #pragma unroll
        for (int mat = 0; mat < 2; ++mat) {
            #pragma unroll
            for (int mt = 0; mt < 2; ++mt) {
                #pragma unroll
                for (int it = 0; it < 4; ++it) {
                    f32x4 a = {};
                    #pragma unroll
                    for (int ks = 0; ks < 4; ++ks)
                        a = mfma16(wf[mat][mt][ks], xf[it][ks], a);
                    int i = it * 16 + l15;
                    int m0 = (wid * 2 + mt) * 16 + lg * 4;
                    float4 bb2 = mat ? bk4[mt] : bq4[mt];
                    int c = m0 >> 3;
                    *(uint2*)(smem + mat * 16384 + i * 256 + ((c ^ swz8(i)) * 16) + (lg & 1) * 8)
                        = make_uint2(pk2bf(a[0] + bb2.x, a[1] + bb2.y),
                                     pk2bf(a[2] + bb2.z, a[3] + bb2.w));
                }
            }
        }
        // ---- V (mat2): D[j][d] -> V LDS rows d, permuted j-order
        //   j = it*16 + lg*4 + rr  ->  slot = (it>>1)*32 + lg*8 + (it&1)*4 + rr
        #pragma unroll
        for (int mt = 0; mt < 2; ++mt) {
            #pragma unroll
            for (int it = 0; it < 4; ++it) {
                f32x4 a = {};
                #pragma unroll
                for (int ks = 0; ks < 4; ++ks)
                    a = mfma16(xf[it][ks], wf[2][mt][ks], a);
                int d = (wid * 2 + mt) * 16 + l15;
                int c2 = (it >> 1) * 4 + lg;
                float bv = bvv[mt];
                *(uint2*)(smem + 32768 + d * 128 + ((c2 ^ swz8(d)) * 16) + (it & 1) * 8)
                    = make_uint2(pk2bf(a[0] + bv, a[1] + bv),
                                 pk2bf(a[2] + bv, a[3] + bv));
            }
        }
        __syncthreads();   // B: proj writes visible; all waves' xf reads done -> X free

        if (r < 6) stageX(rc + 1);   // overlaps QK/softmax/PV below (T14)

        // ---- S^T = K*Q : lane holds S[j = ct*16+lg*4+reg][i = istrip+l15]
        bf16x8 aq[4];
        #pragma unroll
        for (int ks = 0; ks < 4; ++ks) {
            int row = istrip + l15;
            int ch = ks * 4 + lg;
            aq[ks] = *(const bf16x8*)(smem + row * 256 + ((ch ^ swz8(row)) * 16));
        }
        f32x4 sacc[4] = {};
        #pragma unroll
        for (int ct = 0; ct < 4; ++ct) {
            #pragma unroll
            for (int ks = 0; ks < 4; ++ks) {
                int j = ct * 16 + l15;
                int ch = ks * 4 + lg;
                bf16x8 kb = *(const bf16x8*)(smem + 16384 + j * 256 + ((ch ^ swz8(j)) * 16));
                sacc[ct] = mfma16(kb, aq[ks], sacc[ct]);
            }
        }

        // ---- softmax fully in-register (row i = istrip+l15 on 4 lanes lg)
        const int irow = istrip + l15;
        float p[4][4];
        float mx = -1e30f;
        #pragma unroll
        for (int ct = 0; ct < 4; ++ct)
            #pragma unroll
            for (int rr = 0; rr < 4; ++rr) {
                int j = ct * 16 + lg * 4 + rr;
                float x = sacc[ct][rr] * qscale;
                if (j < IMG) x += *(const float*)(smem + 65536 + (irow - j + 55) * 4);
                else x = -1e30f;
                p[ct][rr] = x;
                mx = fmaxf(mx, x);
            }
        mx = fmaxf(mx, __shfl_xor(mx, 16));
        mx = fmaxf(mx, __shfl_xor(mx, 32));
        float s0 = 0.f;
        #pragma unroll
        for (int ct = 0; ct < 4; ++ct)
            #pragma unroll
            for (int rr = 0; rr < 4; ++rr) {
                float e = __expf(p[ct][rr] - mx);
                p[ct][rr] = e; s0 += e;
            }
        s0 += __shfl_xor(s0, 16);
        s0 += __shfl_xor(s0, 32);
        float inv = 1.0f / s0;

        // ---- pack P into PV B-fragments (matches V's permuted LDS layout)
        union { u32 u[4]; bf16x8 v; } pb[2];
        #pragma unroll
        for (int ks = 0; ks < 2; ++ks) {
            pb[ks].u[0] = pk2bf(p[2*ks][0] * inv, p[2*ks][1] * inv);
            pb[ks].u[1] = pk2bf(p[2*ks][2] * inv, p[2*ks][3] * inv);
            pb[ks].u[2] = pk2bf(p[2*ks+1][0] * inv, p[2*ks+1][1] * inv);
            pb[ks].u[3] = pk2bf(p[2*ks+1][2] * inv, p[2*ks+1][3] * inv);
        }

        // ---- O = V*P : D[d][i], thread holds 4 consecutive d at fixed i
        f32x4 oacc[8] = {};
        #pragma unroll
        for (int dt = 0; dt < 8; ++dt) {
            #pragma unroll
            for (int ks = 0; ks < 2; ++ks) {
                int d = dt * 16 + l15;
                int c2 = ks * 4 + lg;
                bf16x8 vb = *(const bf16x8*)(smem + 32768 + d * 128 + ((c2 ^ swz8(d)) * 16));
                oacc[dt] = mfma16(vb, pb[ks].v, oacc[dt]);
            }
        }

        // ---- store p-major scrambled Sb, packed 8B
        const int i = istrip + l15;
        if (i < IMG) {
            int im = n * 14 + (i >> 2);
            long pp = (branch == 0) ? (long)rc * IMG + im : (long)im * IMG + rc;
            u16* dst = S + ((long)b * HW + pp) * 512 + (i & 3) * 128;
            #pragma unroll
            for (int dt = 0; dt < 8; ++dt) {
                int d4 = dt * 16 + lg * 4;
                *(uint2*)(dst + d4) = make_uint2(pk2bf(oacc[dt][0], oacc[dt][1]),
                                                 pk2bf(oacc[dt][2], oacc[dt][3]));
            }
        }
    }
}

// ---------------------------------------------------------------------------
// opcp: fused out-projection (X and Y) + cp conv per 64-row p-tile.
// ---------------------------------------------------------------------------
__global__ __launch_bounds__(256, 2) void opcp(
    const u16* __restrict__ Wb, const float* __restrict__ Bc,
    const u16* __restrict__ SbX, const u16* __restrict__ SbY,
    const u16* __restrict__ Xt, const float* __restrict__ ls1,
    u16* __restrict__ NETp)
{
    __shared__ __align__(16) char smem[81920];
    const int tid = threadIdx.x;
    const int lane = tid & 63, wid = tid >> 6;
    const int l15 = lane & 15, lg = lane >> 4;
    const int P0 = blockIdx.x * 64;      // 49 tiles, exact
    const int b  = blockIdx.z;

    const u16* xp = Wb + 393216;
    const u16* yp = Wb + 458752;
    const u16* cpw = Wb + 524288;

    f32x4 acc[4][4] = {};

    // ---- stage1: K=512 over SbX/SbY
    for (int ko = 0; ko < 512; ko += 64) {
        #pragma unroll
        for (int t = 0; t < 2; ++t) {
            int row = wid * 16 + t * 8 + (lane >> 3);
            int c = (lane & 7) ^ swz8(row);
            long prow = (long)b * HW + P0 + row;
            gl_lds(SbX + prow * 512 + ko + c * 8, smem + wid * 2048 + t * 1024);
            gl_lds(SbY + prow * 512 + ko + c * 8, smem + 8192 + wid * 2048 + t * 1024);
        }
        #pragma unroll
        for (int t = 0; t < 4; ++t) {
            int row = wid * 32 + t * 8 + (lane >> 3);
            int c = (lane & 7) ^ swz8(row);
            gl_lds(xp + (long)row * 512 + ko + c * 8, smem + 16384 + wid * 4096 + t * 1024);
            gl_lds(yp + (long)row * 512 + ko + c * 8, smem + 32768 + wid * 4096 + t * 1024);
        }
        __syncthreads();

        const int actb = (wid < 2) ? 0 : 8192;
        const int wbse = (wid < 2) ? 16384 : 32768;
        const int wrow0 = (wid & 1) * 64;
        #pragma unroll
        for (int ks = 0; ks < 2; ++ks) {
            int ch = ks * 4 + lg;
            bf16x8 af[4], bfr[4];
            #pragma unroll
            for (int rt = 0; rt < 4; ++rt) {
                int row = rt * 16 + l15;
                af[rt] = *(const bf16x8*)(smem + actb + row * 128 + ((ch ^ swz8(row)) * 16));
            }
            #pragma unroll
            for (int ct = 0; ct < 4; ++ct) {
                int row = wrow0 + ct * 16 + l15;
                bfr[ct] = *(const bf16x8*)(smem + wbse + row * 128 + ((ch ^ swz8(row)) * 16));
            }
            #pragma unroll
            for (int rt = 0; rt < 4; ++rt)
                #pragma unroll
                for (int ct = 0; ct < 4; ++ct)
                    acc[rt][ct] = mfma16(bfr[ct], af[rt], acc[rt][ct]);
        }
        __syncthreads();
    }

    // ---- stage1 epilogue -> AXY LDS (rows 512B, 16B-chunk low-3 XOR swizzle)
    #pragma unroll
    for (int rt = 0; rt < 4; ++rt) {
        int pl = rt * 16 + l15;
        long rowp = (long)b * HW + P0 + pl;
        #pragma unroll
        for (int ct = 0; ct < 4; ++ct) {
            int mg2 = wid * 64 + ct * 16 + lg * 4;
            float4 bv = *(const float4*)(Bc + 3072 + mg2);
            ushort4 rv = *(const ushort4*)(Xt + rowp * 256 + mg2);
            float v0 = acc[rt][ct][0] + bv.x + bf2f(rv.x);
            float v1 = acc[rt][ct][1] + bv.y + bf2f(rv.y);
            float v2 = acc[rt][ct][2] + bv.z + bf2f(rv.z);
            float v3 = acc[rt][ct][3] + bv.w + bf2f(rv.w);
            int cc = mg2 >> 3;
            int pos = (cc & 24) | ((cc ^ swz8(pl)) & 7);
            *(uint2*)(smem + 49152 + pl * 512 + pos * 16 + (mg2 & 7) * 2)
                = make_uint2(pk2bf(v0, v1), pk2bf(v2, v3));
        }
    }
    __syncthreads();

    // ---- stage2: cp K=256, act = AXY LDS
    f32x4 acc2[4][4] = {};
    for (int ko = 0; ko < 256; ko += 64) {
        #pragma unroll
        for (int t = 0; t < 8; ++t) {
            int row = wid * 64 + t * 8 + (lane >> 3);
            int c = (lane & 7) ^ swz8(row);
            gl_lds(cpw + (long)row * 256 + ko + c * 8, smem + 16384 + wid * 8192 + t * 1024);
        }
        __syncthreads();

        #pragma unroll
        for (int ks = 0; ks < 2; ++ks) {
            int ch = ks * 4 + lg;
            bf16x8 af[4], bfr[4];
            #pragma unroll
            for (int rt = 0; rt < 4; ++rt) {
                int row = rt * 16 + l15;
                int c = (ko >> 3) + ch;
                int pos = (c & 24) | ((c ^ swz8(row)) & 7);
                af[rt] = *(const bf16x8*)(smem + 49152 + row * 512 + pos * 16);
            }
            #pragma unroll
            for (int ct = 0; ct < 4; ++ct) {
                int row = wid * 64 + ct * 16 + l15;
                bfr[ct] = *(const bf16x8*)(smem + 16384 + row * 128 + ((ch ^ swz8(row)) * 16));
            }
            #pragma unroll
            for (int rt = 0; rt < 4; ++rt)
                #pragma unroll
                for (int ct = 0; ct < 4; ++ct)
                    acc2[rt][ct] = mfma16(bfr[ct], af[rt], acc2[rt][ct]);
        }
        __syncthreads();
    }

    // ---- stage2 epilogue: ls1 scale + Xt residual -> NETp global
    #pragma unroll
    for (int rt = 0; rt < 4; ++rt) {
        int pl = rt * 16 + l15;
        long rowp = (long)b * HW + P0 + pl;
        #pragma unroll
        for (int ct = 0; ct < 4; ++ct) {
            int mg = wid * 64 + ct * 16 + lg * 4;
            float4 bv = *(const float4*)(Bc + 3328 + mg);
            float4 sv = *(const float4*)(ls1 + mg);
            ushort4 rv = *(const ushort4*)(Xt + rowp * 256 + mg);
            float v0 = (acc2[rt][ct][0] + bv.x) * sv.x + bf2f(rv.x);
            float v1 = (acc2[rt][ct][1] + bv.y) * sv.y + bf2f(rv.y);
            float v2 = (acc2[rt][ct][2] + bv.z) * sv.z + bf2f(rv.z);
            float v3 = (acc2[rt][ct][3] + bv.w) * sv.w + bf2f(rv.w);
            *(uint2*)(NETp + rowp * 256 + mg) = make_uint2(pk2bf(v0, v1), pk2bf(v2, v3));
        }
    }
}

// ---------------------------------------------------------------------------
// mlp: fused m1 (+GELU) + m2 per 64-row p-tile; hidden in 4 LDS chunks.
// ---------------------------------------------------------------------------
__global__ __launch_bounds__(256, 2) void mlp(
    const u16* __restrict__ Wb, const float* __restrict__ Bc,
    const u16* __restrict__ NETp, const float* __restrict__ ls2,
    u16* __restrict__ OUTp)
{
    __shared__ __align__(16) char smem[81920];
    const int tid = threadIdx.x;
    const int lane = tid & 63, wid = tid >> 6;
    const int l15 = lane & 15, lg = lane >> 4;
    const int P0 = blockIdx.x * 64;
    const int b  = blockIdx.z;

    const u16* m1w = Wb + 589824;
    const u16* m2w = Wb + 720896;

    // ---- stage NET tile [64][256ch] into LDS (inverse-swizzled source)
    #pragma unroll
    for (int t = 0; t < 8; ++t) {
        int row = wid * 16 + t * 2 + (lane >> 5);
        int cc = lane & 31;
        int sc = (cc & 24) | ((cc ^ swz8(row)) & 7);
        gl_lds(NETp + ((long)b * HW + P0 + row) * 256 + sc * 8,
               smem + wid * 8192 + t * 1024);
    }

    f32x4 aco[4][4] = {};

    for (int hc = 0; hc < 4; ++hc) {
        // ---- m1 chunk: H[64p][128h] = gelu(m1W[hc] @ NET + b)
        f32x4 ach[4][2] = {};
        for (int ko = 0; ko < 256; ko += 64) {
            #pragma unroll
            for (int t = 0; t < 4; ++t) {
                int row = wid * 32 + t * 8 + (lane >> 3);
                int c = (lane & 7) ^ swz8(row);
                gl_lds(m1w + (long)(hc * 128 + row) * 256 + ko + c * 8,
                       smem + 49152 + wid * 4096 + t * 1024);
            }
            __syncthreads();

            #pragma unroll
            for (int ks = 0; ks < 2; ++ks) {
                int ch = ks * 4 + lg;
                bf16x8 af[4], bfrh[2];
                #pragma unroll
                for (int rt = 0; rt < 4; ++rt) {
                    int row = rt * 16 + l15;
                    int c = (ko >> 3) + ch;
                    int pos = (c & 24) | ((c ^ swz8(row)) & 7);
                    af[rt] = *(const bf16x8*)(smem + row * 512 + pos * 16);
                }
                #pragma unroll
                for (int mt = 0; mt < 2; ++mt) {
                    int row = wid * 32 + mt * 16 + l15;
                    bfrh[mt] = *(const bf16x8*)(smem + 49152 + row * 128 + ((ch ^ swz8(row)) * 16));
                }
                #pragma unroll
                for (int rt = 0; rt < 4; ++rt)
                    #pragma unroll
                    for (int mt = 0; mt < 2; ++mt)
                        ach[rt][mt] = mfma16(bfrh[mt], af[rt], ach[rt][mt]);
            }
            __syncthreads();
        }
        // H epilogue -> H LDS (rows 256B, low-3 XOR on 16B-chunk index)
        #pragma unroll
        for (int rt = 0; rt < 4; ++rt) {
            int pl = rt * 16 + l15;
            #pragma unroll
            for (int mt = 0; mt < 2; ++mt) {
                int hloc = wid * 32 + mt * 16 + lg * 4;
                float4 bv = *(const float4*)(Bc + 3584 + hc * 128 + hloc);
                float v[4];
                #pragma unroll
                for (int j = 0; j < 4; ++j) {
                    float tt = ach[rt][mt][j] + ((const float*)&bv)[j];
                    v[j] = tt * 0.5f * (1.0f + erff(tt * 0.70710678118f));
                }
                int cc = hloc >> 3;
                int pos = (cc & 8) | ((cc ^ swz8(pl)) & 7);
                *(uint2*)(smem + 32768 + pl * 256 + pos * 16 + (hloc & 7) * 2)
                    = make_uint2(pk2bf(v[0], v[1]), pk2bf(v[2], v[3]));
            }
        }

        // ---- m2 partial: aco += m2W[:, hc*128..] @ H
        for (int ko = 0; ko < 128; ko += 64) {
            #pragma unroll
            for (int t = 0; t < 8; ++t) {
                int row = wid * 64 + t * 8 + (lane >> 3);
                int c = (lane & 7) ^ swz8(row);
                gl_lds(m2w + (long)row * 512 + hc * 128 + ko + c * 8,
                       smem + 49152 + wid * 8192 + t * 1024);
            }
            __syncthreads();

            #pragma unroll
            for (int ks = 0; ks < 2; ++ks) {
                int ch = ks * 4 + lg;
                bf16x8 af[4], bfr[4];
                #pragma unroll
                for (int rt = 0; rt < 4; ++rt) {
                    int row = rt * 16 + l15;
                    int c = (ko >> 3) + ch;
                    int pos = (c & 8) | ((c ^ swz8(row)) & 7);
                    af[rt] = *(const bf16x8*)(smem + 32768 + row * 256 + pos * 16);
                }
                #pragma unroll
                for (int ct = 0; ct < 4; ++ct) {
                    int row = wid * 64 + ct * 16 + l15;
                    bfr[ct] = *(const bf16x8*)(smem + 49152 + row * 128 + ((ch ^ swz8(row)) * 16));
                }
                #pragma unroll
                for (int rt = 0; rt < 4; ++rt)
                    #pragma unroll
                    for (int ct = 0; ct < 4; ++ct)
                        aco[rt][ct] = mfma16(bfr[ct], af[rt], aco[rt][ct]);
            }
            __syncthreads();
        }
    }

    // ---- final epilogue: +b2, *ls2, + NET residual (from LDS) -> OUTp
    #pragma unroll
    for (int rt = 0; rt < 4; ++rt) {
        int pl = rt * 16 + l15;
        long rowp = (long)b * HW + P0 + pl;
        #pragma unroll
        for (int ct = 0; ct < 4; ++ct) {
            int mg = wid * 64 + ct * 16 + lg * 4;
            float4 bv = *(const float4*)(Bc + 4096 + mg);
            float4 sv = *(const float4*)(ls2 + mg);
            int cc = mg >> 3;
            int pos = (cc & 24) | ((cc ^ swz8(pl)) & 7);
            uint2 nv2 = *(const uint2*)(smem + pl * 512 + pos * 16 + (mg & 7) * 2);
            u16 nv[4] = { (u16)(nv2.x & 0xffff), (u16)(nv2.x >> 16),
                          (u16)(nv2.y & 0xffff), (u16)(nv2.y >> 16) };
            float v0 = (aco[rt][ct][0] + bv.x) * sv.x + bf2f(nv[0]);
            float v1 = (aco[rt][ct][1] + bv.y) * sv.y + bf2f(nv[1]);
            float v2 = (aco[rt][ct][2] + bv.z) * sv.z + bf2f(nv[2]);
            float v3 = (aco[rt][ct][3] + bv.w) * sv.w + bf2f(nv[3]);
            *(uint2*)(OUTp + rowp * 256 + mg) = make_uint2(pk2bf(v0, v1), pk2bf(v2, v3));
        }
    }
}

// ---------------------------------------------------------------------------
// fuse_out: d_out[b][c][p] (f32, m-major) = OUTp[b][p][c] (bf16, p-major)
// ---------------------------------------------------------------------------
__global__ __launch_bounds__(256) void fuse_out(
    const u16* __restrict__ OUTp, float* __restrict__ y)
{
    __shared__ float lds[32][132];
    const int t = threadIdx.x;
    const int Pb = blockIdx.x * 128;
    const int Cb = blockIdx.y * 32;
    const int b  = blockIdx.z;

    #pragma unroll
    for (int q = 0; q < 4; ++q) {
        int id = t + q * 256;
        int p = id >> 3, cq = (id & 7) * 4;
        int pg = Pb + p;
        float4 v = make_float4(0.f, 0.f, 0.f, 0.f);
        if (pg < HW) {
            ushort4 nv = *(const ushort4*)(OUTp + ((long)b * HW + pg) * 256 + Cb + cq);
            v.x = bf2f(nv.x); v.y = bf2f(nv.y); v.z = bf2f(nv.z); v.w = bf2f(nv.w);
        }
        lds[cq + 0][p] = v.x; lds[cq + 1][p] = v.y;
        lds[cq + 2][p] = v.z; lds[cq + 3][p] = v.w;
    }
    __syncthreads();
    #pragma unroll
    for (int q = 0; q < 4; ++q) {
        int id = t + q * 256;
        int c = id >> 5, pq = (id & 31) * 4;
        int pg = Pb + pq;
        if (pg + 3 < HW) {
            float4 v = make_float4(lds[c][pq], lds[c][pq + 1], lds[c][pq + 2], lds[c][pq + 3]);
            *(float4*)(y + ((long)(b * 256 + Cb + c)) * HW + pg) = v;
        }
    }
}

// ---------------------------------------------------------------------------
extern "C" void kernel_launch(void* const* d_in, const int* in_sizes, int n_in,
                              void* d_out, int out_size, void* d_ws, size_t ws_size,
                              hipStream_t stream)
{
    const float* x     = (const float*)d_in[0];
    const float* xq_w  = (const float*)d_in[1];
    const float* xq_b  = (const float*)d_in[2];
    const float* xk_w  = (const float*)d_in[3];
    const float* xk_b  = (const float*)d_in[4];
    const float* xv_w  = (const float*)d_in[5];
    const float* xv_b  = (const float*)d_in[6];
    const float* xp_w  = (const float*)d_in[7];
    const float* xp_b  = (const float*)d_in[8];
    const float* rel_x = (const float*)d_in[9];
    const float* yq_w  = (const float*)d_in[10];
    const float* yq_b  = (const float*)d_in[11];
    const float* yk_w  = (const float*)d_in[12];
    const float* yk_b  = (const float*)d_in[13];
    const float* yv_w  = (const float*)d_in[14];
    const float* yv_b  = (const float*)d_in[15];
    const float* yp_w  = (const float*)d_in[16];
    const float* yp_b  = (const float*)d_in[17];
    const float* rel_y = (const float*)d_in[18];
    const float* cp_w  = (const float*)d_in[19];
    const float* cp_b  = (const float*)d_in[20];
    const float* m1_w  = (const float*)d_in[21];
    const float* m1_b  = (const float*)d_in[22];
    const float* m2_w  = (const float*)d_in[23];
    const float* m2_b  = (const float*)d_in[24];
    const float* ls1   = (const float*)d_in[25];
    const float* ls2   = (const float*)d_in[26];

    if (ws_size < 128450560) return;

    char* ws = (char*)d_ws;
    u16*   SbY  = (u16*)(ws + 0);            // [8][3136][512] bf16
    u16*   OUTp = (u16*)(ws + 25690112);     // [8][3136][256] bf16
    u16*   Xt   = (u16*)(ws + 77070336);     // [8][3136][256] bf16
    u16*   SbX  = (u16*)(ws + 89915392);     // [8][3136][512] bf16
    u16*   NETp = (u16*)(ws + 115605504);    // [8][3136][256] bf16

    // weights/biases in d_out scratch (fully overwritten by fuse_out at the end)
    u16*   Wb = (u16*)d_out;                      // 851968 bf16 = 1,703,936 B
    float* Bc = (float*)((char*)d_out + 1703936); // 4352 f32

    dim3 blk(256, 1, 1);

    wcvt<<<dim3(833, 1, 1), blk, 0, stream>>>(
        xq_w, xk_w, xv_w, yq_w, yk_w, yv_w, xp_w, yp_w, cp_w, m1_w, m2_w,
        xq_b, xk_b, xv_b, yq_b, yk_b, yv_b, xp_b, yp_b, cp_b, m1_b, m2_b,
        Wb, Bc);
    transpose_x<<<dim3(49, 4, 8), blk, 0, stream>>>(x, Xt);
    fused_attn<<<dim3(8, 4, 16), blk, 0, stream>>>(Wb, Bc, Xt, rel_x, rel_y, SbX, SbY);
    // out-proj X+Y + cp fused -> NETp
    opcp<<<dim3(49, 1, 8), blk, 0, stream>>>(Wb, Bc, SbX, SbY, Xt, ls1, NETp);
    // m1 + GELU + m2 fused -> OUTp
    mlp<<<dim3(49, 1, 8), blk, 0, stream>>>(Wb, Bc, NETp, ls2, OUTp);
    fuse_out<<<dim3(25, 8, 8), blk, 0, stream>>>(OUTp, (float*)d_out);
}

// Round 16
// 136.550 us; speedup vs baseline: 1.7761x; 1.0853x over previous
//
#include <hip/hip_runtime.h>

using u16 = unsigned short;
using u32 = unsigned int;

typedef short bf16x8 __attribute__((ext_vector_type(8)));
typedef float f32x4 __attribute__((ext_vector_type(4)));

#define HW 3136
#define IMG 56

__device__ __forceinline__ float bf2f(u16 v) {
    union { u32 u; float f; } c; c.u = ((u32)v) << 16; return c.f;
}
__device__ __forceinline__ u16 f2bf(float f) {
    union { float f; u32 u; } c; c.f = f;
    return (u16)((c.u + 0x7fffu + ((c.u >> 16) & 1u)) >> 16);
}
// pack 2 f32 -> 2 bf16 in one u32 (RNE, hardware cvt)
__device__ __forceinline__ u32 pk2bf(float a, float b) {
    u32 r;
    asm("v_cvt_pk_bf16_f32 %0, %1, %2" : "=v"(r) : "v"(a), "v"(b));
    return r;
}
__device__ __forceinline__ int swz8(int r) { return (r ^ (r >> 3)) & 7; }

__device__ __forceinline__ f32x4 mfma16(bf16x8 a, bf16x8 b, f32x4 c) {
    return __builtin_amdgcn_mfma_f32_16x16x32_bf16(a, b, c, 0, 0, 0);
}

// async global->LDS, 16B per lane; dest = lds_base + lane*16 (wave-uniform base)
__device__ __forceinline__ void gl_lds(const void* g, void* l) {
    __builtin_amdgcn_global_load_lds((const __attribute__((address_space(1))) void*)g,
                                     (__attribute__((address_space(3))) void*)l, 16, 0, 0);
}

// ---------------------------------------------------------------------------
// prep: merged wcvt + transpose_x.
// blocks [0,1568): transpose x [b][256][HW] f32 -> Xt [b][HW][256] bf16
// blocks [1568,2401): weights f32->bf16 into Wb; block 2400 also biases->Bc
// Wb: xq|xk|xv (196608) yq|yk|yv (196608) xp(65536) yp(65536) cp(65536)
//     m1(131072) m2(131072) = 851968 elems
// Bc: qkv x|y (3072) xp(128) yp(128) cp(256) m1(512) m2(256) = 4352
// ---------------------------------------------------------------------------
__global__ __launch_bounds__(256) void prep(
    const float* __restrict__ x, u16* __restrict__ Xt,
    const float* __restrict__ s0, const float* __restrict__ s1, const float* __restrict__ s2,
    const float* __restrict__ s3, const float* __restrict__ s4, const float* __restrict__ s5,
    const float* __restrict__ s6, const float* __restrict__ s7, const float* __restrict__ s8,
    const float* __restrict__ s9, const float* __restrict__ s10,
    const float* __restrict__ b0, const float* __restrict__ b1, const float* __restrict__ b2,
    const float* __restrict__ b3, const float* __restrict__ b4, const float* __restrict__ b5,
    const float* __restrict__ b6, const float* __restrict__ b7, const float* __restrict__ b8,
    const float* __restrict__ b9, const float* __restrict__ b10,
    u16* __restrict__ Wb, float* __restrict__ Bc)
{
    __shared__ u16 lds[64][80];
    const int t = threadIdx.x;
    const int idx = blockIdx.x;

    if (idx < 1568) {   // transpose path
        const int Pb = (idx % 49) * 64;
        const int Cb = ((idx / 49) & 3) * 64;
        const int b  = idx / 196;
        #pragma unroll
        for (int q = 0; q < 4; ++q) {
            int id = t + q * 256;
            int c = id >> 4, pf = (id & 15) * 4;
            float4 v = *(const float4*)(x + ((long)(b * 256 + Cb + c)) * HW + Pb + pf);
            u16 vv[4] = { f2bf(v.x), f2bf(v.y), f2bf(v.z), f2bf(v.w) };
            #pragma unroll
            for (int j = 0; j < 4; ++j) {
                int p = pf + j;
                int cc = (((c >> 3) ^ ((p >> 2) & 7)) << 3) + (c & 7);
                lds[p][cc] = vv[j];
            }
        }
        __syncthreads();
        int p = t >> 2, cf = (t & 3) * 16;
        u16* dst = Xt + ((long)b * HW + Pb + p) * 256 + Cb + cf;
        int cc0 = ((cf >> 3) + 0) ^ ((p >> 2) & 7);
        int cc1 = ((cf >> 3) + 1) ^ ((p >> 2) & 7);
        *(uint4*)(dst + 0) = *(uint4*)&lds[p][cc0 * 8];
        *(uint4*)(dst + 8) = *(uint4*)&lds[p][cc1 * 8];
        return;
    }

    const int bx = idx - 1568;          // wcvt path, 0..832
    if (bx == 832) {                    // biases
        for (int i = t; i < 4352; i += 256) {
            const float* src; int off;
            if      (i < 512)  { src = b0;  off = i; }
            else if (i < 1024) { src = b1;  off = i - 512; }
            else if (i < 1536) { src = b2;  off = i - 1024; }
            else if (i < 2048) { src = b3;  off = i - 1536; }
            else if (i < 2560) { src = b4;  off = i - 2048; }
            else if (i < 3072) { src = b5;  off = i - 2560; }
            else if (i < 3200) { src = b6;  off = i - 3072; }
            else if (i < 3328) { src = b7;  off = i - 3200; }
            else if (i < 3584) { src = b8;  off = i - 3328; }
            else if (i < 4096) { src = b9;  off = i - 3584; }
            else               { src = b10; off = i - 4096; }
            Bc[i] = src[off];
        }
        return;
    }
    long gid4 = ((long)bx * 256 + t) * 4;
    const float* src; long off;
    if (gid4 < 589824) {
        int seg = (int)(gid4 >> 16);
        const float* tab[9] = { s0, s1, s2, s3, s4, s5, s6, s7, s8 };
        src = tab[seg]; off = gid4 - ((long)seg << 16);
    } else if (gid4 < 720896) { src = s9;  off = gid4 - 589824; }
    else                      { src = s10; off = gid4 - 720896; }
    float4 v = *(const float4*)(src + off);
    *(uint2*)(Wb + gid4) = make_uint2(pk2bf(v.x, v.y), pk2bf(v.z, v.w));
}

// ---------------------------------------------------------------------------
// fused_attn: QKV projection + axial attention (round-15 verified: staged X
// with T14 async split, per-XCD L2 partition grid).
// LDS: QT[0,16K) KT[16K,32K) V[32K,48K) X[49152,65536) RELf32[65536,66048).
// ---------------------------------------------------------------------------
__global__ __launch_bounds__(256, 2) void fused_attn(
    const u16* __restrict__ Wb, const float* __restrict__ Bc,
    const u16* __restrict__ Xt,
    const float* __restrict__ rel_x, const float* __restrict__ rel_y,
    u16* __restrict__ SbX, u16* __restrict__ SbY)
{
    __shared__ __align__(16) char smem[66048];
    const int tid = threadIdx.x;
    const int lane = tid & 63, wid = tid >> 6;
    const int l15 = lane & 15, lg = lane >> 4;

    const int g = blockIdx.x;            // 8 groups of 7 rows; bid%8 = g -> XCD partition
    const int n = blockIdx.y;            // head
    const int branch = blockIdx.z >> 3;
    const int b = blockIdx.z & 7;

    const float* rel = branch ? rel_y : rel_x;
    u16* S = branch ? SbY : SbX;
    const u16* wsrc = Wb + branch * 196608 + n * 16384;
    const float* bsrc = Bc + branch * 1536 + n * 128;

    if (tid < 128) {
        float v = (tid < 112) ? rel[n * HW + tid] : 0.0f;
        *(float*)(smem + 65536 + tid * 4) = v;
    }

    bf16x8 wf[3][2][4];
    #pragma unroll
    for (int mat = 0; mat < 3; ++mat)
        #pragma unroll
        for (int mt = 0; mt < 2; ++mt) {
            int mrow = (wid * 2 + mt) * 16 + l15;
            const u16* wr = wsrc + mat * 65536 + mrow * 128;
            #pragma unroll
            for (int ks = 0; ks < 4; ++ks)
                wf[mat][mt][ks] = *(const bf16x8*)(wr + (ks * 4 + lg) * 8);
        }
    float4 bq4[2], bk4[2]; float bvv[2];
    #pragma unroll
    for (int mt = 0; mt < 2; ++mt) {
        int m0 = (wid * 2 + mt) * 16 + lg * 4;
        bq4[mt] = *(const float4*)(bsrc + m0);
        bk4[mt] = *(const float4*)(bsrc + 512 + m0);
        bvv[mt] = bsrc[1024 + (wid * 2 + mt) * 16 + l15];
    }

    const int istrip = wid * 16;
    const float qscale = 0.08838834764831845f;

    auto stageX = [&](int rc2) {
        const int i0 = wid * 16 + (lane >> 4);
        #pragma unroll
        for (int t = 0; t < 4; ++t) {
            int i = i0 + t * 4;
            int ic = (i > 55) ? 55 : i;
            long p = (branch == 0) ? (long)rc2 * IMG + ic : (long)ic * IMG + rc2;
            const u16* src = Xt + ((long)b * HW + p) * 256 + branch * 128
                             + (((lane & 15) ^ swz8(i)) * 8);
            gl_lds(src, smem + 49152 + wid * 4096 + t * 1024);
        }
    };

    stageX(g * 7);

    for (int r = 0; r < 7; ++r) {
        const int rc = g * 7 + r;

        __syncthreads();   // A: X(r) staged + prev LDS reads done

        bf16x8 xf[4][4];
        #pragma unroll
        for (int it = 0; it < 4; ++it) {
            int i = it * 16 + l15;
            #pragma unroll
            for (int ks = 0; ks < 4; ++ks)
                xf[it][ks] = *(const bf16x8*)(smem + 49152 + i * 256
                                              + (((ks * 4 + lg) ^ swz8(i)) * 16));
        }

        #pragma unroll
        for (int mat = 0; mat < 2; ++mat) {
            #pragma unroll
            for (int mt = 0; mt < 2; ++mt) {
                #pragma unroll
                for (int it = 0; it < 4; ++it) {
                    f32x4 a = {};
                    #pragma unroll
                    for (int ks = 0; ks < 4; ++ks)
                        a = mfma16(wf[mat][mt][ks], xf[it][ks], a);
                    int i = it * 16 + l15;
                    int m0 = (wid * 2 + mt) * 16 + lg * 4;
                    float4 bb2 = mat ? bk4[mt] : bq4[mt];
                    int c = m0 >> 3;
                    *(uint2*)(smem + mat * 16384 + i * 256 + ((c ^ swz8(i)) * 16) + (lg & 1) * 8)
                        = make_uint2(pk2bf(a[0] + bb2.x, a[1] + bb2.y),
                                     pk2bf(a[2] + bb2.z, a[3] + bb2.w));
                }
            }
        }
        #pragma unroll
        for (int mt = 0; mt < 2; ++mt) {
            #pragma unroll
            for (int it = 0; it < 4; ++it) {
                f32x4 a = {};
                #pragma unroll
                for (int ks = 0; ks < 4; ++ks)
                    a = mfma16(xf[it][ks], wf[2][mt][ks], a);
                int d = (wid * 2 + mt) * 16 + l15;
                int c2 = (it >> 1) * 4 + lg;
                float bv = bvv[mt];
                *(uint2*)(smem + 32768 + d * 128 + ((c2 ^ swz8(d)) * 16) + (it & 1) * 8)
                    = make_uint2(pk2bf(a[0] + bv, a[1] + bv),
                                 pk2bf(a[2] + bv, a[3] + bv));
            }
        }
        __syncthreads();   // B: proj visible; X region free

        if (r < 6) stageX(rc + 1);   // overlaps QK/softmax/PV (T14)

        bf16x8 aq[4];
        #pragma unroll
        for (int ks = 0; ks < 4; ++ks) {
            int row = istrip + l15;
            int ch = ks * 4 + lg;
            aq[ks] = *(const bf16x8*)(smem + row * 256 + ((ch ^ swz8(row)) * 16));
        }
        f32x4 sacc[4] = {};
        #pragma unroll
        for (int ct = 0; ct < 4; ++ct) {
            #pragma unroll
            for (int ks = 0; ks < 4; ++ks) {
                int j = ct * 16 + l15;
                int ch = ks * 4 + lg;
                bf16x8 kb = *(const bf16x8*)(smem + 16384 + j * 256 + ((ch ^ swz8(j)) * 16));
                sacc[ct] = mfma16(kb, aq[ks], sacc[ct]);
            }
        }

        const int irow = istrip + l15;
        float p[4][4];
        float mx = -1e30f;
        #pragma unroll
        for (int ct = 0; ct < 4; ++ct)
            #pragma unroll
            for (int rr = 0; rr < 4; ++rr) {
                int j = ct * 16 + lg * 4 + rr;
                float x = sacc[ct][rr] * qscale;
                if (j < IMG) x += *(const float*)(smem + 65536 + (irow - j + 55) * 4);
                else x = -1e30f;
                p[ct][rr] = x;
                mx = fmaxf(mx, x);
            }
        mx = fmaxf(mx, __shfl_xor(mx, 16));
        mx = fmaxf(mx, __shfl_xor(mx, 32));
        float s0 = 0.f;
        #pragma unroll
        for (int ct = 0; ct < 4; ++ct)
            #pragma unroll
            for (int rr = 0; rr < 4; ++rr) {
                float e = __expf(p[ct][rr] - mx);
                p[ct][rr] = e; s0 += e;
            }
        s0 += __shfl_xor(s0, 16);
        s0 += __shfl_xor(s0, 32);
        float inv = 1.0f / s0;

        union { u32 u[4]; bf16x8 v; } pb[2];
        #pragma unroll
        for (int ks = 0; ks < 2; ++ks) {
            pb[ks].u[0] = pk2bf(p[2*ks][0] * inv, p[2*ks][1] * inv);
            pb[ks].u[1] = pk2bf(p[2*ks][2] * inv, p[2*ks][3] * inv);
            pb[ks].u[2] = pk2bf(p[2*ks+1][0] * inv, p[2*ks+1][1] * inv);
            pb[ks].u[3] = pk2bf(p[2*ks+1][2] * inv, p[2*ks+1][3] * inv);
        }

        f32x4 oacc[8] = {};
        #pragma unroll
        for (int dt = 0; dt < 8; ++dt) {
            #pragma unroll
            for (int ks = 0; ks < 2; ++ks) {
                int d = dt * 16 + l15;
                int c2 = ks * 4 + lg;
                bf16x8 vb = *(const bf16x8*)(smem + 32768 + d * 128 + ((c2 ^ swz8(d)) * 16));
                oacc[dt] = mfma16(vb, pb[ks].v, oacc[dt]);
            }
        }

        const int i = istrip + l15;
        if (i < IMG) {
            int im = n * 14 + (i >> 2);
            long pp = (branch == 0) ? (long)rc * IMG + im : (long)im * IMG + rc;
            u16* dst = S + ((long)b * HW + pp) * 512 + (i & 3) * 128;
            #pragma unroll
            for (int dt = 0; dt < 8; ++dt) {
                int d4 = dt * 16 + lg * 4;
                *(uint2*)(dst + d4) = make_uint2(pk2bf(oacc[dt][0], oacc[dt][1]),
                                                 pk2bf(oacc[dt][2], oacc[dt][3]));
            }
        }
    }
}

// ---------------------------------------------------------------------------
// tail: fused out-proj(X,Y) + cp + m1/GELU + m2 per 64-row p-tile.
// NET never leaves LDS (replaces opcp->NETp->mlp round-trip).
// LDS phases (80K):
//  P1: actX@0 8K | actY@8192 8K | xpW@16384 16K | ypW@32768 16K | AXY@49152 32K
//  P2: cpW@16384 32K (reads AXY)  -> NET@16384 32K (after last sync)
//  P3: m1W@0 16K | H@49152 16K | m2W waves01@0 16K, waves23@65536 16K
// ---------------------------------------------------------------------------
__global__ __launch_bounds__(256, 2) void tail(
    const u16* __restrict__ Wb, const float* __restrict__ Bc,
    const u16* __restrict__ SbX, const u16* __restrict__ SbY,
    const u16* __restrict__ Xt,
    const float* __restrict__ ls1, const float* __restrict__ ls2,
    u16* __restrict__ OUTp)
{
    __shared__ __align__(16) char smem[81920];
    const int tid = threadIdx.x;
    const int lane = tid & 63, wid = tid >> 6;
    const int l15 = lane & 15, lg = lane >> 4;
    const int P0 = blockIdx.x * 64;
    const int b  = blockIdx.z;

    const u16* xp  = Wb + 393216;
    const u16* yp  = Wb + 458752;
    const u16* cpw = Wb + 524288;
    const u16* m1w = Wb + 589824;
    const u16* m2w = Wb + 720896;

    // ================= phase 1: out-projection X|Y -> AXY LDS =================
    f32x4 acc[4][4] = {};
    for (int ko = 0; ko < 512; ko += 64) {
        #pragma unroll
        for (int t = 0; t < 2; ++t) {
            int row = wid * 16 + t * 8 + (lane >> 3);
            int c = (lane & 7) ^ swz8(row);
            long prow = (long)b * HW + P0 + row;
            gl_lds(SbX + prow * 512 + ko + c * 8, smem + wid * 2048 + t * 1024);
            gl_lds(SbY + prow * 512 + ko + c * 8, smem + 8192 + wid * 2048 + t * 1024);
        }
        #pragma unroll
        for (int t = 0; t < 4; ++t) {
            int row = wid * 32 + t * 8 + (lane >> 3);
            int c = (lane & 7) ^ swz8(row);
            gl_lds(xp + (long)row * 512 + ko + c * 8, smem + 16384 + wid * 4096 + t * 1024);
            gl_lds(yp + (long)row * 512 + ko + c * 8, smem + 32768 + wid * 4096 + t * 1024);
        }
        __syncthreads();

        const int actb = (wid < 2) ? 0 : 8192;
        const int wbse = (wid < 2) ? 16384 : 32768;
        const int wrow0 = (wid & 1) * 64;
        #pragma unroll
        for (int ks = 0; ks < 2; ++ks) {
            int ch = ks * 4 + lg;
            bf16x8 af[4], bfr[4];
            #pragma unroll
            for (int rt = 0; rt < 4; ++rt) {
                int row = rt * 16 + l15;
                af[rt] = *(const bf16x8*)(smem + actb + row * 128 + ((ch ^ swz8(row)) * 16));
            }
            #pragma unroll
            for (int ct = 0; ct < 4; ++ct) {
                int row = wrow0 + ct * 16 + l15;
                bfr[ct] = *(const bf16x8*)(smem + wbse + row * 128 + ((ch ^ swz8(row)) * 16));
            }
            #pragma unroll
            for (int rt = 0; rt < 4; ++rt)
                #pragma unroll
                for (int ct = 0; ct < 4; ++ct)
                    acc[rt][ct] = mfma16(bfr[ct], af[rt], acc[rt][ct]);
        }
        __syncthreads();
    }

    #pragma unroll
    for (int rt = 0; rt < 4; ++rt) {
        int pl = rt * 16 + l15;
        long rowp = (long)b * HW + P0 + pl;
        #pragma unroll
        for (int ct = 0; ct < 4; ++ct) {
            int mg2 = wid * 64 + ct * 16 + lg * 4;
            float4 bv = *(const float4*)(Bc + 3072 + mg2);
            ushort4 rv = *(const ushort4*)(Xt + rowp * 256 + mg2);
            float v0 = acc[rt][ct][0] + bv.x + bf2f(rv.x);
            float v1 = acc[rt][ct][1] + bv.y + bf2f(rv.y);
            float v2 = acc[rt][ct][2] + bv.z + bf2f(rv.z);
            float v3 = acc[rt][ct][3] + bv.w + bf2f(rv.w);
            int cc = mg2 >> 3;
            int pos = (cc & 24) | ((cc ^ swz8(pl)) & 7);
            *(uint2*)(smem + 49152 + pl * 512 + pos * 16 + (mg2 & 7) * 2)
                = make_uint2(pk2bf(v0, v1), pk2bf(v2, v3));
        }
    }
    __syncthreads();

    // ================= phase 2: cp -> NET LDS =================
    f32x4 acc2[4][4] = {};
    for (int ko = 0; ko < 256; ko += 64) {
        #pragma unroll
        for (int t = 0; t < 8; ++t) {
            int row = wid * 64 + t * 8 + (lane >> 3);
            int c = (lane & 7) ^ swz8(row);
            gl_lds(cpw + (long)row * 256 + ko + c * 8, smem + 16384 + wid * 8192 + t * 1024);
        }
        __syncthreads();

        #pragma unroll
        for (int ks = 0; ks < 2; ++ks) {
            int ch = ks * 4 + lg;
            bf16x8 af[4], bfr[4];
            #pragma unroll
            for (int rt = 0; rt < 4; ++rt) {
                int row = rt * 16 + l15;
                int c = (ko >> 3) + ch;
                int pos = (c & 24) | ((c ^ swz8(row)) & 7);
                af[rt] = *(const bf16x8*)(smem + 49152 + row * 512 + pos * 16);
            }
            #pragma unroll
            for (int ct = 0; ct < 4; ++ct) {
                int row = wid * 64 + ct * 16 + l15;
                bfr[ct] = *(const bf16x8*)(smem + 16384 + row * 128 + ((ch ^ swz8(row)) * 16));
            }
            #pragma unroll
            for (int rt = 0; rt < 4; ++rt)
                #pragma unroll
                for (int ct = 0; ct < 4; ++ct)
                    acc2[rt][ct] = mfma16(bfr[ct], af[rt], acc2[rt][ct]);
        }
        __syncthreads();
    }

    // NET = ls1*(cp+b) + Xt -> LDS @16384 (rows [64][512B], swizzled)
    #pragma unroll
    for (int rt = 0; rt < 4; ++rt) {
        int pl = rt * 16 + l15;
        long rowp = (long)b * HW + P0 + pl;
        #pragma unroll
        for (int ct = 0; ct < 4; ++ct) {
            int mg = wid * 64 + ct * 16 + lg * 4;
            float4 bv = *(const float4*)(Bc + 3328 + mg);
            float4 sv = *(const float4*)(ls1 + mg);
            ushort4 rv = *(const ushort4*)(Xt + rowp * 256 + mg);
            float v0 = (acc2[rt][ct][0] + bv.x) * sv.x + bf2f(rv.x);
            float v1 = (acc2[rt][ct][1] + bv.y) * sv.y + bf2f(rv.y);
            float v2 = (acc2[rt][ct][2] + bv.z) * sv.z + bf2f(rv.z);
            float v3 = (acc2[rt][ct][3] + bv.w) * sv.w + bf2f(rv.w);
            int cc = mg >> 3;
            int pos = (cc & 24) | ((cc ^ swz8(pl)) & 7);
            *(uint2*)(smem + 16384 + pl * 512 + pos * 16 + (mg & 7) * 2)
                = make_uint2(pk2bf(v0, v1), pk2bf(v2, v3));
        }
    }

    // ================= phase 3: m1 + GELU + m2 =================
    f32x4 aco[4][4] = {};

    for (int hc = 0; hc < 4; ++hc) {
        // m1 chunk -> H
        f32x4 ach[4][2] = {};
        for (int ko = 0; ko < 256; ko += 64) {
            #pragma unroll
            for (int t = 0; t < 4; ++t) {
                int row = wid * 32 + t * 8 + (lane >> 3);
                int c = (lane & 7) ^ swz8(row);
                gl_lds(m1w + (long)(hc * 128 + row) * 256 + ko + c * 8,
                       smem + wid * 4096 + t * 1024);
            }
            __syncthreads();

            #pragma unroll
            for (int ks = 0; ks < 2; ++ks) {
                int ch = ks * 4 + lg;
                bf16x8 af[4], bfrh[2];
                #pragma unroll
                for (int rt = 0; rt < 4; ++rt) {
                    int row = rt * 16 + l15;
                    int c = (ko >> 3) + ch;
                    int pos = (c & 24) | ((c ^ swz8(row)) & 7);
                    af[rt] = *(const bf16x8*)(smem + 16384 + row * 512 + pos * 16);
                }
                #pragma unroll
                for (int mt = 0; mt < 2; ++mt) {
                    int row = wid * 32 + mt * 16 + l15;
                    bfrh[mt] = *(const bf16x8*)(smem + row * 128 + ((ch ^ swz8(row)) * 16));
                }
                #pragma unroll
                for (int rt = 0; rt < 4; ++rt)
                    #pragma unroll
                    for (int mt = 0; mt < 2; ++mt)
                        ach[rt][mt] = mfma16(bfrh[mt], af[rt], ach[rt][mt]);
            }
            __syncthreads();
        }
        // H = gelu(m1+b) -> LDS @49152 (rows [64][256B])
        #pragma unroll
        for (int rt = 0; rt < 4; ++rt) {
            int pl = rt * 16 + l15;
            #pragma unroll
            for (int mt = 0; mt < 2; ++mt) {
                int hloc = wid * 32 + mt * 16 + lg * 4;
                float4 bv = *(const float4*)(Bc + 3584 + hc * 128 + hloc);
                float v[4];
                #pragma unroll
                for (int j = 0; j < 4; ++j) {
                    float tt = ach[rt][mt][j] + ((const float*)&bv)[j];
                    v[j] = tt * 0.5f * (1.0f + erff(tt * 0.70710678118f));
                }
                int cc = hloc >> 3;
                int pos = (cc & 8) | ((cc ^ swz8(pl)) & 7);
                *(uint2*)(smem + 49152 + pl * 256 + pos * 16 + (hloc & 7) * 2)
                    = make_uint2(pk2bf(v[0], v[1]), pk2bf(v[2], v[3]));
            }
        }

        // m2 partial: aco += m2W[:, hc*128..] @ H
        for (int ko = 0; ko < 128; ko += 64) {
            #pragma unroll
            for (int t = 0; t < 8; ++t) {
                int row = wid * 64 + t * 8 + (lane >> 3);
                int c = (lane & 7) ^ swz8(row);
                char* dst = ((wid < 2) ? (smem + wid * 8192) : (smem + 65536 + (wid - 2) * 8192))
                            + t * 1024;
                gl_lds(m2w + (long)row * 512 + hc * 128 + ko + c * 8, dst);
            }
            __syncthreads();

            #pragma unroll
            for (int ks = 0; ks < 2; ++ks) {
                int ch = ks * 4 + lg;
                bf16x8 af[4], bfr[4];
                #pragma unroll
                for (int rt = 0; rt < 4; ++rt) {
                    int row = rt * 16 + l15;
                    int c = (ko >> 3) + ch;
                    int pos = (c & 8) | ((c ^ swz8(row)) & 7);
                    af[rt] = *(const bf16x8*)(smem + 49152 + row * 256 + pos * 16);
                }
                #pragma unroll
                for (int ct = 0; ct < 4; ++ct) {
                    int row = wid * 64 + ct * 16 + l15;
                    const char* base = (wid < 2) ? smem : (smem + 65536 - 16384);
                    bfr[ct] = *(const bf16x8*)(base + row * 128 + ((ch ^ swz8(row)) * 16));
                }
                #pragma unroll
                for (int rt = 0; rt < 4; ++rt)
                    #pragma unroll
                    for (int ct = 0; ct < 4; ++ct)
                        aco[rt][ct] = mfma16(bfr[ct], af[rt], aco[rt][ct]);
            }
            __syncthreads();
        }
    }

    // ---- final epilogue: +b2, *ls2, + NET (LDS) -> OUTp
    #pragma unroll
    for (int rt = 0; rt < 4; ++rt) {
        int pl = rt * 16 + l15;
        long rowp = (long)b * HW + P0 + pl;
        #pragma unroll
        for (int ct = 0; ct < 4; ++ct) {
            int mg = wid * 64 + ct * 16 + lg * 4;
            float4 bv = *(const float4*)(Bc + 4096 + mg);
            float4 sv = *(const float4*)(ls2 + mg);
            int cc = mg >> 3;
            int pos = (cc & 24) | ((cc ^ swz8(pl)) & 7);
            uint2 nv2 = *(const uint2*)(smem + 16384 + pl * 512 + pos * 16 + (mg & 7) * 2);
            u16 nv[4] = { (u16)(nv2.x & 0xffff), (u16)(nv2.x >> 16),
                          (u16)(nv2.y & 0xffff), (u16)(nv2.y >> 16) };
            float v0 = (aco[rt][ct][0] + bv.x) * sv.x + bf2f(nv[0]);
            float v1 = (aco[rt][ct][1] + bv.y) * sv.y + bf2f(nv[1]);
            float v2 = (aco[rt][ct][2] + bv.z) * sv.z + bf2f(nv[2]);
            float v3 = (aco[rt][ct][3] + bv.w) * sv.w + bf2f(nv[3]);
            *(uint2*)(OUTp + rowp * 256 + mg) = make_uint2(pk2bf(v0, v1), pk2bf(v2, v3));
        }
    }
}

// ---------------------------------------------------------------------------
// fuse_out: d_out[b][c][p] (f32, m-major) = OUTp[b][p][c] (bf16, p-major)
// ---------------------------------------------------------------------------
__global__ __launch_bounds__(256) void fuse_out(
    const u16* __restrict__ OUTp, float* __restrict__ y)
{
    __shared__ float lds[32][132];
    const int t = threadIdx.x;
    const int Pb = blockIdx.x * 128;
    const int Cb = blockIdx.y * 32;
    const int b  = blockIdx.z;

    #pragma unroll
    for (int q = 0; q < 4; ++q) {
        int id = t + q * 256;
        int p = id >> 3, cq = (id & 7) * 4;
        int pg = Pb + p;
        float4 v = make_float4(0.f, 0.f, 0.f, 0.f);
        if (pg < HW) {
            ushort4 nv = *(const ushort4*)(OUTp + ((long)b * HW + pg) * 256 + Cb + cq);
            v.x = bf2f(nv.x); v.y = bf2f(nv.y); v.z = bf2f(nv.z); v.w = bf2f(nv.w);
        }
        lds[cq + 0][p] = v.x; lds[cq + 1][p] = v.y;
        lds[cq + 2][p] = v.z; lds[cq + 3][p] = v.w;
    }
    __syncthreads();
    #pragma unroll
    for (int q = 0; q < 4; ++q) {
        int id = t + q * 256;
        int c = id >> 5, pq = (id & 31) * 4;
        int pg = Pb + pq;
        if (pg + 3 < HW) {
            float4 v = make_float4(lds[c][pq], lds[c][pq + 1], lds[c][pq + 2], lds[c][pq + 3]);
            *(float4*)(y + ((long)(b * 256 + Cb + c)) * HW + pg) = v;
        }
    }
}

// ---------------------------------------------------------------------------
extern "C" void kernel_launch(void* const* d_in, const int* in_sizes, int n_in,
                              void* d_out, int out_size, void* d_ws, size_t ws_size,
                              hipStream_t stream)
{
    const float* x     = (const float*)d_in[0];
    const float* xq_w  = (const float*)d_in[1];
    const float* xq_b  = (const float*)d_in[2];
    const float* xk_w  = (const float*)d_in[3];
    const float* xk_b  = (const float*)d_in[4];
    const float* xv_w  = (const float*)d_in[5];
    const float* xv_b  = (const float*)d_in[6];
    const float* xp_w  = (const float*)d_in[7];
    const float* xp_b  = (const float*)d_in[8];
    const float* rel_x = (const float*)d_in[9];
    const float* yq_w  = (const float*)d_in[10];
    const float* yq_b  = (const float*)d_in[11];
    const float* yk_w  = (const float*)d_in[12];
    const float* yk_b  = (const float*)d_in[13];
    const float* yv_w  = (const float*)d_in[14];
    const float* yv_b  = (const float*)d_in[15];
    const float* yp_w  = (const float*)d_in[16];
    const float* yp_b  = (const float*)d_in[17];
    const float* rel_y = (const float*)d_in[18];
    const float* cp_w  = (const float*)d_in[19];
    const float* cp_b  = (const float*)d_in[20];
    const float* m1_w  = (const float*)d_in[21];
    const float* m1_b  = (const float*)d_in[22];
    const float* m2_w  = (const float*)d_in[23];
    const float* m2_b  = (const float*)d_in[24];
    const float* ls1   = (const float*)d_in[25];
    const float* ls2   = (const float*)d_in[26];

    if (ws_size < 128450560) return;

    char* ws = (char*)d_ws;
    u16*   SbY  = (u16*)(ws + 0);            // [8][3136][512] bf16
    u16*   OUTp = (u16*)(ws + 25690112);     // [8][3136][256] bf16
    u16*   Xt   = (u16*)(ws + 77070336);     // [8][3136][256] bf16
    u16*   SbX  = (u16*)(ws + 89915392);     // [8][3136][512] bf16

    // weights/biases in d_out scratch (fully overwritten by fuse_out at the end)
    u16*   Wb = (u16*)d_out;                      // 851968 bf16 = 1,703,936 B
    float* Bc = (float*)((char*)d_out + 1703936); // 4352 f32

    dim3 blk(256, 1, 1);

    // merged wcvt + transpose_x
    prep<<<dim3(2401, 1, 1), blk, 0, stream>>>(
        x, Xt,
        xq_w, xk_w, xv_w, yq_w, yk_w, yv_w, xp_w, yp_w, cp_w, m1_w, m2_w,
        xq_b, xk_b, xv_b, yq_b, yk_b, yv_b, xp_b, yp_b, cp_b, m1_b, m2_b,
        Wb, Bc);
    fused_attn<<<dim3(8, 4, 16), blk, 0, stream>>>(Wb, Bc, Xt, rel_x, rel_y, SbX, SbY);
    // out-proj X+Y + cp + m1/GELU + m2 fused -> OUTp
    tail<<<dim3(49, 1, 8), blk, 0, stream>>>(Wb, Bc, SbX, SbY, Xt, ls1, ls2, OUTp);
    fuse_out<<<dim3(25, 8, 8), blk, 0, stream>>>(OUTp, (float*)d_out);
}

// Round 17
// 132.740 us; speedup vs baseline: 1.8271x; 1.0287x over previous
//
#include <hip/hip_runtime.h>

using u16 = unsigned short;
using u32 = unsigned int;

typedef short bf16x8 __attribute__((ext_vector_type(8)));
typedef float f32x4 __attribute__((ext_vector_type(4)));

#define HW 3136
#define IMG 56

__device__ __forceinline__ float bf2f(u16 v) {
    union { u32 u; float f; } c; c.u = ((u32)v) << 16; return c.f;
}
__device__ __forceinline__ u16 f2bf(float f) {
    union { float f; u32 u; } c; c.f = f;
    return (u16)((c.u + 0x7fffu + ((c.u >> 16) & 1u)) >> 16);
}
// pack 2 f32 -> 2 bf16 in one u32 (RNE, hardware cvt)
__device__ __forceinline__ u32 pk2bf(float a, float b) {
    u32 r;
    asm("v_cvt_pk_bf16_f32 %0, %1, %2" : "=v"(r) : "v"(a), "v"(b));
    return r;
}
__device__ __forceinline__ int swz8(int r) { return (r ^ (r >> 3)) & 7; }

__device__ __forceinline__ f32x4 mfma16(bf16x8 a, bf16x8 b, f32x4 c) {
    return __builtin_amdgcn_mfma_f32_16x16x32_bf16(a, b, c, 0, 0, 0);
}

// async global->LDS, 16B per lane; dest = lds_base + lane*16 (wave-uniform base)
__device__ __forceinline__ void gl_lds(const void* g, void* l) {
    __builtin_amdgcn_global_load_lds((const __attribute__((address_space(1))) void*)g,
                                     (__attribute__((address_space(3))) void*)l, 16, 0, 0);
}

// ---------------------------------------------------------------------------
// prep: merged wcvt + transpose_x.
// blocks [0,1568): transpose x [b][256][HW] f32 -> Xt [b][HW][256] bf16
// blocks [1568,2401): weights f32->bf16 into Wb; block 2400 also biases->Bc
// ---------------------------------------------------------------------------
__global__ __launch_bounds__(256) void prep(
    const float* __restrict__ x, u16* __restrict__ Xt,
    const float* __restrict__ s0, const float* __restrict__ s1, const float* __restrict__ s2,
    const float* __restrict__ s3, const float* __restrict__ s4, const float* __restrict__ s5,
    const float* __restrict__ s6, const float* __restrict__ s7, const float* __restrict__ s8,
    const float* __restrict__ s9, const float* __restrict__ s10,
    const float* __restrict__ b0, const float* __restrict__ b1, const float* __restrict__ b2,
    const float* __restrict__ b3, const float* __restrict__ b4, const float* __restrict__ b5,
    const float* __restrict__ b6, const float* __restrict__ b7, const float* __restrict__ b8,
    const float* __restrict__ b9, const float* __restrict__ b10,
    u16* __restrict__ Wb, float* __restrict__ Bc)
{
    __shared__ u16 lds[64][80];
    const int t = threadIdx.x;
    const int idx = blockIdx.x;

    if (idx < 1568) {   // transpose path
        const int Pb = (idx % 49) * 64;
        const int Cb = ((idx / 49) & 3) * 64;
        const int b  = idx / 196;
        #pragma unroll
        for (int q = 0; q < 4; ++q) {
            int id = t + q * 256;
            int c = id >> 4, pf = (id & 15) * 4;
            float4 v = *(const float4*)(x + ((long)(b * 256 + Cb + c)) * HW + Pb + pf);
            u16 vv[4] = { f2bf(v.x), f2bf(v.y), f2bf(v.z), f2bf(v.w) };
            #pragma unroll
            for (int j = 0; j < 4; ++j) {
                int p = pf + j;
                int cc = (((c >> 3) ^ ((p >> 2) & 7)) << 3) + (c & 7);
                lds[p][cc] = vv[j];
            }
        }
        __syncthreads();
        int p = t >> 2, cf = (t & 3) * 16;
        u16* dst = Xt + ((long)b * HW + Pb + p) * 256 + Cb + cf;
        int cc0 = ((cf >> 3) + 0) ^ ((p >> 2) & 7);
        int cc1 = ((cf >> 3) + 1) ^ ((p >> 2) & 7);
        *(uint4*)(dst + 0) = *(uint4*)&lds[p][cc0 * 8];
        *(uint4*)(dst + 8) = *(uint4*)&lds[p][cc1 * 8];
        return;
    }

    const int bx = idx - 1568;          // wcvt path, 0..832
    if (bx == 832) {                    // biases
        for (int i = t; i < 4352; i += 256) {
            const float* src; int off;
            if      (i < 512)  { src = b0;  off = i; }
            else if (i < 1024) { src = b1;  off = i - 512; }
            else if (i < 1536) { src = b2;  off = i - 1024; }
            else if (i < 2048) { src = b3;  off = i - 1536; }
            else if (i < 2560) { src = b4;  off = i - 2048; }
            else if (i < 3072) { src = b5;  off = i - 2560; }
            else if (i < 3200) { src = b6;  off = i - 3072; }
            else if (i < 3328) { src = b7;  off = i - 3200; }
            else if (i < 3584) { src = b8;  off = i - 3328; }
            else if (i < 4096) { src = b9;  off = i - 3584; }
            else               { src = b10; off = i - 4096; }
            Bc[i] = src[off];
        }
        return;
    }
    long gid4 = ((long)bx * 256 + t) * 4;
    const float* src; long off;
    if (gid4 < 589824) {
        int seg = (int)(gid4 >> 16);
        const float* tab[9] = { s0, s1, s2, s3, s4, s5, s6, s7, s8 };
        src = tab[seg]; off = gid4 - ((long)seg << 16);
    } else if (gid4 < 720896) { src = s9;  off = gid4 - 589824; }
    else                      { src = s10; off = gid4 - 720896; }
    float4 v = *(const float4*)(src + off);
    *(uint2*)(Wb + gid4) = make_uint2(pk2bf(v.x, v.y), pk2bf(v.z, v.w));
}

// ---------------------------------------------------------------------------
// fused_attn: QKV projection + axial attention (round-15 verified structure:
// staged X with T14 async split, per-XCD L2 partition grid) + T5 setprio
// around MFMA clusters.
// LDS: QT[0,16K) KT[16K,32K) V[32K,48K) X[49152,65536) RELf32[65536,66048).
// ---------------------------------------------------------------------------
__global__ __launch_bounds__(256, 2) void fused_attn(
    const u16* __restrict__ Wb, const float* __restrict__ Bc,
    const u16* __restrict__ Xt,
    const float* __restrict__ rel_x, const float* __restrict__ rel_y,
    u16* __restrict__ SbX, u16* __restrict__ SbY)
{
    __shared__ __align__(16) char smem[66048];
    const int tid = threadIdx.x;
    const int lane = tid & 63, wid = tid >> 6;
    const int l15 = lane & 15, lg = lane >> 4;

    const int g = blockIdx.x;            // 8 groups of 7 rows; bid%8 = g -> XCD partition
    const int n = blockIdx.y;            // head
    const int branch = blockIdx.z >> 3;
    const int b = blockIdx.z & 7;

    const float* rel = branch ? rel_y : rel_x;
    u16* S = branch ? SbY : SbX;
    const u16* wsrc = Wb + branch * 196608 + n * 16384;
    const float* bsrc = Bc + branch * 1536 + n * 128;

    if (tid < 128) {
        float v = (tid < 112) ? rel[n * HW + tid] : 0.0f;
        *(float*)(smem + 65536 + tid * 4) = v;
    }

    bf16x8 wf[3][2][4];
    #pragma unroll
    for (int mat = 0; mat < 3; ++mat)
        #pragma unroll
        for (int mt = 0; mt < 2; ++mt) {
            int mrow = (wid * 2 + mt) * 16 + l15;
            const u16* wr = wsrc + mat * 65536 + mrow * 128;
            #pragma unroll
            for (int ks = 0; ks < 4; ++ks)
                wf[mat][mt][ks] = *(const bf16x8*)(wr + (ks * 4 + lg) * 8);
        }
    float4 bq4[2], bk4[2]; float bvv[2];
    #pragma unroll
    for (int mt = 0; mt < 2; ++mt) {
        int m0 = (wid * 2 + mt) * 16 + lg * 4;
        bq4[mt] = *(const float4*)(bsrc + m0);
        bk4[mt] = *(const float4*)(bsrc + 512 + m0);
        bvv[mt] = bsrc[1024 + (wid * 2 + mt) * 16 + l15];
    }

    const int istrip = wid * 16;
    const float qscale = 0.08838834764831845f;

    auto stageX = [&](int rc2) {
        const int i0 = wid * 16 + (lane >> 4);
        #pragma unroll
        for (int t = 0; t < 4; ++t) {
            int i = i0 + t * 4;
            int ic = (i > 55) ? 55 : i;
            long p = (branch == 0) ? (long)rc2 * IMG + ic : (long)ic * IMG + rc2;
            const u16* src = Xt + ((long)b * HW + p) * 256 + branch * 128
                             + (((lane & 15) ^ swz8(i)) * 8);
            gl_lds(src, smem + 49152 + wid * 4096 + t * 1024);
        }
    };

    stageX(g * 7);

    for (int r = 0; r < 7; ++r) {
        const int rc = g * 7 + r;

        __syncthreads();   // A: X(r) staged + prev LDS reads done

        bf16x8 xf[4][4];
        #pragma unroll
        for (int it = 0; it < 4; ++it) {
            int i = it * 16 + l15;
            #pragma unroll
            for (int ks = 0; ks < 4; ++ks)
                xf[it][ks] = *(const bf16x8*)(smem + 49152 + i * 256
                                              + (((ks * 4 + lg) ^ swz8(i)) * 16));
        }

        __builtin_amdgcn_s_setprio(1);
        #pragma unroll
        for (int mat = 0; mat < 2; ++mat) {
            #pragma unroll
            for (int mt = 0; mt < 2; ++mt) {
                #pragma unroll
                for (int it = 0; it < 4; ++it) {
                    f32x4 a = {};
                    #pragma unroll
                    for (int ks = 0; ks < 4; ++ks)
                        a = mfma16(wf[mat][mt][ks], xf[it][ks], a);
                    int i = it * 16 + l15;
                    int m0 = (wid * 2 + mt) * 16 + lg * 4;
                    float4 bb2 = mat ? bk4[mt] : bq4[mt];
                    int c = m0 >> 3;
                    *(uint2*)(smem + mat * 16384 + i * 256 + ((c ^ swz8(i)) * 16) + (lg & 1) * 8)
                        = make_uint2(pk2bf(a[0] + bb2.x, a[1] + bb2.y),
                                     pk2bf(a[2] + bb2.z, a[3] + bb2.w));
                }
            }
        }
        #pragma unroll
        for (int mt = 0; mt < 2; ++mt) {
            #pragma unroll
            for (int it = 0; it < 4; ++it) {
                f32x4 a = {};
                #pragma unroll
                for (int ks = 0; ks < 4; ++ks)
                    a = mfma16(xf[it][ks], wf[2][mt][ks], a);
                int d = (wid * 2 + mt) * 16 + l15;
                int c2 = (it >> 1) * 4 + lg;
                float bv = bvv[mt];
                *(uint2*)(smem + 32768 + d * 128 + ((c2 ^ swz8(d)) * 16) + (it & 1) * 8)
                    = make_uint2(pk2bf(a[0] + bv, a[1] + bv),
                                 pk2bf(a[2] + bv, a[3] + bv));
            }
        }
        __builtin_amdgcn_s_setprio(0);
        __syncthreads();   // B: proj visible; X region free

        if (r < 6) stageX(rc + 1);   // overlaps QK/softmax/PV (T14)

        bf16x8 aq[4];
        #pragma unroll
        for (int ks = 0; ks < 4; ++ks) {
            int row = istrip + l15;
            int ch = ks * 4 + lg;
            aq[ks] = *(const bf16x8*)(smem + row * 256 + ((ch ^ swz8(row)) * 16));
        }
        __builtin_amdgcn_s_setprio(1);
        f32x4 sacc[4] = {};
        #pragma unroll
        for (int ct = 0; ct < 4; ++ct) {
            #pragma unroll
            for (int ks = 0; ks < 4; ++ks) {
                int j = ct * 16 + l15;
                int ch = ks * 4 + lg;
                bf16x8 kb = *(const bf16x8*)(smem + 16384 + j * 256 + ((ch ^ swz8(j)) * 16));
                sacc[ct] = mfma16(kb, aq[ks], sacc[ct]);
            }
        }
        __builtin_amdgcn_s_setprio(0);

        const int irow = istrip + l15;
        float p[4][4];
        float mx = -1e30f;
        #pragma unroll
        for (int ct = 0; ct < 4; ++ct)
            #pragma unroll
            for (int rr = 0; rr < 4; ++rr) {
                int j = ct * 16 + lg * 4 + rr;
                float x = sacc[ct][rr] * qscale;
                if (j < IMG) x += *(const float*)(smem + 65536 + (irow - j + 55) * 4);
                else x = -1e30f;
                p[ct][rr] = x;
                mx = fmaxf(mx, x);
            }
        mx = fmaxf(mx, __shfl_xor(mx, 16));
        mx = fmaxf(mx, __shfl_xor(mx, 32));
        float s0 = 0.f;
        #pragma unroll
        for (int ct = 0; ct < 4; ++ct)
            #pragma unroll
            for (int rr = 0; rr < 4; ++rr) {
                float e = __expf(p[ct][rr] - mx);
                p[ct][rr] = e; s0 += e;
            }
        s0 += __shfl_xor(s0, 16);
        s0 += __shfl_xor(s0, 32);
        float inv = 1.0f / s0;

        union { u32 u[4]; bf16x8 v; } pb[2];
        #pragma unroll
        for (int ks = 0; ks < 2; ++ks) {
            pb[ks].u[0] = pk2bf(p[2*ks][0] * inv, p[2*ks][1] * inv);
            pb[ks].u[1] = pk2bf(p[2*ks][2] * inv, p[2*ks][3] * inv);
            pb[ks].u[2] = pk2bf(p[2*ks+1][0] * inv, p[2*ks+1][1] * inv);
            pb[ks].u[3] = pk2bf(p[2*ks+1][2] * inv, p[2*ks+1][3] * inv);
        }

        __builtin_amdgcn_s_setprio(1);
        f32x4 oacc[8] = {};
        #pragma unroll
        for (int dt = 0; dt < 8; ++dt) {
            #pragma unroll
            for (int ks = 0; ks < 2; ++ks) {
                int d = dt * 16 + l15;
                int c2 = ks * 4 + lg;
                bf16x8 vb = *(const bf16x8*)(smem + 32768 + d * 128 + ((c2 ^ swz8(d)) * 16));
                oacc[dt] = mfma16(vb, pb[ks].v, oacc[dt]);
            }
        }
        __builtin_amdgcn_s_setprio(0);

        const int i = istrip + l15;
        if (i < IMG) {
            int im = n * 14 + (i >> 2);
            long pp = (branch == 0) ? (long)rc * IMG + im : (long)im * IMG + rc;
            u16* dst = S + ((long)b * HW + pp) * 512 + (i & 3) * 128;
            #pragma unroll
            for (int dt = 0; dt < 8; ++dt) {
                int d4 = dt * 16 + lg * 4;
                *(uint2*)(dst + d4) = make_uint2(pk2bf(oacc[dt][0], oacc[dt][1]),
                                                 pk2bf(oacc[dt][2], oacc[dt][3]));
            }
        }
    }
}

// ---------------------------------------------------------------------------
// tail: fused out-proj(X,Y) + cp + m1/GELU + m2 + final transpose to d_out.
// NET never leaves LDS; final f32 output transposed in LDS ([256c][65f32]
// pitch -> ~2-way banks) and streamed m-major: thread t owns channel t.
// LDS phases (81920):
//  P1: actX@0 8K | actY@8192 8K | xpW@16384 16K | ypW@32768 16K | AXY@49152 32K
//  P2: cpW@16384 32K (reads AXY) -> NET@16384 32K (after last sync)
//  P3: m1W@0 16K | H@49152 16K | m2W waves01@0, waves23@65536
//  P4: out f32 [256][65] @0 (66560B)
// ---------------------------------------------------------------------------
__global__ __launch_bounds__(256, 2) void tail(
    const u16* __restrict__ Wb, const float* __restrict__ Bc,
    const u16* __restrict__ SbX, const u16* __restrict__ SbY,
    const u16* __restrict__ Xt,
    const float* __restrict__ ls1, const float* __restrict__ ls2,
    float* __restrict__ y)
{
    __shared__ __align__(16) char smem[81920];
    const int tid = threadIdx.x;
    const int lane = tid & 63, wid = tid >> 6;
    const int l15 = lane & 15, lg = lane >> 4;
    const int P0 = blockIdx.x * 64;
    const int b  = blockIdx.z;

    const u16* xp  = Wb + 393216;
    const u16* yp  = Wb + 458752;
    const u16* cpw = Wb + 524288;
    const u16* m1w = Wb + 589824;
    const u16* m2w = Wb + 720896;

    // ================= phase 1: out-projection X|Y -> AXY LDS =================
    f32x4 acc[4][4] = {};
    for (int ko = 0; ko < 512; ko += 64) {
        #pragma unroll
        for (int t = 0; t < 2; ++t) {
            int row = wid * 16 + t * 8 + (lane >> 3);
            int c = (lane & 7) ^ swz8(row);
            long prow = (long)b * HW + P0 + row;
            gl_lds(SbX + prow * 512 + ko + c * 8, smem + wid * 2048 + t * 1024);
            gl_lds(SbY + prow * 512 + ko + c * 8, smem + 8192 + wid * 2048 + t * 1024);
        }
        #pragma unroll
        for (int t = 0; t < 4; ++t) {
            int row = wid * 32 + t * 8 + (lane >> 3);
            int c = (lane & 7) ^ swz8(row);
            gl_lds(xp + (long)row * 512 + ko + c * 8, smem + 16384 + wid * 4096 + t * 1024);
            gl_lds(yp + (long)row * 512 + ko + c * 8, smem + 32768 + wid * 4096 + t * 1024);
        }
        __syncthreads();

        const int actb = (wid < 2) ? 0 : 8192;
        const int wbse = (wid < 2) ? 16384 : 32768;
        const int wrow0 = (wid & 1) * 64;
        #pragma unroll
        for (int ks = 0; ks < 2; ++ks) {
            int ch = ks * 4 + lg;
            bf16x8 af[4], bfr[4];
            #pragma unroll
            for (int rt = 0; rt < 4; ++rt) {
                int row = rt * 16 + l15;
                af[rt] = *(const bf16x8*)(smem + actb + row * 128 + ((ch ^ swz8(row)) * 16));
            }
            #pragma unroll
            for (int ct = 0; ct < 4; ++ct) {
                int row = wrow0 + ct * 16 + l15;
                bfr[ct] = *(const bf16x8*)(smem + wbse + row * 128 + ((ch ^ swz8(row)) * 16));
            }
            #pragma unroll
            for (int rt = 0; rt < 4; ++rt)
                #pragma unroll
                for (int ct = 0; ct < 4; ++ct)
                    acc[rt][ct] = mfma16(bfr[ct], af[rt], acc[rt][ct]);
        }
        __syncthreads();
    }

    #pragma unroll
    for (int rt = 0; rt < 4; ++rt) {
        int pl = rt * 16 + l15;
        long rowp = (long)b * HW + P0 + pl;
        #pragma unroll
        for (int ct = 0; ct < 4; ++ct) {
            int mg2 = wid * 64 + ct * 16 + lg * 4;
            float4 bv = *(const float4*)(Bc + 3072 + mg2);
            ushort4 rv = *(const ushort4*)(Xt + rowp * 256 + mg2);
            float v0 = acc[rt][ct][0] + bv.x + bf2f(rv.x);
            float v1 = acc[rt][ct][1] + bv.y + bf2f(rv.y);
            float v2 = acc[rt][ct][2] + bv.z + bf2f(rv.z);
            float v3 = acc[rt][ct][3] + bv.w + bf2f(rv.w);
            int cc = mg2 >> 3;
            int pos = (cc & 24) | ((cc ^ swz8(pl)) & 7);
            *(uint2*)(smem + 49152 + pl * 512 + pos * 16 + (mg2 & 7) * 2)
                = make_uint2(pk2bf(v0, v1), pk2bf(v2, v3));
        }
    }
    __syncthreads();

    // ================= phase 2: cp -> NET LDS =================
    f32x4 acc2[4][4] = {};
    for (int ko = 0; ko < 256; ko += 64) {
        #pragma unroll
        for (int t = 0; t < 8; ++t) {
            int row = wid * 64 + t * 8 + (lane >> 3);
            int c = (lane & 7) ^ swz8(row);
            gl_lds(cpw + (long)row * 256 + ko + c * 8, smem + 16384 + wid * 8192 + t * 1024);
        }
        __syncthreads();

        #pragma unroll
        for (int ks = 0; ks < 2; ++ks) {
            int ch = ks * 4 + lg;
            bf16x8 af[4], bfr[4];
            #pragma unroll
            for (int rt = 0; rt < 4; ++rt) {
                int row = rt * 16 + l15;
                int c = (ko >> 3) + ch;
                int pos = (c & 24) | ((c ^ swz8(row)) & 7);
                af[rt] = *(const bf16x8*)(smem + 49152 + row * 512 + pos * 16);
            }
            #pragma unroll
            for (int ct = 0; ct < 4; ++ct) {
                int row = wid * 64 + ct * 16 + l15;
                bfr[ct] = *(const bf16x8*)(smem + 16384 + row * 128 + ((ch ^ swz8(row)) * 16));
            }
            #pragma unroll
            for (int rt = 0; rt < 4; ++rt)
                #pragma unroll
                for (int ct = 0; ct < 4; ++ct)
                    acc2[rt][ct] = mfma16(bfr[ct], af[rt], acc2[rt][ct]);
        }
        __syncthreads();
    }

    // NET = ls1*(cp+b) + Xt -> LDS @16384 (rows [64][512B], swizzled)
    #pragma unroll
    for (int rt = 0; rt < 4; ++rt) {
        int pl = rt * 16 + l15;
        long rowp = (long)b * HW + P0 + pl;
        #pragma unroll
        for (int ct = 0; ct < 4; ++ct) {
            int mg = wid * 64 + ct * 16 + lg * 4;
            float4 bv = *(const float4*)(Bc + 3328 + mg);
            float4 sv = *(const float4*)(ls1 + mg);
            ushort4 rv = *(const ushort4*)(Xt + rowp * 256 + mg);
            float v0 = (acc2[rt][ct][0] + bv.x) * sv.x + bf2f(rv.x);
            float v1 = (acc2[rt][ct][1] + bv.y) * sv.y + bf2f(rv.y);
            float v2 = (acc2[rt][ct][2] + bv.z) * sv.z + bf2f(rv.z);
            float v3 = (acc2[rt][ct][3] + bv.w) * sv.w + bf2f(rv.w);
            int cc = mg >> 3;
            int pos = (cc & 24) | ((cc ^ swz8(pl)) & 7);
            *(uint2*)(smem + 16384 + pl * 512 + pos * 16 + (mg & 7) * 2)
                = make_uint2(pk2bf(v0, v1), pk2bf(v2, v3));
        }
    }

    // ================= phase 3: m1 + GELU + m2 =================
    f32x4 aco[4][4] = {};

    for (int hc = 0; hc < 4; ++hc) {
        // m1 chunk -> H
        f32x4 ach[4][2] = {};
        for (int ko = 0; ko < 256; ko += 64) {
            #pragma unroll
            for (int t = 0; t < 4; ++t) {
                int row = wid * 32 + t * 8 + (lane >> 3);
                int c = (lane & 7) ^ swz8(row);
                gl_lds(m1w + (long)(hc * 128 + row) * 256 + ko + c * 8,
                       smem + wid * 4096 + t * 1024);
            }
            __syncthreads();

            #pragma unroll
            for (int ks = 0; ks < 2; ++ks) {
                int ch = ks * 4 + lg;
                bf16x8 af[4], bfrh[2];
                #pragma unroll
                for (int rt = 0; rt < 4; ++rt) {
                    int row = rt * 16 + l15;
                    int c = (ko >> 3) + ch;
                    int pos = (c & 24) | ((c ^ swz8(row)) & 7);
                    af[rt] = *(const bf16x8*)(smem + 16384 + row * 512 + pos * 16);
                }
                #pragma unroll
                for (int mt = 0; mt < 2; ++mt) {
                    int row = wid * 32 + mt * 16 + l15;
                    bfrh[mt] = *(const bf16x8*)(smem + row * 128 + ((ch ^ swz8(row)) * 16));
                }
                #pragma unroll
                for (int rt = 0; rt < 4; ++rt)
                    #pragma unroll
                    for (int mt = 0; mt < 2; ++mt)
                        ach[rt][mt] = mfma16(bfrh[mt], af[rt], ach[rt][mt]);
            }
            __syncthreads();
        }
        // H = gelu(m1+b) -> LDS @49152 (rows [64][256B])
        #pragma unroll
        for (int rt = 0; rt < 4; ++rt) {
            int pl = rt * 16 + l15;
            #pragma unroll
            for (int mt = 0; mt < 2; ++mt) {
                int hloc = wid * 32 + mt * 16 + lg * 4;
                float4 bv = *(const float4*)(Bc + 3584 + hc * 128 + hloc);
                float v[4];
                #pragma unroll
                for (int j = 0; j < 4; ++j) {
                    float tt = ach[rt][mt][j] + ((const float*)&bv)[j];
                    v[j] = tt * 0.5f * (1.0f + erff(tt * 0.70710678118f));
                }
                int cc = hloc >> 3;
                int pos = (cc & 8) | ((cc ^ swz8(pl)) & 7);
                *(uint2*)(smem + 49152 + pl * 256 + pos * 16 + (hloc & 7) * 2)
                    = make_uint2(pk2bf(v[0], v[1]), pk2bf(v[2], v[3]));
            }
        }

        // m2 partial: aco += m2W[:, hc*128..] @ H
        for (int ko = 0; ko < 128; ko += 64) {
            #pragma unroll
            for (int t = 0; t < 8; ++t) {
                int row = wid * 64 + t * 8 + (lane >> 3);
                int c = (lane & 7) ^ swz8(row);
                char* dst = ((wid < 2) ? (smem + wid * 8192) : (smem + 65536 + (wid - 2) * 8192))
                            + t * 1024;
                gl_lds(m2w + (long)row * 512 + hc * 128 + ko + c * 8, dst);
            }
            __syncthreads();

            #pragma unroll
            for (int ks = 0; ks < 2; ++ks) {
                int ch = ks * 4 + lg;
                bf16x8 af[4], bfr[4];
                #pragma unroll
                for (int rt = 0; rt < 4; ++rt) {
                    int row = rt * 16 + l15;
                    int c = (ko >> 3) + ch;
                    int pos = (c & 8) | ((c ^ swz8(row)) & 7);
                    af[rt] = *(const bf16x8*)(smem + 49152 + row * 256 + pos * 16);
                }
                #pragma unroll
                for (int ct = 0; ct < 4; ++ct) {
                    int row = wid * 64 + ct * 16 + l15;
                    const char* base = (wid < 2) ? smem : (smem + 65536 - 16384);
                    bfr[ct] = *(const bf16x8*)(base + row * 128 + ((ch ^ swz8(row)) * 16));
                }
                #pragma unroll
                for (int rt = 0; rt < 4; ++rt)
                    #pragma unroll
                    for (int ct = 0; ct < 4; ++ct)
                        aco[rt][ct] = mfma16(bfr[ct], af[rt], aco[rt][ct]);
            }
            __syncthreads();
        }
    }

    // ======== phase 4: +b2, *ls2, +NET (LDS) then transpose-write d_out ======
    #pragma unroll
    for (int rt = 0; rt < 4; ++rt) {
        int pl = rt * 16 + l15;
        #pragma unroll
        for (int ct = 0; ct < 4; ++ct) {
            int mg = wid * 64 + ct * 16 + lg * 4;
            float4 bv = *(const float4*)(Bc + 4096 + mg);
            float4 sv = *(const float4*)(ls2 + mg);
            int cc = mg >> 3;
            int pos = (cc & 24) | ((cc ^ swz8(pl)) & 7);
            uint2 nv2 = *(const uint2*)(smem + 16384 + pl * 512 + pos * 16 + (mg & 7) * 2);
            u16 nv[4] = { (u16)(nv2.x & 0xffff), (u16)(nv2.x >> 16),
                          (u16)(nv2.y & 0xffff), (u16)(nv2.y >> 16) };
            aco[rt][ct][0] = (aco[rt][ct][0] + bv.x) * sv.x + bf2f(nv[0]);
            aco[rt][ct][1] = (aco[rt][ct][1] + bv.y) * sv.y + bf2f(nv[1]);
            aco[rt][ct][2] = (aco[rt][ct][2] + bv.z) * sv.z + bf2f(nv[2]);
            aco[rt][ct][3] = (aco[rt][ct][3] + bv.w) * sv.w + bf2f(nv[3]);
        }
    }
    __syncthreads();   // all NET reads done -> whole LDS free for f32 tile

    #pragma unroll
    for (int rt = 0; rt < 4; ++rt) {
        int pl = rt * 16 + l15;
        #pragma unroll
        for (int ct = 0; ct < 4; ++ct) {
            int mg = wid * 64 + ct * 16 + lg * 4;
            #pragma unroll
            for (int j = 0; j < 4; ++j)
                ((float*)smem)[(mg + j) * 65 + pl] = aco[rt][ct][j];
        }
    }
    __syncthreads();

    {   // thread t streams channel t: 64 contiguous floats -> d_out
        const float* srcr = (const float*)smem + tid * 65;
        float* dst = y + ((long)(b * 256 + tid)) * HW + P0;
        #pragma unroll
        for (int k = 0; k < 16; ++k)
            *(float4*)(dst + k * 4) = *(const float4*)(srcr + k * 4);
    }
}

// ---------------------------------------------------------------------------
extern "C" void kernel_launch(void* const* d_in, const int* in_sizes, int n_in,
                              void* d_out, int out_size, void* d_ws, size_t ws_size,
                              hipStream_t stream)
{
    const float* x     = (const float*)d_in[0];
    const float* xq_w  = (const float*)d_in[1];
    const float* xq_b  = (const float*)d_in[2];
    const float* xk_w  = (const float*)d_in[3];
    const float* xk_b  = (const float*)d_in[4];
    const float* xv_w  = (const float*)d_in[5];
    const float* xv_b  = (const float*)d_in[6];
    const float* xp_w  = (const float*)d_in[7];
    const float* xp_b  = (const float*)d_in[8];
    const float* rel_x = (const float*)d_in[9];
    const float* yq_w  = (const float*)d_in[10];
    const float* yq_b  = (const float*)d_in[11];
    const float* yk_w  = (const float*)d_in[12];
    const float* yk_b  = (const float*)d_in[13];
    const float* yv_w  = (const float*)d_in[14];
    const float* yv_b  = (const float*)d_in[15];
    const float* yp_w  = (const float*)d_in[16];
    const float* yp_b  = (const float*)d_in[17];
    const float* rel_y = (const float*)d_in[18];
    const float* cp_w  = (const float*)d_in[19];
    const float* cp_b  = (const float*)d_in[20];
    const float* m1_w  = (const float*)d_in[21];
    const float* m1_b  = (const float*)d_in[22];
    const float* m2_w  = (const float*)d_in[23];
    const float* m2_b  = (const float*)d_in[24];
    const float* ls1   = (const float*)d_in[25];
    const float* ls2   = (const float*)d_in[26];

    if (ws_size < 128450560) return;

    char* ws = (char*)d_ws;
    u16*   SbY  = (u16*)(ws + 0);             // [8][3136][512] bf16
    u16*   Wb   = (u16*)(ws + 25690112);      // 851968 bf16
    float* Bc   = (float*)(ws + 27394048);    // 4352 f32
    u16*   Xt   = (u16*)(ws + 77070336);      // [8][3136][256] bf16
    u16*   SbX  = (u16*)(ws + 89915392);      // [8][3136][512] bf16

    dim3 blk(256, 1, 1);

    // merged wcvt + transpose_x
    prep<<<dim3(2401, 1, 1), blk, 0, stream>>>(
        x, Xt,
        xq_w, xk_w, xv_w, yq_w, yk_w, yv_w, xp_w, yp_w, cp_w, m1_w, m2_w,
        xq_b, xk_b, xv_b, yq_b, yk_b, yv_b, xp_b, yp_b, cp_b, m1_b, m2_b,
        Wb, Bc);
    fused_attn<<<dim3(8, 4, 16), blk, 0, stream>>>(Wb, Bc, Xt, rel_x, rel_y, SbX, SbY);
    // out-proj X+Y + cp + m1/GELU + m2 + output transpose, straight to d_out
    tail<<<dim3(49, 1, 8), blk, 0, stream>>>(Wb, Bc, SbX, SbY, Xt, ls1, ls2, (float*)d_out);
}

// Round 18
// 132.033 us; speedup vs baseline: 1.8369x; 1.0054x over previous
//
#include <hip/hip_runtime.h>

using u16 = unsigned short;
using u32 = unsigned int;

typedef short bf16x8 __attribute__((ext_vector_type(8)));
typedef float f32x4 __attribute__((ext_vector_type(4)));

#define HW 3136
#define IMG 56

__device__ __forceinline__ float bf2f(u16 v) {
    union { u32 u; float f; } c; c.u = ((u32)v) << 16; return c.f;
}
__device__ __forceinline__ u16 f2bf(float f) {
    union { float f; u32 u; } c; c.f = f;
    return (u16)((c.u + 0x7fffu + ((c.u >> 16) & 1u)) >> 16);
}
// pack 2 f32 -> 2 bf16 in one u32 (RNE, hardware cvt)
__device__ __forceinline__ u32 pk2bf(float a, float b) {
    u32 r;
    asm("v_cvt_pk_bf16_f32 %0, %1, %2" : "=v"(r) : "v"(a), "v"(b));
    return r;
}
__device__ __forceinline__ int swz8(int r) { return (r ^ (r >> 3)) & 7; }

__device__ __forceinline__ f32x4 mfma16(bf16x8 a, bf16x8 b, f32x4 c) {
    return __builtin_amdgcn_mfma_f32_16x16x32_bf16(a, b, c, 0, 0, 0);
}

// async global->LDS, 16B per lane; dest = lds_base + lane*16 (wave-uniform base)
__device__ __forceinline__ void gl_lds(const void* g, void* l) {
    __builtin_amdgcn_global_load_lds((const __attribute__((address_space(1))) void*)g,
                                     (__attribute__((address_space(3))) void*)l, 16, 0, 0);
}

// ---------------------------------------------------------------------------
// prep: merged wcvt + transpose_x.
// ---------------------------------------------------------------------------
__global__ __launch_bounds__(256) void prep(
    const float* __restrict__ x, u16* __restrict__ Xt,
    const float* __restrict__ s0, const float* __restrict__ s1, const float* __restrict__ s2,
    const float* __restrict__ s3, const float* __restrict__ s4, const float* __restrict__ s5,
    const float* __restrict__ s6, const float* __restrict__ s7, const float* __restrict__ s8,
    const float* __restrict__ s9, const float* __restrict__ s10,
    const float* __restrict__ b0, const float* __restrict__ b1, const float* __restrict__ b2,
    const float* __restrict__ b3, const float* __restrict__ b4, const float* __restrict__ b5,
    const float* __restrict__ b6, const float* __restrict__ b7, const float* __restrict__ b8,
    const float* __restrict__ b9, const float* __restrict__ b10,
    u16* __restrict__ Wb, float* __restrict__ Bc)
{
    __shared__ u16 lds[64][80];
    const int t = threadIdx.x;
    const int idx = blockIdx.x;

    if (idx < 1568) {   // transpose path
        const int Pb = (idx % 49) * 64;
        const int Cb = ((idx / 49) & 3) * 64;
        const int b  = idx / 196;
        #pragma unroll
        for (int q = 0; q < 4; ++q) {
            int id = t + q * 256;
            int c = id >> 4, pf = (id & 15) * 4;
            float4 v = *(const float4*)(x + ((long)(b * 256 + Cb + c)) * HW + Pb + pf);
            u16 vv[4] = { f2bf(v.x), f2bf(v.y), f2bf(v.z), f2bf(v.w) };
            #pragma unroll
            for (int j = 0; j < 4; ++j) {
                int p = pf + j;
                int cc = (((c >> 3) ^ ((p >> 2) & 7)) << 3) + (c & 7);
                lds[p][cc] = vv[j];
            }
        }
        __syncthreads();
        int p = t >> 2, cf = (t & 3) * 16;
        u16* dst = Xt + ((long)b * HW + Pb + p) * 256 + Cb + cf;
        int cc0 = ((cf >> 3) + 0) ^ ((p >> 2) & 7);
        int cc1 = ((cf >> 3) + 1) ^ ((p >> 2) & 7);
        *(uint4*)(dst + 0) = *(uint4*)&lds[p][cc0 * 8];
        *(uint4*)(dst + 8) = *(uint4*)&lds[p][cc1 * 8];
        return;
    }

    const int bx = idx - 1568;          // wcvt path, 0..832
    if (bx == 832) {                    // biases
        for (int i = t; i < 4352; i += 256) {
            const float* src; int off;
            if      (i < 512)  { src = b0;  off = i; }
            else if (i < 1024) { src = b1;  off = i - 512; }
            else if (i < 1536) { src = b2;  off = i - 1024; }
            else if (i < 2048) { src = b3;  off = i - 1536; }
            else if (i < 2560) { src = b4;  off = i - 2048; }
            else if (i < 3072) { src = b5;  off = i - 2560; }
            else if (i < 3200) { src = b6;  off = i - 3072; }
            else if (i < 3328) { src = b7;  off = i - 3200; }
            else if (i < 3584) { src = b8;  off = i - 3328; }
            else if (i < 4096) { src = b9;  off = i - 3584; }
            else               { src = b10; off = i - 4096; }
            Bc[i] = src[off];
        }
        return;
    }
    long gid4 = ((long)bx * 256 + t) * 4;
    const float* src; long off;
    if (gid4 < 589824) {
        int seg = (int)(gid4 >> 16);
        const float* tab[9] = { s0, s1, s2, s3, s4, s5, s6, s7, s8 };
        src = tab[seg]; off = gid4 - ((long)seg << 16);
    } else if (gid4 < 720896) { src = s9;  off = gid4 - 589824; }
    else                      { src = s10; off = gid4 - 720896; }
    float4 v = *(const float4*)(src + off);
    *(uint2*)(Wb + gid4) = make_uint2(pk2bf(v.x, v.y), pk2bf(v.z, v.w));
}

// ---------------------------------------------------------------------------
// fused_attn: QKV projection + axial attention (round-17 verified).
// LDS: QT[0,16K) KT[16K,32K) V[32K,48K) X[49152,65536) RELf32[65536,66048).
// ---------------------------------------------------------------------------
__global__ __launch_bounds__(256, 2) void fused_attn(
    const u16* __restrict__ Wb, const float* __restrict__ Bc,
    const u16* __restrict__ Xt,
    const float* __restrict__ rel_x, const float* __restrict__ rel_y,
    u16* __restrict__ SbX, u16* __restrict__ SbY)
{
    __shared__ __align__(16) char smem[66048];
    const int tid = threadIdx.x;
    const int lane = tid & 63, wid = tid >> 6;
    const int l15 = lane & 15, lg = lane >> 4;

    const int g = blockIdx.x;            // bid%8 = g -> per-XCD L2 partition
    const int n = blockIdx.y;
    const int branch = blockIdx.z >> 3;
    const int b = blockIdx.z & 7;

    const float* rel = branch ? rel_y : rel_x;
    u16* S = branch ? SbY : SbX;
    const u16* wsrc = Wb + branch * 196608 + n * 16384;
    const float* bsrc = Bc + branch * 1536 + n * 128;

    if (tid < 128) {
        float v = (tid < 112) ? rel[n * HW + tid] : 0.0f;
        *(float*)(smem + 65536 + tid * 4) = v;
    }

    bf16x8 wf[3][2][4];
    #pragma unroll
    for (int mat = 0; mat < 3; ++mat)
        #pragma unroll
        for (int mt = 0; mt < 2; ++mt) {
            int mrow = (wid * 2 + mt) * 16 + l15;
            const u16* wr = wsrc + mat * 65536 + mrow * 128;
            #pragma unroll
            for (int ks = 0; ks < 4; ++ks)
                wf[mat][mt][ks] = *(const bf16x8*)(wr + (ks * 4 + lg) * 8);
        }
    float4 bq4[2], bk4[2]; float bvv[2];
    #pragma unroll
    for (int mt = 0; mt < 2; ++mt) {
        int m0 = (wid * 2 + mt) * 16 + lg * 4;
        bq4[mt] = *(const float4*)(bsrc + m0);
        bk4[mt] = *(const float4*)(bsrc + 512 + m0);
        bvv[mt] = bsrc[1024 + (wid * 2 + mt) * 16 + l15];
    }

    const int istrip = wid * 16;
    const float qscale = 0.08838834764831845f;

    auto stageX = [&](int rc2) {
        const int i0 = wid * 16 + (lane >> 4);
        #pragma unroll
        for (int t = 0; t < 4; ++t) {
            int i = i0 + t * 4;
            int ic = (i > 55) ? 55 : i;
            long p = (branch == 0) ? (long)rc2 * IMG + ic : (long)ic * IMG + rc2;
            const u16* src = Xt + ((long)b * HW + p) * 256 + branch * 128
                             + (((lane & 15) ^ swz8(i)) * 8);
            gl_lds(src, smem + 49152 + wid * 4096 + t * 1024);
        }
    };

    stageX(g * 7);

    for (int r = 0; r < 7; ++r) {
        const int rc = g * 7 + r;

        __syncthreads();   // A: X(r) staged + prev LDS reads done

        bf16x8 xf[4][4];
        #pragma unroll
        for (int it = 0; it < 4; ++it) {
            int i = it * 16 + l15;
            #pragma unroll
            for (int ks = 0; ks < 4; ++ks)
                xf[it][ks] = *(const bf16x8*)(smem + 49152 + i * 256
                                              + (((ks * 4 + lg) ^ swz8(i)) * 16));
        }

        __builtin_amdgcn_s_setprio(1);
        #pragma unroll
        for (int mat = 0; mat < 2; ++mat) {
            #pragma unroll
            for (int mt = 0; mt < 2; ++mt) {
                #pragma unroll
                for (int it = 0; it < 4; ++it) {
                    f32x4 a = {};
                    #pragma unroll
                    for (int ks = 0; ks < 4; ++ks)
                        a = mfma16(wf[mat][mt][ks], xf[it][ks], a);
                    int i = it * 16 + l15;
                    int m0 = (wid * 2 + mt) * 16 + lg * 4;
                    float4 bb2 = mat ? bk4[mt] : bq4[mt];
                    int c = m0 >> 3;
                    *(uint2*)(smem + mat * 16384 + i * 256 + ((c ^ swz8(i)) * 16) + (lg & 1) * 8)
                        = make_uint2(pk2bf(a[0] + bb2.x, a[1] + bb2.y),
                                     pk2bf(a[2] + bb2.z, a[3] + bb2.w));
                }
            }
        }
        #pragma unroll
        for (int mt = 0; mt < 2; ++mt) {
            #pragma unroll
            for (int it = 0; it < 4; ++it) {
                f32x4 a = {};
                #pragma unroll
                for (int ks = 0; ks < 4; ++ks)
                    a = mfma16(xf[it][ks], wf[2][mt][ks], a);
                int d = (wid * 2 + mt) * 16 + l15;
                int c2 = (it >> 1) * 4 + lg;
                float bv = bvv[mt];
                *(uint2*)(smem + 32768 + d * 128 + ((c2 ^ swz8(d)) * 16) + (it & 1) * 8)
                    = make_uint2(pk2bf(a[0] + bv, a[1] + bv),
                                 pk2bf(a[2] + bv, a[3] + bv));
            }
        }
        __builtin_amdgcn_s_setprio(0);
        __syncthreads();   // B: proj visible; X region free

        if (r < 6) stageX(rc + 1);   // overlaps QK/softmax/PV (T14)

        bf16x8 aq[4];
        #pragma unroll
        for (int ks = 0; ks < 4; ++ks) {
            int row = istrip + l15;
            int ch = ks * 4 + lg;
            aq[ks] = *(const bf16x8*)(smem + row * 256 + ((ch ^ swz8(row)) * 16));
        }
        __builtin_amdgcn_s_setprio(1);
        f32x4 sacc[4] = {};
        #pragma unroll
        for (int ct = 0; ct < 4; ++ct) {
            #pragma unroll
            for (int ks = 0; ks < 4; ++ks) {
                int j = ct * 16 + l15;
                int ch = ks * 4 + lg;
                bf16x8 kb = *(const bf16x8*)(smem + 16384 + j * 256 + ((ch ^ swz8(j)) * 16));
                sacc[ct] = mfma16(kb, aq[ks], sacc[ct]);
            }
        }
        __builtin_amdgcn_s_setprio(0);

        const int irow = istrip + l15;
        float p[4][4];
        float mx = -1e30f;
        #pragma unroll
        for (int ct = 0; ct < 4; ++ct)
            #pragma unroll
            for (int rr = 0; rr < 4; ++rr) {
                int j = ct * 16 + lg * 4 + rr;
                float x = sacc[ct][rr] * qscale;
                if (j < IMG) x += *(const float*)(smem + 65536 + (irow - j + 55) * 4);
                else x = -1e30f;
                p[ct][rr] = x;
                mx = fmaxf(mx, x);
            }
        mx = fmaxf(mx, __shfl_xor(mx, 16));
        mx = fmaxf(mx, __shfl_xor(mx, 32));
        float s0 = 0.f;
        #pragma unroll
        for (int ct = 0; ct < 4; ++ct)
            #pragma unroll
            for (int rr = 0; rr < 4; ++rr) {
                float e = __expf(p[ct][rr] - mx);
                p[ct][rr] = e; s0 += e;
            }
        s0 += __shfl_xor(s0, 16);
        s0 += __shfl_xor(s0, 32);
        float inv = 1.0f / s0;

        union { u32 u[4]; bf16x8 v; } pb[2];
        #pragma unroll
        for (int ks = 0; ks < 2; ++ks) {
            pb[ks].u[0] = pk2bf(p[2*ks][0] * inv, p[2*ks][1] * inv);
            pb[ks].u[1] = pk2bf(p[2*ks][2] * inv, p[2*ks][3] * inv);
            pb[ks].u[2] = pk2bf(p[2*ks+1][0] * inv, p[2*ks+1][1] * inv);
            pb[ks].u[3] = pk2bf(p[2*ks+1][2] * inv, p[2*ks+1][3] * inv);
        }

        __builtin_amdgcn_s_setprio(1);
        f32x4 oacc[8] = {};
        #pragma unroll
        for (int dt = 0; dt < 8; ++dt) {
            #pragma unroll
            for (int ks = 0; ks < 2; ++ks) {
                int d = dt * 16 + l15;
                int c2 = ks * 4 + lg;
                bf16x8 vb = *(const bf16x8*)(smem + 32768 + d * 128 + ((c2 ^ swz8(d)) * 16));
                oacc[dt] = mfma16(vb, pb[ks].v, oacc[dt]);
            }
        }
        __builtin_amdgcn_s_setprio(0);

        const int i = istrip + l15;
        if (i < IMG) {
            int im = n * 14 + (i >> 2);
            long pp = (branch == 0) ? (long)rc * IMG + im : (long)im * IMG + rc;
            u16* dst = S + ((long)b * HW + pp) * 512 + (i & 3) * 128;
            #pragma unroll
            for (int dt = 0; dt < 8; ++dt) {
                int d4 = dt * 16 + lg * 4;
                *(uint2*)(dst + d4) = make_uint2(pk2bf(oacc[dt][0], oacc[dt][1]),
                                                 pk2bf(oacc[dt][2], oacc[dt][3]));
            }
        }
    }
}

// ---------------------------------------------------------------------------
// tail: fused out-proj(X,Y) + cp + m1/GELU + m2 + final transpose to d_out.
// P3's m1 weights double-buffered (Wbuf0 [0,16K), Wbuf1 [64K,80K)): one
// barrier per chunk, staging hidden under MFMA. NET [16K,48K), H [48K,64K).
// ---------------------------------------------------------------------------
__global__ __launch_bounds__(256, 2) void tail(
    const u16* __restrict__ Wb, const float* __restrict__ Bc,
    const u16* __restrict__ SbX, const u16* __restrict__ SbY,
    const u16* __restrict__ Xt,
    const float* __restrict__ ls1, const float* __restrict__ ls2,
    float* __restrict__ y)
{
    __shared__ __align__(16) char smem[81920];
    const int tid = threadIdx.x;
    const int lane = tid & 63, wid = tid >> 6;
    const int l15 = lane & 15, lg = lane >> 4;
    const int P0 = blockIdx.x * 64;
    const int b  = blockIdx.z;

    const u16* xp  = Wb + 393216;
    const u16* yp  = Wb + 458752;
    const u16* cpw = Wb + 524288;
    const u16* m1w = Wb + 589824;
    const u16* m2w = Wb + 720896;

    // ================= phase 1: out-projection X|Y -> AXY LDS =================
    f32x4 acc[4][4] = {};
    for (int ko = 0; ko < 512; ko += 64) {
        #pragma unroll
        for (int t = 0; t < 2; ++t) {
            int row = wid * 16 + t * 8 + (lane >> 3);
            int c = (lane & 7) ^ swz8(row);
            long prow = (long)b * HW + P0 + row;
            gl_lds(SbX + prow * 512 + ko + c * 8, smem + wid * 2048 + t * 1024);
            gl_lds(SbY + prow * 512 + ko + c * 8, smem + 8192 + wid * 2048 + t * 1024);
        }
        #pragma unroll
        for (int t = 0; t < 4; ++t) {
            int row = wid * 32 + t * 8 + (lane >> 3);
            int c = (lane & 7) ^ swz8(row);
            gl_lds(xp + (long)row * 512 + ko + c * 8, smem + 16384 + wid * 4096 + t * 1024);
            gl_lds(yp + (long)row * 512 + ko + c * 8, smem + 32768 + wid * 4096 + t * 1024);
        }
        __syncthreads();

        const int actb = (wid < 2) ? 0 : 8192;
        const int wbse = (wid < 2) ? 16384 : 32768;
        const int wrow0 = (wid & 1) * 64;
        __builtin_amdgcn_s_setprio(1);
        #pragma unroll
        for (int ks = 0; ks < 2; ++ks) {
            int ch = ks * 4 + lg;
            bf16x8 af[4], bfr[4];
            #pragma unroll
            for (int rt = 0; rt < 4; ++rt) {
                int row = rt * 16 + l15;
                af[rt] = *(const bf16x8*)(smem + actb + row * 128 + ((ch ^ swz8(row)) * 16));
            }
            #pragma unroll
            for (int ct = 0; ct < 4; ++ct) {
                int row = wrow0 + ct * 16 + l15;
                bfr[ct] = *(const bf16x8*)(smem + wbse + row * 128 + ((ch ^ swz8(row)) * 16));
            }
            #pragma unroll
            for (int rt = 0; rt < 4; ++rt)
                #pragma unroll
                for (int ct = 0; ct < 4; ++ct)
                    acc[rt][ct] = mfma16(bfr[ct], af[rt], acc[rt][ct]);
        }
        __builtin_amdgcn_s_setprio(0);
        __syncthreads();
    }

    #pragma unroll
    for (int rt = 0; rt < 4; ++rt) {
        int pl = rt * 16 + l15;
        long rowp = (long)b * HW + P0 + pl;
        #pragma unroll
        for (int ct = 0; ct < 4; ++ct) {
            int mg2 = wid * 64 + ct * 16 + lg * 4;
            float4 bv = *(const float4*)(Bc + 3072 + mg2);
            ushort4 rv = *(const ushort4*)(Xt + rowp * 256 + mg2);
            float v0 = acc[rt][ct][0] + bv.x + bf2f(rv.x);
            float v1 = acc[rt][ct][1] + bv.y + bf2f(rv.y);
            float v2 = acc[rt][ct][2] + bv.z + bf2f(rv.z);
            float v3 = acc[rt][ct][3] + bv.w + bf2f(rv.w);
            int cc = mg2 >> 3;
            int pos = (cc & 24) | ((cc ^ swz8(pl)) & 7);
            *(uint2*)(smem + 49152 + pl * 512 + pos * 16 + (mg2 & 7) * 2)
                = make_uint2(pk2bf(v0, v1), pk2bf(v2, v3));
        }
    }
    __syncthreads();

    // ================= phase 2: cp -> NET LDS =================
    f32x4 acc2[4][4] = {};
    for (int ko = 0; ko < 256; ko += 64) {
        #pragma unroll
        for (int t = 0; t < 8; ++t) {
            int row = wid * 64 + t * 8 + (lane >> 3);
            int c = (lane & 7) ^ swz8(row);
            gl_lds(cpw + (long)row * 256 + ko + c * 8, smem + 16384 + wid * 8192 + t * 1024);
        }
        __syncthreads();

        __builtin_amdgcn_s_setprio(1);
        #pragma unroll
        for (int ks = 0; ks < 2; ++ks) {
            int ch = ks * 4 + lg;
            bf16x8 af[4], bfr[4];
            #pragma unroll
            for (int rt = 0; rt < 4; ++rt) {
                int row = rt * 16 + l15;
                int c = (ko >> 3) + ch;
                int pos = (c & 24) | ((c ^ swz8(row)) & 7);
                af[rt] = *(const bf16x8*)(smem + 49152 + row * 512 + pos * 16);
            }
            #pragma unroll
            for (int ct = 0; ct < 4; ++ct) {
                int row = wid * 64 + ct * 16 + l15;
                bfr[ct] = *(const bf16x8*)(smem + 16384 + row * 128 + ((ch ^ swz8(row)) * 16));
            }
            #pragma unroll
            for (int rt = 0; rt < 4; ++rt)
                #pragma unroll
                for (int ct = 0; ct < 4; ++ct)
                    acc2[rt][ct] = mfma16(bfr[ct], af[rt], acc2[rt][ct]);
        }
        __builtin_amdgcn_s_setprio(0);
        __syncthreads();
    }

    // NET = ls1*(cp+b) + Xt -> LDS @16384 (rows [64][512B], swizzled)
    #pragma unroll
    for (int rt = 0; rt < 4; ++rt) {
        int pl = rt * 16 + l15;
        long rowp = (long)b * HW + P0 + pl;
        #pragma unroll
        for (int ct = 0; ct < 4; ++ct) {
            int mg = wid * 64 + ct * 16 + lg * 4;
            float4 bv = *(const float4*)(Bc + 3328 + mg);
            float4 sv = *(const float4*)(ls1 + mg);
            ushort4 rv = *(const ushort4*)(Xt + rowp * 256 + mg);
            float v0 = (acc2[rt][ct][0] + bv.x) * sv.x + bf2f(rv.x);
            float v1 = (acc2[rt][ct][1] + bv.y) * sv.y + bf2f(rv.y);
            float v2 = (acc2[rt][ct][2] + bv.z) * sv.z + bf2f(rv.z);
            float v3 = (acc2[rt][ct][3] + bv.w) * sv.w + bf2f(rv.w);
            int cc = mg >> 3;
            int pos = (cc & 24) | ((cc ^ swz8(pl)) & 7);
            *(uint2*)(smem + 16384 + pl * 512 + pos * 16 + (mg & 7) * 2)
                = make_uint2(pk2bf(v0, v1), pk2bf(v2, v3));
        }
    }

    // ================= phase 3: m1 + GELU + m2 (m1W double-buffered) =========
    f32x4 aco[4][4] = {};

    // initial stage: m1W(hc=0, chunk0) -> buf0 ([0,16K) dead since P1)
    #pragma unroll
    for (int t = 0; t < 4; ++t) {
        int row = wid * 32 + t * 8 + (lane >> 3);
        int c = (lane & 7) ^ swz8(row);
        gl_lds(m1w + (long)row * 256 + c * 8, smem + wid * 4096 + t * 1024);
    }

    for (int hc = 0; hc < 4; ++hc) {
        f32x4 ach[4][2] = {};
        #pragma unroll
        for (int idx = 0; idx < 4; ++idx) {
            __syncthreads();   // cur buf staged; prior reads done
            if (idx < 3) {     // stage next chunk into other buf (hidden)
                char* nbuf = ((idx & 1) == 0) ? (smem + 65536) : smem;
                #pragma unroll
                for (int t = 0; t < 4; ++t) {
                    int row = wid * 32 + t * 8 + (lane >> 3);
                    int c = (lane & 7) ^ swz8(row);
                    gl_lds(m1w + (long)(hc * 128 + row) * 256 + (idx + 1) * 64 + c * 8,
                           nbuf + wid * 4096 + t * 1024);
                }
            }
            const char* cbuf = ((idx & 1) == 0) ? smem : (smem + 65536);
            const int ko = idx * 64;
            __builtin_amdgcn_s_setprio(1);
            #pragma unroll
            for (int ks = 0; ks < 2; ++ks) {
                int ch = ks * 4 + lg;
                bf16x8 af[4], bfrh[2];
                #pragma unroll
                for (int rt = 0; rt < 4; ++rt) {
                    int row = rt * 16 + l15;
                    int c = (ko >> 3) + ch;
                    int pos = (c & 24) | ((c ^ swz8(row)) & 7);
                    af[rt] = *(const bf16x8*)(smem + 16384 + row * 512 + pos * 16);
                }
                #pragma unroll
                for (int mt = 0; mt < 2; ++mt) {
                    int row = wid * 32 + mt * 16 + l15;
                    bfrh[mt] = *(const bf16x8*)(cbuf + row * 128 + ((ch ^ swz8(row)) * 16));
                }
                #pragma unroll
                for (int rt = 0; rt < 4; ++rt)
                    #pragma unroll
                    for (int mt = 0; mt < 2; ++mt)
                        ach[rt][mt] = mfma16(bfrh[mt], af[rt], ach[rt][mt]);
            }
            __builtin_amdgcn_s_setprio(0);
        }

        // H = gelu(m1+b) -> LDS @49152 (H region; no conflict with W bufs)
        #pragma unroll
        for (int rt = 0; rt < 4; ++rt) {
            int pl = rt * 16 + l15;
            #pragma unroll
            for (int mt = 0; mt < 2; ++mt) {
                int hloc = wid * 32 + mt * 16 + lg * 4;
                float4 bv = *(const float4*)(Bc + 3584 + hc * 128 + hloc);
                float v[4];
                #pragma unroll
                for (int j = 0; j < 4; ++j) {
                    float tt = ach[rt][mt][j] + ((const float*)&bv)[j];
                    v[j] = tt * 0.5f * (1.0f + erff(tt * 0.70710678118f));
                }
                int cc = hloc >> 3;
                int pos = (cc & 8) | ((cc ^ swz8(pl)) & 7);
                *(uint2*)(smem + 49152 + pl * 256 + pos * 16 + (hloc & 7) * 2)
                    = make_uint2(pk2bf(v[0], v[1]), pk2bf(v[2], v[3]));
            }
        }
        __syncthreads();   // m1 reads done (both bufs free) + H visible

        // m2 partial: aco += m2W[:, hc*128..] @ H   (32KB chunks use both bufs)
        for (int ko = 0; ko < 128; ko += 64) {
            #pragma unroll
            for (int t = 0; t < 8; ++t) {
                int row = wid * 64 + t * 8 + (lane >> 3);
                int c = (lane & 7) ^ swz8(row);
                char* dst = ((wid < 2) ? (smem + wid * 8192) : (smem + 65536 + (wid - 2) * 8192))
                            + t * 1024;
                gl_lds(m2w + (long)row * 512 + hc * 128 + ko + c * 8, dst);
            }
            __syncthreads();

            __builtin_amdgcn_s_setprio(1);
            #pragma unroll
            for (int ks = 0; ks < 2; ++ks) {
                int ch = ks * 4 + lg;
                bf16x8 af[4], bfr[4];
                #pragma unroll
                for (int rt = 0; rt < 4; ++rt) {
                    int row = rt * 16 + l15;
                    int c = (ko >> 3) + ch;
                    int pos = (c & 8) | ((c ^ swz8(row)) & 7);
                    af[rt] = *(const bf16x8*)(smem + 49152 + row * 256 + pos * 16);
                }
                #pragma unroll
                for (int ct = 0; ct < 4; ++ct) {
                    int row = wid * 64 + ct * 16 + l15;
                    const char* base = (wid < 2) ? smem : (smem + 65536 - 16384);
                    bfr[ct] = *(const bf16x8*)(base + row * 128 + ((ch ^ swz8(row)) * 16));
                }
                #pragma unroll
                for (int rt = 0; rt < 4; ++rt)
                    #pragma unroll
                    for (int ct = 0; ct < 4; ++ct)
                        aco[rt][ct] = mfma16(bfr[ct], af[rt], aco[rt][ct]);
            }
            __builtin_amdgcn_s_setprio(0);
            __syncthreads();
        }

        // chain: stage next hc's m1 chunk0 -> buf0 (bufs free after barrier)
        if (hc < 3) {
            #pragma unroll
            for (int t = 0; t < 4; ++t) {
                int row = wid * 32 + t * 8 + (lane >> 3);
                int c = (lane & 7) ^ swz8(row);
                gl_lds(m1w + (long)((hc + 1) * 128 + row) * 256 + c * 8,
                       smem + wid * 4096 + t * 1024);
            }
        }
    }

    // ======== phase 4: +b2, *ls2, +NET (LDS) then transpose-write d_out ======
    #pragma unroll
    for (int rt = 0; rt < 4; ++rt) {
        int pl = rt * 16 + l15;
        #pragma unroll
        for (int ct = 0; ct < 4; ++ct) {
            int mg = wid * 64 + ct * 16 + lg * 4;
            float4 bv = *(const float4*)(Bc + 4096 + mg);
            float4 sv = *(const float4*)(ls2 + mg);
            int cc = mg >> 3;
            int pos = (cc & 24) | ((cc ^ swz8(pl)) & 7);
            uint2 nv2 = *(const uint2*)(smem + 16384 + pl * 512 + pos * 16 + (mg & 7) * 2);
            u16 nv[4] = { (u16)(nv2.x & 0xffff), (u16)(nv2.x >> 16),
                          (u16)(nv2.y & 0xffff), (u16)(nv2.y >> 16) };
            aco[rt][ct][0] = (aco[rt][ct][0] + bv.x) * sv.x + bf2f(nv[0]);
            aco[rt][ct][1] = (aco[rt][ct][1] + bv.y) * sv.y + bf2f(nv[1]);
            aco[rt][ct][2] = (aco[rt][ct][2] + bv.z) * sv.z + bf2f(nv[2]);
            aco[rt][ct][3] = (aco[rt][ct][3] + bv.w) * sv.w + bf2f(nv[3]);
        }
    }
    __syncthreads();   // all NET reads done -> whole LDS free for f32 tile

    #pragma unroll
    for (int rt = 0; rt < 4; ++rt) {
        int pl = rt * 16 + l15;
        #pragma unroll
        for (int ct = 0; ct < 4; ++ct) {
            int mg = wid * 64 + ct * 16 + lg * 4;
            #pragma unroll
            for (int j = 0; j < 4; ++j)
                ((float*)smem)[(mg + j) * 65 + pl] = aco[rt][ct][j];
        }
    }
    __syncthreads();

    {   // thread t streams channel t: 64 contiguous floats -> d_out
        const float* srcr = (const float*)smem + tid * 65;
        float* dst = y + ((long)(b * 256 + tid)) * HW + P0;
        #pragma unroll
        for (int k = 0; k < 16; ++k)
            *(float4*)(dst + k * 4) = *(const float4*)(srcr + k * 4);
    }
}

// ---------------------------------------------------------------------------
extern "C" void kernel_launch(void* const* d_in, const int* in_sizes, int n_in,
                              void* d_out, int out_size, void* d_ws, size_t ws_size,
                              hipStream_t stream)
{
    const float* x     = (const float*)d_in[0];
    const float* xq_w  = (const float*)d_in[1];
    const float* xq_b  = (const float*)d_in[2];
    const float* xk_w  = (const float*)d_in[3];
    const float* xk_b  = (const float*)d_in[4];
    const float* xv_w  = (const float*)d_in[5];
    const float* xv_b  = (const float*)d_in[6];
    const float* xp_w  = (const float*)d_in[7];
    const float* xp_b  = (const float*)d_in[8];
    const float* rel_x = (const float*)d_in[9];
    const float* yq_w  = (const float*)d_in[10];
    const float* yq_b  = (const float*)d_in[11];
    const float* yk_w  = (const float*)d_in[12];
    const float* yk_b  = (const float*)d_in[13];
    const float* yv_w  = (const float*)d_in[14];
    const float* yv_b  = (const float*)d_in[15];
    const float* yp_w  = (const float*)d_in[16];
    const float* yp_b  = (const float*)d_in[17];
    const float* rel_y = (const float*)d_in[18];
    const float* cp_w  = (const float*)d_in[19];
    const float* cp_b  = (const float*)d_in[20];
    const float* m1_w  = (const float*)d_in[21];
    const float* m1_b  = (const float*)d_in[22];
    const float* m2_w  = (const float*)d_in[23];
    const float* m2_b  = (const float*)d_in[24];
    const float* ls1   = (const float*)d_in[25];
    const float* ls2   = (const float*)d_in[26];

    if (ws_size < 128450560) return;

    char* ws = (char*)d_ws;
    u16*   SbY  = (u16*)(ws + 0);             // [8][3136][512] bf16
    u16*   Wb   = (u16*)(ws + 25690112);      // 851968 bf16
    float* Bc   = (float*)(ws + 27394048);    // 4352 f32
    u16*   Xt   = (u16*)(ws + 77070336);      // [8][3136][256] bf16
    u16*   SbX  = (u16*)(ws + 89915392);      // [8][3136][512] bf16

    dim3 blk(256, 1, 1);

    prep<<<dim3(2401, 1, 1), blk, 0, stream>>>(
        x, Xt,
        xq_w, xk_w, xv_w, yq_w, yk_w, yv_w, xp_w, yp_w, cp_w, m1_w, m2_w,
        xq_b, xk_b, xv_b, yq_b, yk_b, yv_b, xp_b, yp_b, cp_b, m1_b, m2_b,
        Wb, Bc);
    fused_attn<<<dim3(8, 4, 16), blk, 0, stream>>>(Wb, Bc, Xt, rel_x, rel_y, SbX, SbY);
    tail<<<dim3(49, 1, 8), blk, 0, stream>>>(Wb, Bc, SbX, SbY, Xt, ls1, ls2, (float*)d_out);
}

// Round 20
// 131.446 us; speedup vs baseline: 1.8451x; 1.0045x over previous
//
#include <hip/hip_runtime.h>

using u16 = unsigned short;
using u32 = unsigned int;

typedef short bf16x8 __attribute__((ext_vector_type(8)));
typedef float f32x4 __attribute__((ext_vector_type(4)));

#define HW 3136
#define IMG 56

__device__ __forceinline__ float bf2f(u16 v) {
    union { u32 u; float f; } c; c.u = ((u32)v) << 16; return c.f;
}
__device__ __forceinline__ u16 f2bf(float f) {
    union { float f; u32 u; } c; c.f = f;
    return (u16)((c.u + 0x7fffu + ((c.u >> 16) & 1u)) >> 16);
}
// pack 2 f32 -> 2 bf16 in one u32 (RNE, hardware cvt)
__device__ __forceinline__ u32 pk2bf(float a, float b) {
    u32 r;
    asm("v_cvt_pk_bf16_f32 %0, %1, %2" : "=v"(r) : "v"(a), "v"(b));
    return r;
}
__device__ __forceinline__ int swz8(int r) { return (r ^ (r >> 3)) & 7; }

__device__ __forceinline__ f32x4 mfma16(bf16x8 a, bf16x8 b, f32x4 c) {
    return __builtin_amdgcn_mfma_f32_16x16x32_bf16(a, b, c, 0, 0, 0);
}

// async global->LDS, 16B per lane; dest = lds_base + lane*16 (wave-uniform base)
__device__ __forceinline__ void gl_lds(const void* g, void* l) {
    __builtin_amdgcn_global_load_lds((const __attribute__((address_space(1))) void*)g,
                                     (__attribute__((address_space(3))) void*)l, 16, 0, 0);
}

// ---------------------------------------------------------------------------
// prep: merged wcvt + transpose_x.
// ---------------------------------------------------------------------------
__global__ __launch_bounds__(256) void prep(
    const float* __restrict__ x, u16* __restrict__ Xt,
    const float* __restrict__ s0, const float* __restrict__ s1, const float* __restrict__ s2,
    const float* __restrict__ s3, const float* __restrict__ s4, const float* __restrict__ s5,
    const float* __restrict__ s6, const float* __restrict__ s7, const float* __restrict__ s8,
    const float* __restrict__ s9, const float* __restrict__ s10,
    const float* __restrict__ b0, const float* __restrict__ b1, const float* __restrict__ b2,
    const float* __restrict__ b3, const float* __restrict__ b4, const float* __restrict__ b5,
    const float* __restrict__ b6, const float* __restrict__ b7, const float* __restrict__ b8,
    const float* __restrict__ b9, const float* __restrict__ b10,
    u16* __restrict__ Wb, float* __restrict__ Bc)
{
    __shared__ u16 lds[64][80];
    const int t = threadIdx.x;
    const int idx = blockIdx.x;

    if (idx < 1568) {   // transpose path
        const int Pb = (idx % 49) * 64;
        const int Cb = ((idx / 49) & 3) * 64;
        const int b  = idx / 196;
        #pragma unroll
        for (int q = 0; q < 4; ++q) {
            int id = t + q * 256;
            int c = id >> 4, pf = (id & 15) * 4;
            float4 v = *(const float4*)(x + ((long)(b * 256 + Cb + c)) * HW + Pb + pf);
            u16 vv[4] = { f2bf(v.x), f2bf(v.y), f2bf(v.z), f2bf(v.w) };
            #pragma unroll
            for (int j = 0; j < 4; ++j) {
                int p = pf + j;
                int cc = (((c >> 3) ^ ((p >> 2) & 7)) << 3) + (c & 7);
                lds[p][cc] = vv[j];
            }
        }
        __syncthreads();
        int p = t >> 2, cf = (t & 3) * 16;
        u16* dst = Xt + ((long)b * HW + Pb + p) * 256 + Cb + cf;
        int cc0 = ((cf >> 3) + 0) ^ ((p >> 2) & 7);
        int cc1 = ((cf >> 3) + 1) ^ ((p >> 2) & 7);
        *(uint4*)(dst + 0) = *(uint4*)&lds[p][cc0 * 8];
        *(uint4*)(dst + 8) = *(uint4*)&lds[p][cc1 * 8];
        return;
    }

    const int bx = idx - 1568;          // wcvt path, 0..832
    if (bx == 832) {                    // biases
        for (int i = t; i < 4352; i += 256) {
            const float* src; int off;
            if      (i < 512)  { src = b0;  off = i; }
            else if (i < 1024) { src = b1;  off = i - 512; }
            else if (i < 1536) { src = b2;  off = i - 1024; }
            else if (i < 2048) { src = b3;  off = i - 1536; }
            else if (i < 2560) { src = b4;  off = i - 2048; }
            else if (i < 3072) { src = b5;  off = i - 2560; }
            else if (i < 3200) { src = b6;  off = i - 3072; }
            else if (i < 3328) { src = b7;  off = i - 3200; }
            else if (i < 3584) { src = b8;  off = i - 3328; }
            else if (i < 4096) { src = b9;  off = i - 3584; }
            else               { src = b10; off = i - 4096; }
            Bc[i] = src[off];
        }
        return;
    }
    long gid4 = ((long)bx * 256 + t) * 4;
    const float* src; long off;
    if (gid4 < 589824) {
        int seg = (int)(gid4 >> 16);
        const float* tab[9] = { s0, s1, s2, s3, s4, s5, s6, s7, s8 };
        src = tab[seg]; off = gid4 - ((long)seg << 16);
    } else if (gid4 < 720896) { src = s9;  off = gid4 - 589824; }
    else                      { src = s10; off = gid4 - 720896; }
    float4 v = *(const float4*)(src + off);
    *(uint2*)(Wb + gid4) = make_uint2(pk2bf(v.x, v.y), pk2bf(v.z, v.w));
}

// ---------------------------------------------------------------------------
// fused_attn: QKV projection + axial attention (round-17 verified).
// LDS: QT[0,16K) KT[16K,32K) V[32K,48K) X[49152,65536) RELf32[65536,66048).
// ---------------------------------------------------------------------------
__global__ __launch_bounds__(256, 2) void fused_attn(
    const u16* __restrict__ Wb, const float* __restrict__ Bc,
    const u16* __restrict__ Xt,
    const float* __restrict__ rel_x, const float* __restrict__ rel_y,
    u16* __restrict__ SbX, u16* __restrict__ SbY)
{
    __shared__ __align__(16) char smem[66048];
    const int tid = threadIdx.x;
    const int lane = tid & 63, wid = tid >> 6;
    const int l15 = lane & 15, lg = lane >> 4;

    const int g = blockIdx.x;            // bid%8 = g -> per-XCD L2 partition
    const int n = blockIdx.y;
    const int branch = blockIdx.z >> 3;
    const int b = blockIdx.z & 7;

    const float* rel = branch ? rel_y : rel_x;
    u16* S = branch ? SbY : SbX;
    const u16* wsrc = Wb + branch * 196608 + n * 16384;
    const float* bsrc = Bc + branch * 1536 + n * 128;

    if (tid < 128) {
        float v = (tid < 112) ? rel[n * HW + tid] : 0.0f;
        *(float*)(smem + 65536 + tid * 4) = v;
    }

    bf16x8 wf[3][2][4];
    #pragma unroll
    for (int mat = 0; mat < 3; ++mat)
        #pragma unroll
        for (int mt = 0; mt < 2; ++mt) {
            int mrow = (wid * 2 + mt) * 16 + l15;
            const u16* wr = wsrc + mat * 65536 + mrow * 128;
            #pragma unroll
            for (int ks = 0; ks < 4; ++ks)
                wf[mat][mt][ks] = *(const bf16x8*)(wr + (ks * 4 + lg) * 8);
        }
    float4 bq4[2], bk4[2]; float bvv[2];
    #pragma unroll
    for (int mt = 0; mt < 2; ++mt) {
        int m0 = (wid * 2 + mt) * 16 + lg * 4;
        bq4[mt] = *(const float4*)(bsrc + m0);
        bk4[mt] = *(const float4*)(bsrc + 512 + m0);
        bvv[mt] = bsrc[1024 + (wid * 2 + mt) * 16 + l15];
    }

    const int istrip = wid * 16;
    const float qscale = 0.08838834764831845f;

    auto stageX = [&](int rc2) {
        const int i0 = wid * 16 + (lane >> 4);
        #pragma unroll
        for (int t = 0; t < 4; ++t) {
            int i = i0 + t * 4;
            int ic = (i > 55) ? 55 : i;
            long p = (branch == 0) ? (long)rc2 * IMG + ic : (long)ic * IMG + rc2;
            const u16* src = Xt + ((long)b * HW + p) * 256 + branch * 128
                             + (((lane & 15) ^ swz8(i)) * 8);
            gl_lds(src, smem + 49152 + wid * 4096 + t * 1024);
        }
    };

    stageX(g * 7);

    for (int r = 0; r < 7; ++r) {
        const int rc = g * 7 + r;

        __syncthreads();   // A: X(r) staged + prev LDS reads done

        bf16x8 xf[4][4];
        #pragma unroll
        for (int it = 0; it < 4; ++it) {
            int i = it * 16 + l15;
            #pragma unroll
            for (int ks = 0; ks < 4; ++ks)
                xf[it][ks] = *(const bf16x8*)(smem + 49152 + i * 256
                                              + (((ks * 4 + lg) ^ swz8(i)) * 16));
        }

        __builtin_amdgcn_s_setprio(1);
        #pragma unroll
        for (int mat = 0; mat < 2; ++mat) {
            #pragma unroll
            for (int mt = 0; mt < 2; ++mt) {
                #pragma unroll
                for (int it = 0; it < 4; ++it) {
                    f32x4 a = {};
                    #pragma unroll
                    for (int ks = 0; ks < 4; ++ks)
                        a = mfma16(wf[mat][mt][ks], xf[it][ks], a);
                    int i = it * 16 + l15;
                    int m0 = (wid * 2 + mt) * 16 + lg * 4;
                    float4 bb2 = mat ? bk4[mt] : bq4[mt];
                    int c = m0 >> 3;
                    *(uint2*)(smem + mat * 16384 + i * 256 + ((c ^ swz8(i)) * 16) + (lg & 1) * 8)
                        = make_uint2(pk2bf(a[0] + bb2.x, a[1] + bb2.y),
                                     pk2bf(a[2] + bb2.z, a[3] + bb2.w));
                }
            }
        }
        #pragma unroll
        for (int mt = 0; mt < 2; ++mt) {
            #pragma unroll
            for (int it = 0; it < 4; ++it) {
                f32x4 a = {};
                #pragma unroll
                for (int ks = 0; ks < 4; ++ks)
                    a = mfma16(xf[it][ks], wf[2][mt][ks], a);
                int d = (wid * 2 + mt) * 16 + l15;
                int c2 = (it >> 1) * 4 + lg;
                float bv = bvv[mt];
                *(uint2*)(smem + 32768 + d * 128 + ((c2 ^ swz8(d)) * 16) + (it & 1) * 8)
                    = make_uint2(pk2bf(a[0] + bv, a[1] + bv),
                                 pk2bf(a[2] + bv, a[3] + bv));
            }
        }
        __builtin_amdgcn_s_setprio(0);
        __syncthreads();   // B: proj visible; X region free

        if (r < 6) stageX(rc + 1);   // overlaps QK/softmax/PV (T14)

        bf16x8 aq[4];
        #pragma unroll
        for (int ks = 0; ks < 4; ++ks) {
            int row = istrip + l15;
            int ch = ks * 4 + lg;
            aq[ks] = *(const bf16x8*)(smem + row * 256 + ((ch ^ swz8(row)) * 16));
        }
        __builtin_amdgcn_s_setprio(1);
        f32x4 sacc[4] = {};
        #pragma unroll
        for (int ct = 0; ct < 4; ++ct) {
            #pragma unroll
            for (int ks = 0; ks < 4; ++ks) {
                int j = ct * 16 + l15;
                int ch = ks * 4 + lg;
                bf16x8 kb = *(const bf16x8*)(smem + 16384 + j * 256 + ((ch ^ swz8(j)) * 16));
                sacc[ct] = mfma16(kb, aq[ks], sacc[ct]);
            }
        }
        __builtin_amdgcn_s_setprio(0);

        const int irow = istrip + l15;
        float p[4][4];
        float mx = -1e30f;
        #pragma unroll
        for (int ct = 0; ct < 4; ++ct)
            #pragma unroll
            for (int rr = 0; rr < 4; ++rr) {
                int j = ct * 16 + lg * 4 + rr;
                float x = sacc[ct][rr] * qscale;
                if (j < IMG) x += *(const float*)(smem + 65536 + (irow - j + 55) * 4);
                else x = -1e30f;
                p[ct][rr] = x;
                mx = fmaxf(mx, x);
            }
        mx = fmaxf(mx, __shfl_xor(mx, 16));
        mx = fmaxf(mx, __shfl_xor(mx, 32));
        float s0 = 0.f;
        #pragma unroll
        for (int ct = 0; ct < 4; ++ct)
            #pragma unroll
            for (int rr = 0; rr < 4; ++rr) {
                float e = __expf(p[ct][rr] - mx);
                p[ct][rr] = e; s0 += e;
            }
        s0 += __shfl_xor(s0, 16);
        s0 += __shfl_xor(s0, 32);
        float inv = 1.0f / s0;

        union { u32 u[4]; bf16x8 v; } pb[2];
        #pragma unroll
        for (int ks = 0; ks < 2; ++ks) {
            pb[ks].u[0] = pk2bf(p[2*ks][0] * inv, p[2*ks][1] * inv);
            pb[ks].u[1] = pk2bf(p[2*ks][2] * inv, p[2*ks][3] * inv);
            pb[ks].u[2] = pk2bf(p[2*ks+1][0] * inv, p[2*ks+1][1] * inv);
            pb[ks].u[3] = pk2bf(p[2*ks+1][2] * inv, p[2*ks+1][3] * inv);
        }

        __builtin_amdgcn_s_setprio(1);
        f32x4 oacc[8] = {};
        #pragma unroll
        for (int dt = 0; dt < 8; ++dt) {
            #pragma unroll
            for (int ks = 0; ks < 2; ++ks) {
                int d = dt * 16 + l15;
                int c2 = ks * 4 + lg;
                bf16x8 vb = *(const bf16x8*)(smem + 32768 + d * 128 + ((c2 ^ swz8(d)) * 16));
                oacc[dt] = mfma16(vb, pb[ks].v, oacc[dt]);
            }
        }
        __builtin_amdgcn_s_setprio(0);

        const int i = istrip + l15;
        if (i < IMG) {
            int im = n * 14 + (i >> 2);
            long pp = (branch == 0) ? (long)rc * IMG + im : (long)im * IMG + rc;
            u16* dst = S + ((long)b * HW + pp) * 512 + (i & 3) * 128;
            #pragma unroll
            for (int dt = 0; dt < 8; ++dt) {
                int d4 = dt * 16 + lg * 4;
                *(uint2*)(dst + d4) = make_uint2(pk2bf(oacc[dt][0], oacc[dt][1]),
                                                 pk2bf(oacc[dt][2], oacc[dt][3]));
            }
        }
    }
}

// ---------------------------------------------------------------------------
// tail: fused out-proj(X,Y) + cp + m1/GELU + m2 + final transpose to d_out.
// P3's m1 weights double-buffered (Wbuf0 [0,16K), Wbuf1 [64K,80K)): one
// barrier per chunk, staging hidden under MFMA. NET [16K,48K), H [48K,64K).
// ---------------------------------------------------------------------------
__global__ __launch_bounds__(256, 2) void tail(
    const u16* __restrict__ Wb, const float* __restrict__ Bc,
    const u16* __restrict__ SbX, const u16* __restrict__ SbY,
    const u16* __restrict__ Xt,
    const float* __restrict__ ls1, const float* __restrict__ ls2,
    float* __restrict__ y)
{
    __shared__ __align__(16) char smem[81920];
    const int tid = threadIdx.x;
    const int lane = tid & 63, wid = tid >> 6;
    const int l15 = lane & 15, lg = lane >> 4;
    const int P0 = blockIdx.x * 64;
    const int b  = blockIdx.z;

    const u16* xp  = Wb + 393216;
    const u16* yp  = Wb + 458752;
    const u16* cpw = Wb + 524288;
    const u16* m1w = Wb + 589824;
    const u16* m2w = Wb + 720896;

    // ================= phase 1: out-projection X|Y -> AXY LDS =================
    f32x4 acc[4][4] = {};
    for (int ko = 0; ko < 512; ko += 64) {
        #pragma unroll
        for (int t = 0; t < 2; ++t) {
            int row = wid * 16 + t * 8 + (lane >> 3);
            int c = (lane & 7) ^ swz8(row);
            long prow = (long)b * HW + P0 + row;
            gl_lds(SbX + prow * 512 + ko + c * 8, smem + wid * 2048 + t * 1024);
            gl_lds(SbY + prow * 512 + ko + c * 8, smem + 8192 + wid * 2048 + t * 1024);
        }
        #pragma unroll
        for (int t = 0; t < 4; ++t) {
            int row = wid * 32 + t * 8 + (lane >> 3);
            int c = (lane & 7) ^ swz8(row);
            gl_lds(xp + (long)row * 512 + ko + c * 8, smem + 16384 + wid * 4096 + t * 1024);
            gl_lds(yp + (long)row * 512 + ko + c * 8, smem + 32768 + wid * 4096 + t * 1024);
        }
        __syncthreads();

        const int actb = (wid < 2) ? 0 : 8192;
        const int wbse = (wid < 2) ? 16384 : 32768;
        const int wrow0 = (wid & 1) * 64;
        __builtin_amdgcn_s_setprio(1);
        #pragma unroll
        for (int ks = 0; ks < 2; ++ks) {
            int ch = ks * 4 + lg;
            bf16x8 af[4], bfr[4];
            #pragma unroll
            for (int rt = 0; rt < 4; ++rt) {
                int row = rt * 16 + l15;
                af[rt] = *(const bf16x8*)(smem + actb + row * 128 + ((ch ^ swz8(row)) * 16));
            }
            #pragma unroll
            for (int ct = 0; ct < 4; ++ct) {
                int row = wrow0 + ct * 16 + l15;
                bfr[ct] = *(const bf16x8*)(smem + wbse + row * 128 + ((ch ^ swz8(row)) * 16));
            }
            #pragma unroll
            for (int rt = 0; rt < 4; ++rt)
                #pragma unroll
                for (int ct = 0; ct < 4; ++ct)
                    acc[rt][ct] = mfma16(bfr[ct], af[rt], acc[rt][ct]);
        }
        __builtin_amdgcn_s_setprio(0);
        __syncthreads();
    }

    #pragma unroll
    for (int rt = 0; rt < 4; ++rt) {
        int pl = rt * 16 + l15;
        long rowp = (long)b * HW + P0 + pl;
        #pragma unroll
        for (int ct = 0; ct < 4; ++ct) {
            int mg2 = wid * 64 + ct * 16 + lg * 4;
            float4 bv = *(const float4*)(Bc + 3072 + mg2);
            ushort4 rv = *(const ushort4*)(Xt + rowp * 256 + mg2);
            float v0 = acc[rt][ct][0] + bv.x + bf2f(rv.x);
            float v1 = acc[rt][ct][1] + bv.y + bf2f(rv.y);
            float v2 = acc[rt][ct][2] + bv.z + bf2f(rv.z);
            float v3 = acc[rt][ct][3] + bv.w + bf2f(rv.w);
            int cc = mg2 >> 3;
            int pos = (cc & 24) | ((cc ^ swz8(pl)) & 7);
            *(uint2*)(smem + 49152 + pl * 512 + pos * 16 + (mg2 & 7) * 2)
                = make_uint2(pk2bf(v0, v1), pk2bf(v2, v3));
        }
    }
    __syncthreads();

    // ================= phase 2: cp -> NET LDS =================
    f32x4 acc2[4][4] = {};
    for (int ko = 0; ko < 256; ko += 64) {
        #pragma unroll
        for (int t = 0; t < 8; ++t) {
            int row = wid * 64 + t * 8 + (lane >> 3);
            int c = (lane & 7) ^ swz8(row);
            gl_lds(cpw + (long)row * 256 + ko + c * 8, smem + 16384 + wid * 8192 + t * 1024);
        }
        __syncthreads();

        __builtin_amdgcn_s_setprio(1);
        #pragma unroll
        for (int ks = 0; ks < 2; ++ks) {
            int ch = ks * 4 + lg;
            bf16x8 af[4], bfr[4];
            #pragma unroll
            for (int rt = 0; rt < 4; ++rt) {
                int row = rt * 16 + l15;
                int c = (ko >> 3) + ch;
                int pos = (c & 24) | ((c ^ swz8(row)) & 7);
                af[rt] = *(const bf16x8*)(smem + 49152 + row * 512 + pos * 16);
            }
            #pragma unroll
            for (int ct = 0; ct < 4; ++ct) {
                int row = wid * 64 + ct * 16 + l15;
                bfr[ct] = *(const bf16x8*)(smem + 16384 + row * 128 + ((ch ^ swz8(row)) * 16));
            }
            #pragma unroll
            for (int rt = 0; rt < 4; ++rt)
                #pragma unroll
                for (int ct = 0; ct < 4; ++ct)
                    acc2[rt][ct] = mfma16(bfr[ct], af[rt], acc2[rt][ct]);
        }
        __builtin_amdgcn_s_setprio(0);
        __syncthreads();
    }

    // NET = ls1*(cp+b) + Xt -> LDS @16384 (rows [64][512B], swizzled)
    #pragma unroll
    for (int rt = 0; rt < 4; ++rt) {
        int pl = rt * 16 + l15;
        long rowp = (long)b * HW + P0 + pl;
        #pragma unroll
        for (int ct = 0; ct < 4; ++ct) {
            int mg = wid * 64 + ct * 16 + lg * 4;
            float4 bv = *(const float4*)(Bc + 3328 + mg);
            float4 sv = *(const float4*)(ls1 + mg);
            ushort4 rv = *(const ushort4*)(Xt + rowp * 256 + mg);
            float v0 = (acc2[rt][ct][0] + bv.x) * sv.x + bf2f(rv.x);
            float v1 = (acc2[rt][ct][1] + bv.y) * sv.y + bf2f(rv.y);
            float v2 = (acc2[rt][ct][2] + bv.z) * sv.z + bf2f(rv.z);
            float v3 = (acc2[rt][ct][3] + bv.w) * sv.w + bf2f(rv.w);
            int cc = mg >> 3;
            int pos = (cc & 24) | ((cc ^ swz8(pl)) & 7);
            *(uint2*)(smem + 16384 + pl * 512 + pos * 16 + (mg & 7) * 2)
                = make_uint2(pk2bf(v0, v1), pk2bf(v2, v3));
        }
    }

    // ================= phase 3: m1 + GELU + m2 (m1W double-buffered) =========
    f32x4 aco[4][4] = {};

    // initial stage: m1W(hc=0, chunk0) -> buf0 ([0,16K) dead since P1)
    #pragma unroll
    for (int t = 0; t < 4; ++t) {
        int row = wid * 32 + t * 8 + (lane >> 3);
        int c = (lane & 7) ^ swz8(row);
        gl_lds(m1w + (long)row * 256 + c * 8, smem + wid * 4096 + t * 1024);
    }

    for (int hc = 0; hc < 4; ++hc) {
        f32x4 ach[4][2] = {};
        #pragma unroll
        for (int idx = 0; idx < 4; ++idx) {
            __syncthreads();   // cur buf staged; prior reads done
            if (idx < 3) {     // stage next chunk into other buf (hidden)
                char* nbuf = ((idx & 1) == 0) ? (smem + 65536) : smem;
                #pragma unroll
                for (int t = 0; t < 4; ++t) {
                    int row = wid * 32 + t * 8 + (lane >> 3);
                    int c = (lane & 7) ^ swz8(row);
                    gl_lds(m1w + (long)(hc * 128 + row) * 256 + (idx + 1) * 64 + c * 8,
                           nbuf + wid * 4096 + t * 1024);
                }
            }
            const char* cbuf = ((idx & 1) == 0) ? smem : (smem + 65536);
            const int ko = idx * 64;
            __builtin_amdgcn_s_setprio(1);
            #pragma unroll
            for (int ks = 0; ks < 2; ++ks) {
                int ch = ks * 4 + lg;
                bf16x8 af[4], bfrh[2];
                #pragma unroll
                for (int rt = 0; rt < 4; ++rt) {
                    int row = rt * 16 + l15;
                    int c = (ko >> 3) + ch;
                    int pos = (c & 24) | ((c ^ swz8(row)) & 7);
                    af[rt] = *(const bf16x8*)(smem + 16384 + row * 512 + pos * 16);
                }
                #pragma unroll
                for (int mt = 0; mt < 2; ++mt) {
                    int row = wid * 32 + mt * 16 + l15;
                    bfrh[mt] = *(const bf16x8*)(cbuf + row * 128 + ((ch ^ swz8(row)) * 16));
                }
                #pragma unroll
                for (int rt = 0; rt < 4; ++rt)
                    #pragma unroll
                    for (int mt = 0; mt < 2; ++mt)
                        ach[rt][mt] = mfma16(bfrh[mt], af[rt], ach[rt][mt]);
            }
            __builtin_amdgcn_s_setprio(0);
        }

        // H = gelu(m1+b) -> LDS @49152 (H region; no conflict with W bufs)
        #pragma unroll
        for (int rt = 0; rt < 4; ++rt) {
            int pl = rt * 16 + l15;
            #pragma unroll
            for (int mt = 0; mt < 2; ++mt) {
                int hloc = wid * 32 + mt * 16 + lg * 4;
                float4 bv = *(const float4*)(Bc + 3584 + hc * 128 + hloc);
                float v[4];
                #pragma unroll
                for (int j = 0; j < 4; ++j) {
                    float tt = ach[rt][mt][j] + ((const float*)&bv)[j];
                    v[j] = tt * 0.5f * (1.0f + erff(tt * 0.70710678118f));
                }
                int cc = hloc >> 3;
                int pos = (cc & 8) | ((cc ^ swz8(pl)) & 7);
                *(uint2*)(smem + 49152 + pl * 256 + pos * 16 + (hloc & 7) * 2)
                    = make_uint2(pk2bf(v[0], v[1]), pk2bf(v[2], v[3]));
            }
        }
        __syncthreads();   // m1 reads done (both bufs free) + H visible

        // m2 partial: aco += m2W[:, hc*128..] @ H   (32KB chunks use both bufs)
        for (int ko = 0; ko < 128; ko += 64) {
            #pragma unroll
            for (int t = 0; t < 8; ++t) {
                int row = wid * 64 + t * 8 + (lane >> 3);
                int c = (lane & 7) ^ swz8(row);
                char* dst = ((wid < 2) ? (smem + wid * 8192) : (smem + 65536 + (wid - 2) * 8192))
                            + t * 1024;
                gl_lds(m2w + (long)row * 512 + hc * 128 + ko + c * 8, dst);
            }
            __syncthreads();

            __builtin_amdgcn_s_setprio(1);
            #pragma unroll
            for (int ks = 0; ks < 2; ++ks) {
                int ch = ks * 4 + lg;
                bf16x8 af[4], bfr[4];
                #pragma unroll
                for (int rt = 0; rt < 4; ++rt) {
                    int row = rt * 16 + l15;
                    int c = (ko >> 3) + ch;
                    int pos = (c & 8) | ((c ^ swz8(row)) & 7);
                    af[rt] = *(const bf16x8*)(smem + 49152 + row * 256 + pos * 16);
                }
                #pragma unroll
                for (int ct = 0; ct < 4; ++ct) {
                    int row = wid * 64 + ct * 16 + l15;
                    const char* base = (wid < 2) ? smem : (smem + 65536 - 16384);
                    bfr[ct] = *(const bf16x8*)(base + row * 128 + ((ch ^ swz8(row)) * 16));
                }
                #pragma unroll
                for (int rt = 0; rt < 4; ++rt)
                    #pragma unroll
                    for (int ct = 0; ct < 4; ++ct)
                        aco[rt][ct] = mfma16(bfr[ct], af[rt], aco[rt][ct]);
            }
            __builtin_amdgcn_s_setprio(0);
            __syncthreads();
        }

        // chain: stage next hc's m1 chunk0 -> buf0 (bufs free after barrier)
        if (hc < 3) {
            #pragma unroll
            for (int t = 0; t < 4; ++t) {
                int row = wid * 32 + t * 8 + (lane >> 3);
                int c = (lane & 7) ^ swz8(row);
                gl_lds(m1w + (long)((hc + 1) * 128 + row) * 256 + c * 8,
                       smem + wid * 4096 + t * 1024);
            }
        }
    }

    // ======== phase 4: +b2, *ls2, +NET (LDS) then transpose-write d_out ======
    #pragma unroll
    for (int rt = 0; rt < 4; ++rt) {
        int pl = rt * 16 + l15;
        #pragma unroll
        for (int ct = 0; ct < 4; ++ct) {
            int mg = wid * 64 + ct * 16 + lg * 4;
            float4 bv = *(const float4*)(Bc + 4096 + mg);
            float4 sv = *(const float4*)(ls2 + mg);
            int cc = mg >> 3;
            int pos = (cc & 24) | ((cc ^ swz8(pl)) & 7);
            uint2 nv2 = *(const uint2*)(smem + 16384 + pl * 512 + pos * 16 + (mg & 7) * 2);
            u16 nv[4] = { (u16)(nv2.x & 0xffff), (u16)(nv2.x >> 16),
                          (u16)(nv2.y & 0xffff), (u16)(nv2.y >> 16) };
            aco[rt][ct][0] = (aco[rt][ct][0] + bv.x) * sv.x + bf2f(nv[0]);
            aco[rt][ct][1] = (aco[rt][ct][1] + bv.y) * sv.y + bf2f(nv[1]);
            aco[rt][ct][2] = (aco[rt][ct][2] + bv.z) * sv.z + bf2f(nv[2]);
            aco[rt][ct][3] = (aco[rt][ct][3] + bv.w) * sv.w + bf2f(nv[3]);
        }
    }
    __syncthreads();   // all NET reads done -> whole LDS free for f32 tile

    #pragma unroll
    for (int rt = 0; rt < 4; ++rt) {
        int pl = rt * 16 + l15;
        #pragma unroll
        for (int ct = 0; ct < 4; ++ct) {
            int mg = wid * 64 + ct * 16 + lg * 4;
            #pragma unroll
            for (int j = 0; j < 4; ++j)
                ((float*)smem)[(mg + j) * 65 + pl] = aco[rt][ct][j];
        }
    }
    __syncthreads();

    {   // thread t streams channel t: 64 contiguous floats -> d_out
        const float* srcr = (const float*)smem + tid * 65;
        float* dst = y + ((long)(b * 256 + tid)) * HW + P0;
        #pragma unroll
        for (int k = 0; k < 16; ++k)
            *(float4*)(dst + k * 4) = *(const float4*)(srcr + k * 4);
    }
}

// ---------------------------------------------------------------------------
extern "C" void kernel_launch(void* const* d_in, const int* in_sizes, int n_in,
                              void* d_out, int out_size, void* d_ws, size_t ws_size,
                              hipStream_t stream)
{
    const float* x     = (const float*)d_in[0];
    const float* xq_w  = (const float*)d_in[1];
    const float* xq_b  = (const float*)d_in[2];
    const float* xk_w  = (const float*)d_in[3];
    const float* xk_b  = (const float*)d_in[4];
    const float* xv_w  = (const float*)d_in[5];
    const float* xv_b  = (const float*)d_in[6];
    const float* xp_w  = (const float*)d_in[7];
    const float* xp_b  = (const float*)d_in[8];
    const float* rel_x = (const float*)d_in[9];
    const float* yq_w  = (const float*)d_in[10];
    const float* yq_b  = (const float*)d_in[11];
    const float* yk_w  = (const float*)d_in[12];
    const float* yk_b  = (const float*)d_in[13];
    const float* yv_w  = (const float*)d_in[14];
    const float* yv_b  = (const float*)d_in[15];
    const float* yp_w  = (const float*)d_in[16];
    const float* yp_b  = (const float*)d_in[17];
    const float* rel_y = (const float*)d_in[18];
    const float* cp_w  = (const float*)d_in[19];
    const float* cp_b  = (const float*)d_in[20];
    const float* m1_w  = (const float*)d_in[21];
    const float* m1_b  = (const float*)d_in[22];
    const float* m2_w  = (const float*)d_in[23];
    const float* m2_b  = (const float*)d_in[24];
    const float* ls1   = (const float*)d_in[25];
    const float* ls2   = (const float*)d_in[26];

    if (ws_size < 128450560) return;

    char* ws = (char*)d_ws;
    u16*   SbY  = (u16*)(ws + 0);             // [8][3136][512] bf16
    u16*   Wb   = (u16*)(ws + 25690112);      // 851968 bf16
    float* Bc   = (float*)(ws + 27394048);    // 4352 f32
    u16*   Xt   = (u16*)(ws + 77070336);      // [8][3136][256] bf16
    u16*   SbX  = (u16*)(ws + 89915392);      // [8][3136][512] bf16

    dim3 blk(256, 1, 1);

    prep<<<dim3(2401, 1, 1), blk, 0, stream>>>(
        x, Xt,
        xq_w, xk_w, xv_w, yq_w, yk_w, yv_w, xp_w, yp_w, cp_w, m1_w, m2_w,
        xq_b, xk_b, xv_b, yq_b, yk_b, yv_b, xp_b, yp_b, cp_b, m1_b, m2_b,
        Wb, Bc);
    fused_attn<<<dim3(8, 4, 16), blk, 0, stream>>>(Wb, Bc, Xt, rel_x, rel_y, SbX, SbY);
    tail<<<dim3(49, 1, 8), blk, 0, stream>>>(Wb, Bc, SbX, SbY, Xt, ls1, ls2, (float*)d_out);
}